// Round 16
// baseline (231.067 us; speedup 1.0000x reference)
//
#include <hip/hip_runtime.h>
#include <hip/hip_bf16.h>

#define BB 8
#define NN 1024
#define DD 384
#define HH 6
#define HD 64
#define BN 8192          // B*N rows
#define D3 1152          // 3*D
#define D4 1536          // 4*D
#define SEC 3145728      // B*H*N*HD elems per plane

typedef __attribute__((ext_vector_type(8))) short short8;
typedef __attribute__((ext_vector_type(4))) float f32x4;
typedef __attribute__((ext_vector_type(2))) float f32x2;
typedef long v2i64 __attribute__((ext_vector_type(2)));

typedef __attribute__((address_space(3))) unsigned char as3_byte;
typedef __attribute__((address_space(1))) const unsigned char as1_byte;

__device__ __forceinline__ void gload16(const void* g, void* l){
  __builtin_amdgcn_global_load_lds((as1_byte*)g, (as3_byte*)l, 16, 0, 0);
}

__device__ __forceinline__ float b2f(unsigned short u){
  union{unsigned int i; float f;} x; x.i=((unsigned int)u)<<16; return x.f;
}
__device__ __forceinline__ unsigned short f2b(float f){
  unsigned int u=__float_as_uint(f);
  return (unsigned short)((u + 0x7FFFu + ((u>>16)&1u))>>16);
}

// ---------------- fp32 -> bf16 weight convert (all 4 weights), one launch ----------------
__global__ void cvt_kernel(const float* __restrict__ w0, const float* __restrict__ w1,
                           const float* __restrict__ w2, const float* __restrict__ w3,
                           unsigned short* __restrict__ out){
  int i = blockIdx.x*256 + threadIdx.x;
  if (i < 442368)        out[i] = f2b(w0[i]);
  else if (i < 589824)   out[i] = f2b(w1[i - 442368]);
  else if (i < 1179648)  out[i] = f2b(w2[i - 589824]);
  else if (i < 1769472)  out[i] = f2b(w3[i - 1179648]);
}

// ---------------- LayerNorm over D=384, one block per row ----------------
template<int OUTBF>
__global__ __launch_bounds__(128)
void ln_kernel(const float* __restrict__ in, const float* __restrict__ gg, const float* __restrict__ bb,
               float* __restrict__ outf, unsigned short* __restrict__ outb){
  int row = blockIdx.x, t = threadIdx.x;
  const float* r = in + (size_t)row*DD;
  float v0=r[t], v1=r[t+128], v2=r[t+256];
  float s=v0+v1+v2, q=v0*v0+v1*v1+v2*v2;
  #pragma unroll
  for (int o=32;o>0;o>>=1){ s+=__shfl_down(s,o); q+=__shfl_down(q,o); }
  __shared__ float ls[2], lq[2];
  if ((t&63)==0){ ls[t>>6]=s; lq[t>>6]=q; }
  __syncthreads();
  float S=ls[0]+ls[1], Q=lq[0]+lq[1];
  float mean=S*(1.0f/DD);
  float rstd=rsqrtf(Q*(1.0f/DD)-mean*mean+1e-5f);
  float o0=(v0-mean)*rstd*gg[t]+bb[t];
  float o1=(v1-mean)*rstd*gg[t+128]+bb[t+128];
  float o2=(v2-mean)*rstd*gg[t+256]+bb[t+256];
  if (OUTBF){ unsigned short* o=outb+(size_t)row*DD; o[t]=f2b(o0); o[t+128]=f2b(o1); o[t+256]=f2b(o2); }
  else      { float* o=outf+(size_t)row*DD; o[t]=o0; o[t+128]=o1; o[t+256]=o2; }
}

// ---------------- depthwise conv1d (K=7, same) + bias + LayerNorm ----------------
__global__ __launch_bounds__(128)
void conv_ln_kernel(const float* __restrict__ h2, const float* __restrict__ dww, const float* __restrict__ dwb,
                    const float* __restrict__ gg, const float* __restrict__ bb, unsigned short* __restrict__ out){
  int row=blockIdx.x, t=threadIdx.x;
  int bi=row>>10, n=row&1023;
  const float* base = h2 + (size_t)(bi<<10)*DD;
  float a[3];
  #pragma unroll
  for (int j=0;j<3;j++){
    int d=t+j*128;
    float acc=dwb[d];
    #pragma unroll
    for (int k=0;k<7;k++){
      int nn=n+k-3;
      if (nn>=0 && nn<NN) acc += dww[d*7+k]*base[(size_t)nn*DD + d];
    }
    a[j]=acc;
  }
  float s=a[0]+a[1]+a[2], q=a[0]*a[0]+a[1]*a[1]+a[2]*a[2];
  #pragma unroll
  for (int o=32;o>0;o>>=1){ s+=__shfl_down(s,o); q+=__shfl_down(q,o); }
  __shared__ float ls[2], lq[2];
  if ((t&63)==0){ ls[t>>6]=s; lq[t>>6]=q; }
  __syncthreads();
  float S=ls[0]+ls[1], Q=lq[0]+lq[1];
  float mean=S*(1.0f/DD);
  float rstd=rsqrtf(Q*(1.0f/DD)-mean*mean+1e-5f);
  unsigned short* o = out + (size_t)row*DD;
  #pragma unroll
  for (int j=0;j<3;j++){
    int d=t+j*128;
    o[d]=f2b((a[j]-mean)*rstd*gg[d]+bb[d]);
  }
}

// ================= LDS-staged bf16 MFMA GEMM, 128 x TN tile, BK=32, double-buffered =================
// MODE 0: qkv scatter: q,k -> fp8 planes in MFMA-FRAGMENT layout
//   qk8f[c][(bg)*64 + (n>>4)][lane=((d>>3)&3)*16 + (n&15)][byte=(d>>5)*8 + (d&7)]
//   v -> fp8 transposed V8[bg][d][m]
// MODE 1: out_f32 = resid + C   (proj / fc2)
// MODE 2: out_bf16 = gelu_exact(C)  (fc1)
template<int MODE, int TN>
__global__ __launch_bounds__(256)
void gemm_kernel(const unsigned short* __restrict__ A, const unsigned short* __restrict__ W,
                 const float* __restrict__ bias, const float* __restrict__ resid,
                 float* __restrict__ outf, unsigned short* __restrict__ outb,
                 unsigned char* __restrict__ qk8out, unsigned char* __restrict__ v8out,
                 int Kdim, int Ncols){
  constexpr int JF = TN/32;
  __shared__ __align__(16) unsigned short lds_a[2][128*32];
  __shared__ __align__(16) unsigned short lds_b[2][TN*32];
  int t=threadIdx.x, lane=t&63, w=t>>6;
  int bm = blockIdx.x*128;
  int bn = blockIdx.y*TN;
  int wr = w>>1, wc = w&1;
  int rm = lane&15, r16 = lane>>4;
  f32x4 acc[4][JF] = {};
  char* ldsa_c = (char*)lds_a;
  char* ldsb_c = (char*)lds_b;
  int abyte[4], bbyte[JF];
  #pragma unroll
  for (int i=0;i<4;i++){
    int ra = wr*64 + i*16 + rm;
    abyte[i] = ra*64 + ((r16 ^ ((ra>>1)&3))*16);
  }
  #pragma unroll
  for (int j=0;j<JF;j++){
    int rb = wc*(TN/2) + j*16 + rm;
    bbyte[j] = rb*64 + ((r16 ^ ((rb>>1)&3))*16);
  }
  auto stage = [&](int buf, int k0){
    #pragma unroll
    for (int c=0;c<2;c++){
      int u = t + c*256;
      int row = u>>2, sl = (u&3) ^ ((row>>1)&3);
      gload16(A + (size_t)(bm+row)*Kdim + k0 + sl*8, ldsa_c + buf*8192 + u*16);
    }
    #pragma unroll
    for (int c=0;c<TN/64;c++){
      int u = t + c*256;
      int row = u>>2, sl = (u&3) ^ ((row>>1)&3);
      gload16(W + (size_t)(bn+row)*Kdim + k0 + sl*8, ldsb_c + buf*(TN*64) + u*16);
    }
  };
  int niter = Kdim>>5;
  stage(0, 0);
  __syncthreads();
  for (int it=0; it<niter; ++it){
    if (it+1<niter) stage((it+1)&1, (it+1)<<5);
    int ab = (it&1)*8192, bb2 = (it&1)*(TN*64);
    short8 af[4], bf[JF];
    #pragma unroll
    for (int i=0;i<4;i++) af[i]=*reinterpret_cast<const short8*>(ldsa_c + ab + abyte[i]);
    #pragma unroll
    for (int j=0;j<JF;j++) bf[j]=*reinterpret_cast<const short8*>(ldsb_c + bb2 + bbyte[j]);
    #pragma unroll
    for (int i=0;i<4;i++)
      #pragma unroll
      for (int j=0;j<JF;j++)
        acc[i][j]=__builtin_amdgcn_mfma_f32_16x16x32_bf16(af[i],bf[j],acc[i][j],0,0,0);
    __syncthreads();
  }
  #pragma unroll
  for (int i=0;i<4;i++){
    #pragma unroll
    for (int j=0;j<JF;j++){
      #pragma unroll
      for (int r=0;r<4;r++){
        int row = bm + wr*64 + i*16 + r16*4 + r;
        int col = bn + wc*(TN/2) + j*16 + rm;
        float v = acc[i][j][r] + bias[col];
        if (MODE==0){
          int c = col/384; int rem = col - c*384; int hh = rem>>6, d = rem&63;
          int bi = row>>10, nn = row&1023;
          unsigned char pk = (unsigned char)(__builtin_amdgcn_cvt_pk_fp8_f32(v, v, 0, false) & 0xff);
          if (c==2){
            v8out[(((size_t)(bi*6+hh))<<16) + ((size_t)d<<10) + nn] = pk;
          } else {
            // fragment-order scatter: lane=((d>>3)&3)*16+(nn&15), byte=(d>>5)*8+(d&7)
            size_t fa = ((size_t)c*SEC)
                      + ((((size_t)(bi*6+hh))<<6) + (nn>>4))*1024
                      + ((((d>>3)&3)*16 + (nn&15))<<4) + ((d>>5)*8) + (d&7);
            qk8out[fa] = pk;
          }
        } else if (MODE==1){
          size_t idx = (size_t)row*Ncols + col;
          outf[idx] = resid[idx] + v;
        } else {
          float ge = 0.5f*v*(1.0f+erff(v*0.70710678118654752f));
          outb[(size_t)row*Ncols + col] = f2b(ge);
        }
      }
    }
  }
}

// ================= smx: E(fp8) = exp2(premix(Q8K8^T)·log2e·0.125), lpart[mh][bg][n] = partial rowsum =================
// NO LDS staging, NO main-loop barriers, NO atomics. block = (b, 16-row n-tile, m-quarter): 2048 blocks,
// 4 waves. Register-pipelined: kf for tile t+1 issued BEFORE tile t's MFMA+VALU (hides L2 latency).
// Fragments load directly from L2-resident frag-order planes. fp8 MFMA (A=K rows m, B=Q rows n).
// Partial l written with PLAIN STORES to disjoint [mh] slots (pure overwrite each call).
__global__ __launch_bounds__(256, 4)
void smx_kernel(const unsigned char* __restrict__ qk8, const float* __restrict__ tbm,
                unsigned char* __restrict__ E, float* __restrict__ lpart){
  __shared__ float lred[4][6][16];
  int t=threadIdx.x, lane=t&63, w=t>>6;
  int blk=blockIdx.x;
  int b = blk&7, nt = (blk>>3)&63, mh = blk>>9;   // mh in 0..3
  int n0 = nt*16, mbase = mh*256;
  int c16=lane&15, r16=lane>>4;
  const unsigned char* q8f = qk8;
  const unsigned char* k8f = qk8 + SEC;
  // Q fragments: one 16B per lane per head (constant over m)
  v2i64 qf[6];
  #pragma unroll
  for (int h=0;h<6;h++)
    qf[h] = *(const v2i64*)(q8f + (((((size_t)(b*6+h))<<6) + (n0>>4))<<10) + lane*16);
  float tbr[36];
  #pragma unroll
  for (int i=0;i<36;i++) tbr[i] = tbm[i]*0.125f*1.44269504088896f;  // fold HD^-0.5 + log2(e)
  float lsum[6]={0.f,0.f,0.f,0.f,0.f,0.f};
  auto loadK = [&](int m0, v2i64* dst){
    #pragma unroll
    for (int h=0;h<6;h++)
      dst[h] = *(const v2i64*)(k8f + (((((size_t)(b*6+h))<<6) + (m0>>4))<<10) + lane*16);
  };
  v2i64 kf[6], kfn[6];
  loadK(mbase + w*16, kf);
  #pragma unroll
  for (int mt=0; mt<4; ++mt){
    int m0 = mbase + mt*64 + w*16;      // this wave's 16-m group
    if (mt<3) loadK(m0+64, kfn);        // prefetch next tile: latency hides under MFMA+VALU below
    f32x4 aq[6] = {};
    #pragma unroll
    for (int h=0;h<6;h++){
      aq[h] = __builtin_amdgcn_mfma_f32_16x16x32_fp8_fp8(kf[h][0], qf[h][0], aq[h], 0,0,0);
      aq[h] = __builtin_amdgcn_mfma_f32_16x16x32_fp8_fp8(kf[h][1], qf[h][1], aq[h], 0,0,0);
    }
    float ef[6][4];
    #pragma unroll
    for (int r=0;r<4;r++){
      float s0=aq[0][r], s1=aq[1][r], s2=aq[2][r],
            s3=aq[3][r], s4=aq[4][r], s5=aq[5][r];
      #pragma unroll
      for (int g=0;g<6;g++){
        float sm = tbr[g*6]*s0 + tbr[g*6+1]*s1 + tbr[g*6+2]*s2
                 + tbr[g*6+3]*s3 + tbr[g*6+4]*s4 + tbr[g*6+5]*s5;
        float e = __builtin_amdgcn_exp2f(sm);
        ef[g][r] = e;
        lsum[g] += e;
      }
    }
    #pragma unroll
    for (int g=0;g<6;g++){
      int pkv = __builtin_amdgcn_cvt_pk_fp8_f32(ef[g][0], ef[g][1], 0, false);
      pkv = __builtin_amdgcn_cvt_pk_fp8_f32(ef[g][2], ef[g][3], pkv, true);
      *(unsigned int*)(E + (((size_t)(b*6+g))<<20) + ((size_t)(n0+c16)<<10) + m0 + r16*4)
        = (unsigned int)pkv;
    }
    #pragma unroll
    for (int h=0;h<6;h++) kf[h] = kfn[h];
  }
  // l reduction: in-wave over r16, cross-wave via LDS, one plain store per (mh,g,n)
  #pragma unroll
  for (int g=0;g<6;g++){
    lsum[g] += __shfl_xor(lsum[g],16);
    lsum[g] += __shfl_xor(lsum[g],32);
  }
  if (r16==0){
    #pragma unroll
    for (int g=0;g<6;g++) lred[w][g][c16] = lsum[g];
  }
  __syncthreads();
  if (w==0 && r16==0){
    #pragma unroll
    for (int g=0;g<6;g++){
      float l = lred[0][g][c16]+lred[1][g][c16]+lred[2][g][c16]+lred[3][g][c16];
      lpart[(((size_t)(mh*48 + b*6+g))<<10) + n0 + c16] = l;
    }
  }
}

// ================= pvmix: out[n,g*64+d] = (1/256) sum_m (sum_h ta[g,h]*(256/l[h,n])*E[h,n,m]) * V8[g,d,m] =================
// block = (b, 16-row n-tile): 512 blocks, 4 waves (d-quarters). l = sum of 4 lpart slots.
__global__ __launch_bounds__(256, 2)
void pvmix_kernel(const unsigned char* __restrict__ E, const unsigned char* __restrict__ V8,
                  const float* __restrict__ lpart, const float* __restrict__ tam,
                  unsigned short* __restrict__ outp){
  __shared__ __align__(16) unsigned char Es[6*16*64];    // 6 KB
  __shared__ __align__(16) unsigned char Vs[6*64*64];    // 24 KB
  __shared__ __align__(16) unsigned char pms[6*16*64];   // 6 KB
  int t=threadIdx.x, lane=t&63, w=t>>6;
  int b = blockIdx.x&7, nt = blockIdx.x>>3;
  int n0 = nt*16;
  int c16 = lane&15, r16 = lane>>4;
  int mn = t&15, mg = (t>>4)&7, gh = t>>7;
  float cf[3][6];
  #pragma unroll
  for (int g=0;g<6;g++){
    float l = 0.f;
    #pragma unroll
    for (int mh=0;mh<4;mh++)
      l += lpart[(((size_t)(mh*48 + b*6+g))<<10) + n0 + mn];
    float iv = 256.0f/l;
    #pragma unroll
    for (int j=0;j<3;j++) cf[j][g] = tam[(gh*3+j)*6 + g]*iv;
  }
  auto stageE = [&](int m0){
    #pragma unroll
    for (int i=0;i<2;i++){
      int u = t + i*256;
      if (u<384){
        int r = u>>2, s = (u&3) ^ (r&3);
        int g = r>>4, n = r&15;
        gload16(E + (((size_t)(b*6+g))<<20) + ((size_t)(n0+n)<<10) + m0 + s*16,
                (char*)Es + u*16);
      }
    }
  };
  auto stageV = [&](int m0){
    #pragma unroll
    for (int i=0;i<6;i++){
      int u = t + i*256;
      int r = u>>2, s = (u&3) ^ (r&3);
      int g = r>>6, d = r&63;
      gload16(V8 + (((size_t)(b*6+g))<<16) + ((size_t)d<<10) + m0 + s*16,
              (char*)Vs + u*16);
    }
  };
  stageE(0); stageV(0);
  __syncthreads();
  f32x4 acc[6] = {};
  for (int mt=0; mt<16; ++mt){
    // ---- MIX: Es -> pms ----
    float e[6][8];
    #pragma unroll
    for (int g=0;g<6;g++){
      int row = g*16 + mn;
      int byteo = row*64 + ((mg*8) ^ ((row&3)<<4));
      unsigned int lo = *(const unsigned int*)(Es + byteo);
      unsigned int hi = *(const unsigned int*)(Es + byteo + 4);
      f32x2 p0 = __builtin_amdgcn_cvt_pk_f32_fp8(lo, false);
      f32x2 p1 = __builtin_amdgcn_cvt_pk_f32_fp8(lo, true);
      f32x2 p2 = __builtin_amdgcn_cvt_pk_f32_fp8(hi, false);
      f32x2 p3 = __builtin_amdgcn_cvt_pk_f32_fp8(hi, true);
      e[g][0]=p0.x; e[g][1]=p0.y; e[g][2]=p1.x; e[g][3]=p1.y;
      e[g][4]=p2.x; e[g][5]=p2.y; e[g][6]=p3.x; e[g][7]=p3.y;
    }
    #pragma unroll
    for (int j=0;j<3;j++){
      float pm[8];
      #pragma unroll
      for (int m=0;m<8;m++)
        pm[m] = cf[j][0]*e[0][m]+cf[j][1]*e[1][m]+cf[j][2]*e[2][m]
              + cf[j][3]*e[3][m]+cf[j][4]*e[4][m]+cf[j][5]*e[5][m];
      int d0 = __builtin_amdgcn_cvt_pk_fp8_f32(pm[0], pm[1], 0, false);
      d0 = __builtin_amdgcn_cvt_pk_fp8_f32(pm[2], pm[3], d0, true);
      int d1 = __builtin_amdgcn_cvt_pk_fp8_f32(pm[4], pm[5], 0, false);
      d1 = __builtin_amdgcn_cvt_pk_fp8_f32(pm[6], pm[7], d1, true);
      int prow = (gh*3+j)*16 + mn;
      int pbyte = prow*64 + ((mg*8) ^ ((mn&7)<<3));
      *(unsigned int*)(pms + pbyte)     = (unsigned int)d0;
      *(unsigned int*)(pms + pbyte + 4) = (unsigned int)d1;
    }
    __syncthreads();                 // pms visible; Es reads done
    if (mt<15) stageE((mt+1)*64);
    // ---- MFMA: pm x V8 ----
    #pragma unroll
    for (int g=0;g<6;g++){
      int arow = g*16 + c16;
      int vrow = g*64 + w*16 + c16;
      #pragma unroll
      for (int kk=0;kk<2;kk++){
        long af = *(const long*)(pms + arow*64 + ((kk*32 + r16*8) ^ ((c16&7)<<3)));
        long bf = *(const long*)(Vs + vrow*64
                   + ((((kk*2 + (r16>>1)) ^ (vrow&3))<<4) + ((r16&1)<<3)));
        acc[g] = __builtin_amdgcn_mfma_f32_16x16x32_fp8_fp8(af, bf, acc[g], 0,0,0);
      }
    }
    __syncthreads();                 // pms/Vs reads done
    if (mt<15) stageV((mt+1)*64);
  }
  #pragma unroll
  for (int g=0;g<6;g++)
    #pragma unroll
    for (int r=0;r<4;r++){
      int n = n0 + r16*4 + r;
      int d = g*64 + w*16 + c16;
      outp[((size_t)(b*1024 + n))*DD + d] = f2b(acc[g][r] * 0.00390625f);
    }
}

extern "C" void kernel_launch(void* const* d_in, const int* in_sizes, int n_in,
                              void* d_out, int out_size, void* d_ws, size_t ws_size,
                              hipStream_t stream){
  const float* x      = (const float*)d_in[0];
  const float* qkv_w  = (const float*)d_in[1];
  const float* qkv_b  = (const float*)d_in[2];
  const float* proj_w = (const float*)d_in[3];
  const float* proj_b = (const float*)d_in[4];
  const float* t_before=(const float*)d_in[5];
  const float* t_after =(const float*)d_in[6];
  const float* dw_w   = (const float*)d_in[7];
  const float* dw_b   = (const float*)d_in[8];
  const float* mlp_g  = (const float*)d_in[9];
  const float* mlp_b  = (const float*)d_in[10];
  const float* n1_g   = (const float*)d_in[11];
  const float* n1_b   = (const float*)d_in[12];
  const float* n2_g   = (const float*)d_in[13];
  const float* n2_b   = (const float*)d_in[14];
  const float* fc1_w  = (const float*)d_in[15];
  const float* fc1_b  = (const float*)d_in[16];
  const float* fc2_w  = (const float*)d_in[17];
  const float* fc2_b  = (const float*)d_in[18];
  float* out = (float*)d_out;
  char* ws = (char*)d_ws;
  unsigned short* qkvwb = (unsigned short*)(ws + 0);          // 1152*384 bf16
  unsigned short* projwb= (unsigned short*)(ws + 884736);
  unsigned short* fc1wb = (unsigned short*)(ws + 1179648);
  unsigned short* fc2wb = (unsigned short*)(ws + 2359296);
  unsigned short* hb    = (unsigned short*)(ws + 3538944);    // 8192*384 bf16 (reuse: hcln)
  unsigned char*  qk8   = (unsigned char*) (ws + 9830400);    // q8f,k8f fp8 frag planes (reuse: h2 f32)
  unsigned char*  V8    = (unsigned char*) (ws + 28704768);   // 48*64*1024 fp8
  float*          lpart = (float*)        (ws + 31850496);    // 4*48*1024 f32 partial l-sums
  unsigned char*  Ebuf  = (unsigned char*) (ws + 34996224);   // 48MB fp8 E (reuse: fc1o)
  unsigned short* attnb = (unsigned short*)(ws + 85327872);   // 8192*384 bf16
  float*          x2    = (float*)(ws + 91619328);            // 8192*384 f32
  float* h2 = (float*)qk8;
  unsigned short* hcln = hb;
  unsigned short* fc1o = (unsigned short*)Ebuf;

  cvt_kernel<<<6912,256,0,stream>>>(qkv_w, proj_w, fc1_w, fc2_w, qkvwb);

  ln_kernel<1><<<BN,128,0,stream>>>(x, n1_g, n1_b, nullptr, hb);
  { dim3 g(BN/128, D3/128); gemm_kernel<0,128><<<g,256,0,stream>>>(hb, qkvwb, qkv_b, nullptr, nullptr, nullptr, qk8, V8, DD, D3); }
  smx_kernel<<<2048,256,0,stream>>>(qk8, t_before, Ebuf, lpart);
  pvmix_kernel<<<512,256,0,stream>>>(Ebuf, V8, lpart, t_after, attnb);
  { dim3 g(BN/128, DD/64); gemm_kernel<1,64><<<g,256,0,stream>>>(attnb, projwb, proj_b, x, x2, nullptr, nullptr, nullptr, DD, DD); }
  ln_kernel<0><<<BN,128,0,stream>>>(x2, n2_g, n2_b, h2, nullptr);
  conv_ln_kernel<<<BN,128,0,stream>>>(h2, dw_w, dw_b, mlp_g, mlp_b, hcln);
  { dim3 g(BN/128, D4/128); gemm_kernel<2,128><<<g,256,0,stream>>>(hcln, fc1wb, fc1_b, nullptr, nullptr, fc1o, nullptr, nullptr, DD, D4); }
  { dim3 g(BN/128, DD/64); gemm_kernel<1,64><<<g,256,0,stream>>>(fc1o, fc2wb, fc2_b, x2, out, nullptr, nullptr, nullptr, D4, DD); }
}

// Round 17
// 194.677 us; speedup vs baseline: 1.1869x; 1.1869x over previous
//
#include <hip/hip_runtime.h>
#include <hip/hip_bf16.h>

#define BB 8
#define NN 1024
#define DD 384
#define HH 6
#define HD 64
#define BN 8192          // B*N rows
#define D3 1152          // 3*D
#define D4 1536          // 4*D
#define SEC 3145728      // B*H*N*HD elems per plane

typedef __attribute__((ext_vector_type(8))) short short8;
typedef __attribute__((ext_vector_type(4))) float f32x4;
typedef __attribute__((ext_vector_type(2))) float f32x2;
typedef long v2i64 __attribute__((ext_vector_type(2)));

typedef __attribute__((address_space(3))) unsigned char as3_byte;
typedef __attribute__((address_space(1))) const unsigned char as1_byte;

__device__ __forceinline__ void gload16(const void* g, void* l){
  __builtin_amdgcn_global_load_lds((as1_byte*)g, (as3_byte*)l, 16, 0, 0);
}

__device__ __forceinline__ float b2f(unsigned short u){
  union{unsigned int i; float f;} x; x.i=((unsigned int)u)<<16; return x.f;
}
__device__ __forceinline__ unsigned short f2b(float f){
  unsigned int u=__float_as_uint(f);
  return (unsigned short)((u + 0x7FFFu + ((u>>16)&1u))>>16);
}

// ---------------- fp32 -> bf16 weight convert (all 4 weights), one launch ----------------
__global__ void cvt_kernel(const float* __restrict__ w0, const float* __restrict__ w1,
                           const float* __restrict__ w2, const float* __restrict__ w3,
                           unsigned short* __restrict__ out){
  int i = blockIdx.x*256 + threadIdx.x;
  if (i < 442368)        out[i] = f2b(w0[i]);
  else if (i < 589824)   out[i] = f2b(w1[i - 442368]);
  else if (i < 1179648)  out[i] = f2b(w2[i - 589824]);
  else if (i < 1769472)  out[i] = f2b(w3[i - 1179648]);
}

// ---------------- LayerNorm over D=384, one block per row (bf16 out) ----------------
__global__ __launch_bounds__(128)
void ln_kernel(const float* __restrict__ in, const float* __restrict__ gg, const float* __restrict__ bb,
               unsigned short* __restrict__ outb){
  int row = blockIdx.x, t = threadIdx.x;
  const float* r = in + (size_t)row*DD;
  float v0=r[t], v1=r[t+128], v2=r[t+256];
  float s=v0+v1+v2, q=v0*v0+v1*v1+v2*v2;
  #pragma unroll
  for (int o=32;o>0;o>>=1){ s+=__shfl_down(s,o); q+=__shfl_down(q,o); }
  __shared__ float ls[2], lq[2];
  if ((t&63)==0){ ls[t>>6]=s; lq[t>>6]=q; }
  __syncthreads();
  float S=ls[0]+ls[1], Q=lq[0]+lq[1];
  float mean=S*(1.0f/DD);
  float rstd=rsqrtf(Q*(1.0f/DD)-mean*mean+1e-5f);
  unsigned short* o=outb+(size_t)row*DD;
  o[t]    =f2b((v0-mean)*rstd*gg[t]+bb[t]);
  o[t+128]=f2b((v1-mean)*rstd*gg[t+128]+bb[t+128]);
  o[t+256]=f2b((v2-mean)*rstd*gg[t+256]+bb[t+256]);
}

// ---------------- depthwise conv1d (K=7, same) + bias + LayerNorm, bf16 in/out ----------------
__global__ __launch_bounds__(128)
void conv_ln_kernel(const unsigned short* __restrict__ h2, const float* __restrict__ dww, const float* __restrict__ dwb,
                    const float* __restrict__ gg, const float* __restrict__ bb, unsigned short* __restrict__ out){
  int row=blockIdx.x, t=threadIdx.x;
  int bi=row>>10, n=row&1023;
  const unsigned short* base = h2 + (size_t)(bi<<10)*DD;
  float a[3];
  #pragma unroll
  for (int j=0;j<3;j++){
    int d=t+j*128;
    float acc=dwb[d];
    #pragma unroll
    for (int k=0;k<7;k++){
      int nn=n+k-3;
      if (nn>=0 && nn<NN) acc += dww[d*7+k]*b2f(base[(size_t)nn*DD + d]);
    }
    a[j]=acc;
  }
  float s=a[0]+a[1]+a[2], q=a[0]*a[0]+a[1]*a[1]+a[2]*a[2];
  #pragma unroll
  for (int o=32;o>0;o>>=1){ s+=__shfl_down(s,o); q+=__shfl_down(q,o); }
  __shared__ float ls[2], lq[2];
  if ((t&63)==0){ ls[t>>6]=s; lq[t>>6]=q; }
  __syncthreads();
  float S=ls[0]+ls[1], Q=lq[0]+lq[1];
  float mean=S*(1.0f/DD);
  float rstd=rsqrtf(Q*(1.0f/DD)-mean*mean+1e-5f);
  unsigned short* o = out + (size_t)row*DD;
  #pragma unroll
  for (int j=0;j<3;j++){
    int d=t+j*128;
    o[d]=f2b((a[j]-mean)*rstd*gg[d]+bb[d]);
  }
}

// ================= LDS-staged bf16 MFMA GEMM, 128 x TN tile, BK=32, double-buffered =================
// MODE 0: qkv scatter: q,k -> fp8 planes in MFMA-FRAGMENT layout
//   qk8f[c][(bg)*64 + (n>>4)][lane=((d>>3)&3)*16 + (n&15)][byte=(d>>5)*8 + (d&7)]
//   v -> fp8 transposed V8[bg][d][m]
// MODE 1: out_f32 = resid + C   (proj / fc2)
// MODE 2: out_bf16 = gelu_exact(C)  (fc1)
template<int MODE, int TN>
__global__ __launch_bounds__(256)
void gemm_kernel(const unsigned short* __restrict__ A, const unsigned short* __restrict__ W,
                 const float* __restrict__ bias, const float* __restrict__ resid,
                 float* __restrict__ outf, unsigned short* __restrict__ outb,
                 unsigned char* __restrict__ qk8out, unsigned char* __restrict__ v8out,
                 int Kdim, int Ncols){
  constexpr int JF = TN/32;
  __shared__ __align__(16) unsigned short lds_a[2][128*32];
  __shared__ __align__(16) unsigned short lds_b[2][TN*32];
  int t=threadIdx.x, lane=t&63, w=t>>6;
  int bm = blockIdx.x*128;
  int bn = blockIdx.y*TN;
  int wr = w>>1, wc = w&1;
  int rm = lane&15, r16 = lane>>4;
  f32x4 acc[4][JF] = {};
  char* ldsa_c = (char*)lds_a;
  char* ldsb_c = (char*)lds_b;
  int abyte[4], bbyte[JF];
  #pragma unroll
  for (int i=0;i<4;i++){
    int ra = wr*64 + i*16 + rm;
    abyte[i] = ra*64 + ((r16 ^ ((ra>>1)&3))*16);
  }
  #pragma unroll
  for (int j=0;j<JF;j++){
    int rb = wc*(TN/2) + j*16 + rm;
    bbyte[j] = rb*64 + ((r16 ^ ((rb>>1)&3))*16);
  }
  auto stage = [&](int buf, int k0){
    #pragma unroll
    for (int c=0;c<2;c++){
      int u = t + c*256;
      int row = u>>2, sl = (u&3) ^ ((row>>1)&3);
      gload16(A + (size_t)(bm+row)*Kdim + k0 + sl*8, ldsa_c + buf*8192 + u*16);
    }
    #pragma unroll
    for (int c=0;c<TN/64;c++){
      int u = t + c*256;
      int row = u>>2, sl = (u&3) ^ ((row>>1)&3);
      gload16(W + (size_t)(bn+row)*Kdim + k0 + sl*8, ldsb_c + buf*(TN*64) + u*16);
    }
  };
  int niter = Kdim>>5;
  stage(0, 0);
  __syncthreads();
  for (int it=0; it<niter; ++it){
    if (it+1<niter) stage((it+1)&1, (it+1)<<5);
    int ab = (it&1)*8192, bb2 = (it&1)*(TN*64);
    short8 af[4], bf[JF];
    #pragma unroll
    for (int i=0;i<4;i++) af[i]=*reinterpret_cast<const short8*>(ldsa_c + ab + abyte[i]);
    #pragma unroll
    for (int j=0;j<JF;j++) bf[j]=*reinterpret_cast<const short8*>(ldsb_c + bb2 + bbyte[j]);
    #pragma unroll
    for (int i=0;i<4;i++)
      #pragma unroll
      for (int j=0;j<JF;j++)
        acc[i][j]=__builtin_amdgcn_mfma_f32_16x16x32_bf16(af[i],bf[j],acc[i][j],0,0,0);
    __syncthreads();
  }
  #pragma unroll
  for (int i=0;i<4;i++){
    #pragma unroll
    for (int j=0;j<JF;j++){
      #pragma unroll
      for (int r=0;r<4;r++){
        int row = bm + wr*64 + i*16 + r16*4 + r;
        int col = bn + wc*(TN/2) + j*16 + rm;
        float v = acc[i][j][r] + bias[col];
        if (MODE==0){
          int c = col/384; int rem = col - c*384; int hh = rem>>6, d = rem&63;
          int bi = row>>10, nn = row&1023;
          unsigned char pk = (unsigned char)(__builtin_amdgcn_cvt_pk_fp8_f32(v, v, 0, false) & 0xff);
          if (c==2){
            v8out[(((size_t)(bi*6+hh))<<16) + ((size_t)d<<10) + nn] = pk;
          } else {
            // fragment-order scatter: lane=((d>>3)&3)*16+(nn&15), byte=(d>>5)*8+(d&7)
            size_t fa = ((size_t)c*SEC)
                      + ((((size_t)(bi*6+hh))<<6) + (nn>>4))*1024
                      + ((((d>>3)&3)*16 + (nn&15))<<4) + ((d>>5)*8) + (d&7);
            qk8out[fa] = pk;
          }
        } else if (MODE==1){
          size_t idx = (size_t)row*Ncols + col;
          outf[idx] = resid[idx] + v;
        } else {
          float ge = 0.5f*v*(1.0f+erff(v*0.70710678118654752f));
          outb[(size_t)row*Ncols + col] = f2b(ge);
        }
      }
    }
  }
}

// ================= smx: E(fp8) = exp2(premix(Q8K8^T)·log2e·0.125), lpart[mh][bg][n] = partial rowsum =================
// NO LDS staging, NO main-loop barriers, NO atomics. block = (b, 16-row n-tile, m-half): 1024 blocks, 4 waves.
// Wave w owns m-slice w*16 of each 64-m tile. Fragments load directly from L2-resident
// frag-order planes (one coalesced 16B load per lane per head). fp8 MFMA (A=K rows m, B=Q rows n).
// Partial l written with PLAIN STORES to disjoint [mh] slots (pure overwrite each call).
__global__ __launch_bounds__(256, 4)
void smx_kernel(const unsigned char* __restrict__ qk8, const float* __restrict__ tbm,
                unsigned char* __restrict__ E, float* __restrict__ lpart){
  __shared__ float lred[4][6][16];
  int t=threadIdx.x, lane=t&63, w=t>>6;
  int blk=blockIdx.x;
  int b = blk&7, nt = (blk>>3)&63, mh = blk>>9;
  int n0 = nt*16, mbase = mh*512;
  int c16=lane&15, r16=lane>>4;
  const unsigned char* q8f = qk8;
  const unsigned char* k8f = qk8 + SEC;
  // Q fragments: one 16B per lane per head (constant over m)
  v2i64 qf[6];
  #pragma unroll
  for (int h=0;h<6;h++)
    qf[h] = *(const v2i64*)(q8f + (((((size_t)(b*6+h))<<6) + (n0>>4))<<10) + lane*16);
  float tbr[36];
  #pragma unroll
  for (int i=0;i<36;i++) tbr[i] = tbm[i]*0.125f*1.44269504088896f;  // fold HD^-0.5 + log2(e)
  float lsum[6]={0.f,0.f,0.f,0.f,0.f,0.f};
  for (int mt=0; mt<8; ++mt){
    int m0 = mbase + mt*64 + w*16;      // this wave's 16-m group
    v2i64 kf[6];
    #pragma unroll
    for (int h=0;h<6;h++)
      kf[h] = *(const v2i64*)(k8f + (((((size_t)(b*6+h))<<6) + (m0>>4))<<10) + lane*16);
    f32x4 aq[6] = {};
    #pragma unroll
    for (int h=0;h<6;h++){
      aq[h] = __builtin_amdgcn_mfma_f32_16x16x32_fp8_fp8(kf[h][0], qf[h][0], aq[h], 0,0,0);
      aq[h] = __builtin_amdgcn_mfma_f32_16x16x32_fp8_fp8(kf[h][1], qf[h][1], aq[h], 0,0,0);
    }
    float ef[6][4];
    #pragma unroll
    for (int r=0;r<4;r++){
      float s0=aq[0][r], s1=aq[1][r], s2=aq[2][r],
            s3=aq[3][r], s4=aq[4][r], s5=aq[5][r];
      #pragma unroll
      for (int g=0;g<6;g++){
        float sm = tbr[g*6]*s0 + tbr[g*6+1]*s1 + tbr[g*6+2]*s2
                 + tbr[g*6+3]*s3 + tbr[g*6+4]*s4 + tbr[g*6+5]*s5;
        float e = __builtin_amdgcn_exp2f(sm);
        ef[g][r] = e;
        lsum[g] += e;
      }
    }
    #pragma unroll
    for (int g=0;g<6;g++){
      int pkv = __builtin_amdgcn_cvt_pk_fp8_f32(ef[g][0], ef[g][1], 0, false);
      pkv = __builtin_amdgcn_cvt_pk_fp8_f32(ef[g][2], ef[g][3], pkv, true);
      *(unsigned int*)(E + (((size_t)(b*6+g))<<20) + ((size_t)(n0+c16)<<10) + m0 + r16*4)
        = (unsigned int)pkv;
    }
  }
  // l reduction: in-wave over r16, cross-wave via LDS, one plain store per (mh,g,n)
  #pragma unroll
  for (int g=0;g<6;g++){
    lsum[g] += __shfl_xor(lsum[g],16);
    lsum[g] += __shfl_xor(lsum[g],32);
  }
  if (r16==0){
    #pragma unroll
    for (int g=0;g<6;g++) lred[w][g][c16] = lsum[g];
  }
  __syncthreads();
  if (w==0 && r16==0){
    #pragma unroll
    for (int g=0;g<6;g++){
      float l = lred[0][g][c16]+lred[1][g][c16]+lred[2][g][c16]+lred[3][g][c16];
      lpart[(((size_t)(mh*48 + b*6+g))<<10) + n0 + c16] = l;
    }
  }
}

// ================= pvmix: out[n,g*64+d] = (1/256) sum_m (sum_h ta[g,h]*(256/l[h,n])*E[h,n,m]) * V8[g,d,m] =================
// block = (b, 16-row n-tile): 512 blocks, 4 waves (d-quarters), 2 blocks/CU. l = lpart[0]+lpart[1].
__global__ __launch_bounds__(256, 2)
void pvmix_kernel(const unsigned char* __restrict__ E, const unsigned char* __restrict__ V8,
                  const float* __restrict__ lpart, const float* __restrict__ tam,
                  unsigned short* __restrict__ outp){
  __shared__ __align__(16) unsigned char Es[6*16*64];    // 6 KB
  __shared__ __align__(16) unsigned char Vs[6*64*64];    // 24 KB
  __shared__ __align__(16) unsigned char pms[6*16*64];   // 6 KB
  int t=threadIdx.x, lane=t&63, w=t>>6;
  int b = blockIdx.x&7, nt = blockIdx.x>>3;
  int n0 = nt*16;
  int c16 = lane&15, r16 = lane>>4;
  int mn = t&15, mg = (t>>4)&7, gh = t>>7;
  float cf[3][6];
  #pragma unroll
  for (int g=0;g<6;g++){
    float l0 = lpart[(((size_t)(b*6+g))<<10) + n0 + mn];
    float l1 = lpart[(((size_t)(48 + b*6+g))<<10) + n0 + mn];
    float iv = 256.0f/(l0 + l1);
    #pragma unroll
    for (int j=0;j<3;j++) cf[j][g] = tam[(gh*3+j)*6 + g]*iv;
  }
  auto stageE = [&](int m0){
    #pragma unroll
    for (int i=0;i<2;i++){
      int u = t + i*256;
      if (u<384){
        int r = u>>2, s = (u&3) ^ (r&3);
        int g = r>>4, n = r&15;
        gload16(E + (((size_t)(b*6+g))<<20) + ((size_t)(n0+n)<<10) + m0 + s*16,
                (char*)Es + u*16);
      }
    }
  };
  auto stageV = [&](int m0){
    #pragma unroll
    for (int i=0;i<6;i++){
      int u = t + i*256;
      int r = u>>2, s = (u&3) ^ (r&3);
      int g = r>>6, d = r&63;
      gload16(V8 + (((size_t)(b*6+g))<<16) + ((size_t)d<<10) + m0 + s*16,
              (char*)Vs + u*16);
    }
  };
  stageE(0); stageV(0);
  __syncthreads();
  f32x4 acc[6] = {};
  for (int mt=0; mt<16; ++mt){
    // ---- MIX: Es -> pms ----
    float e[6][8];
    #pragma unroll
    for (int g=0;g<6;g++){
      int row = g*16 + mn;
      int byteo = row*64 + ((mg*8) ^ ((row&3)<<4));
      unsigned int lo = *(const unsigned int*)(Es + byteo);
      unsigned int hi = *(const unsigned int*)(Es + byteo + 4);
      f32x2 p0 = __builtin_amdgcn_cvt_pk_f32_fp8(lo, false);
      f32x2 p1 = __builtin_amdgcn_cvt_pk_f32_fp8(lo, true);
      f32x2 p2 = __builtin_amdgcn_cvt_pk_f32_fp8(hi, false);
      f32x2 p3 = __builtin_amdgcn_cvt_pk_f32_fp8(hi, true);
      e[g][0]=p0.x; e[g][1]=p0.y; e[g][2]=p1.x; e[g][3]=p1.y;
      e[g][4]=p2.x; e[g][5]=p2.y; e[g][6]=p3.x; e[g][7]=p3.y;
    }
    #pragma unroll
    for (int j=0;j<3;j++){
      float pm[8];
      #pragma unroll
      for (int m=0;m<8;m++)
        pm[m] = cf[j][0]*e[0][m]+cf[j][1]*e[1][m]+cf[j][2]*e[2][m]
              + cf[j][3]*e[3][m]+cf[j][4]*e[4][m]+cf[j][5]*e[5][m];
      int d0 = __builtin_amdgcn_cvt_pk_fp8_f32(pm[0], pm[1], 0, false);
      d0 = __builtin_amdgcn_cvt_pk_fp8_f32(pm[2], pm[3], d0, true);
      int d1 = __builtin_amdgcn_cvt_pk_fp8_f32(pm[4], pm[5], 0, false);
      d1 = __builtin_amdgcn_cvt_pk_fp8_f32(pm[6], pm[7], d1, true);
      int prow = (gh*3+j)*16 + mn;
      int pbyte = prow*64 + ((mg*8) ^ ((mn&7)<<3));
      *(unsigned int*)(pms + pbyte)     = (unsigned int)d0;
      *(unsigned int*)(pms + pbyte + 4) = (unsigned int)d1;
    }
    __syncthreads();                 // pms visible; Es reads done
    if (mt<15) stageE((mt+1)*64);
    // ---- MFMA: pm x V8 ----
    #pragma unroll
    for (int g=0;g<6;g++){
      int arow = g*16 + c16;
      int vrow = g*64 + w*16 + c16;
      #pragma unroll
      for (int kk=0;kk<2;kk++){
        long af = *(const long*)(pms + arow*64 + ((kk*32 + r16*8) ^ ((c16&7)<<3)));
        long bf = *(const long*)(Vs + vrow*64
                   + ((((kk*2 + (r16>>1)) ^ (vrow&3))<<4) + ((r16&1)<<3)));
        acc[g] = __builtin_amdgcn_mfma_f32_16x16x32_fp8_fp8(af, bf, acc[g], 0,0,0);
      }
    }
    __syncthreads();                 // pms/Vs reads done
    if (mt<15) stageV((mt+1)*64);
  }
  #pragma unroll
  for (int g=0;g<6;g++)
    #pragma unroll
    for (int r=0;r<4;r++){
      int n = n0 + r16*4 + r;
      int d = g*64 + w*16 + c16;
      outp[((size_t)(b*1024 + n))*DD + d] = f2b(acc[g][r] * 0.00390625f);
    }
}

extern "C" void kernel_launch(void* const* d_in, const int* in_sizes, int n_in,
                              void* d_out, int out_size, void* d_ws, size_t ws_size,
                              hipStream_t stream){
  const float* x      = (const float*)d_in[0];
  const float* qkv_w  = (const float*)d_in[1];
  const float* qkv_b  = (const float*)d_in[2];
  const float* proj_w = (const float*)d_in[3];
  const float* proj_b = (const float*)d_in[4];
  const float* t_before=(const float*)d_in[5];
  const float* t_after =(const float*)d_in[6];
  const float* dw_w   = (const float*)d_in[7];
  const float* dw_b   = (const float*)d_in[8];
  const float* mlp_g  = (const float*)d_in[9];
  const float* mlp_b  = (const float*)d_in[10];
  const float* n1_g   = (const float*)d_in[11];
  const float* n1_b   = (const float*)d_in[12];
  const float* n2_g   = (const float*)d_in[13];
  const float* n2_b   = (const float*)d_in[14];
  const float* fc1_w  = (const float*)d_in[15];
  const float* fc1_b  = (const float*)d_in[16];
  const float* fc2_w  = (const float*)d_in[17];
  const float* fc2_b  = (const float*)d_in[18];
  float* out = (float*)d_out;
  char* ws = (char*)d_ws;
  unsigned short* qkvwb = (unsigned short*)(ws + 0);          // 1152*384 bf16
  unsigned short* projwb= (unsigned short*)(ws + 884736);
  unsigned short* fc1wb = (unsigned short*)(ws + 1179648);
  unsigned short* fc2wb = (unsigned short*)(ws + 2359296);
  unsigned short* hb    = (unsigned short*)(ws + 3538944);    // 8192*384 bf16 (reuse: hcln)
  unsigned char*  qk8   = (unsigned char*) (ws + 9830400);    // q8f,k8f fp8 frag planes (reuse: h2 bf16)
  unsigned char*  V8    = (unsigned char*) (ws + 28704768);   // 48*64*1024 fp8
  float*          lpart = (float*)        (ws + 31850496);    // 2*48*1024 f32 partial l-sums
  unsigned char*  Ebuf  = (unsigned char*) (ws + 34996224);   // 48MB fp8 E (reuse: fc1o)
  unsigned short* attnb = (unsigned short*)(ws + 85327872);   // 8192*384 bf16
  float*          x2    = (float*)(ws + 91619328);            // 8192*384 f32
  unsigned short* h2 = (unsigned short*)qk8;
  unsigned short* hcln = hb;
  unsigned short* fc1o = (unsigned short*)Ebuf;

  cvt_kernel<<<6912,256,0,stream>>>(qkv_w, proj_w, fc1_w, fc2_w, qkvwb);

  ln_kernel<<<BN,128,0,stream>>>(x, n1_g, n1_b, hb);
  { dim3 g(BN/128, D3/128); gemm_kernel<0,128><<<g,256,0,stream>>>(hb, qkvwb, qkv_b, nullptr, nullptr, nullptr, qk8, V8, DD, D3); }
  smx_kernel<<<1024,256,0,stream>>>(qk8, t_before, Ebuf, lpart);
  pvmix_kernel<<<512,256,0,stream>>>(Ebuf, V8, lpart, t_after, attnb);
  { dim3 g(BN/128, DD/64); gemm_kernel<1,64><<<g,256,0,stream>>>(attnb, projwb, proj_b, x, x2, nullptr, nullptr, nullptr, DD, DD); }
  ln_kernel<<<BN,128,0,stream>>>(x2, n2_g, n2_b, h2);
  conv_ln_kernel<<<BN,128,0,stream>>>(h2, dw_w, dw_b, mlp_g, mlp_b, hcln);
  { dim3 g(BN/128, D4/128); gemm_kernel<2,128><<<g,256,0,stream>>>(hcln, fc1wb, fc1_b, nullptr, nullptr, fc1o, nullptr, nullptr, DD, D4); }
  { dim3 g(BN/128, DD/64); gemm_kernel<1,64><<<g,256,0,stream>>>(fc1o, fc2wb, fc2_b, x2, out, nullptr, nullptr, nullptr, D4, DD); }
}

// Round 18
// 192.920 us; speedup vs baseline: 1.1977x; 1.0091x over previous
//
#include <hip/hip_runtime.h>
#include <hip/hip_bf16.h>

#define BB 8
#define NN 1024
#define DD 384
#define HH 6
#define HD 64
#define BN 8192          // B*N rows
#define D3 1152          // 3*D
#define D4 1536          // 4*D
#define SEC 3145728      // B*H*N*HD elems per plane

typedef __attribute__((ext_vector_type(8))) short short8;
typedef __attribute__((ext_vector_type(4))) float f32x4;
typedef __attribute__((ext_vector_type(2))) float f32x2;
typedef long v2i64 __attribute__((ext_vector_type(2)));

typedef __attribute__((address_space(3))) unsigned char as3_byte;
typedef __attribute__((address_space(1))) const unsigned char as1_byte;

__device__ __forceinline__ void gload16(const void* g, void* l){
  __builtin_amdgcn_global_load_lds((as1_byte*)g, (as3_byte*)l, 16, 0, 0);
}

__device__ __forceinline__ float b2f(unsigned short u){
  union{unsigned int i; float f;} x; x.i=((unsigned int)u)<<16; return x.f;
}
__device__ __forceinline__ unsigned short f2b(float f){
  unsigned int u=__float_as_uint(f);
  return (unsigned short)((u + 0x7FFFu + ((u>>16)&1u))>>16);
}

// ---------------- fp32 -> bf16 weight convert (all 4 weights), one launch ----------------
__global__ void cvt_kernel(const float* __restrict__ w0, const float* __restrict__ w1,
                           const float* __restrict__ w2, const float* __restrict__ w3,
                           unsigned short* __restrict__ out){
  int i = blockIdx.x*256 + threadIdx.x;
  if (i < 442368)        out[i] = f2b(w0[i]);
  else if (i < 589824)   out[i] = f2b(w1[i - 442368]);
  else if (i < 1179648)  out[i] = f2b(w2[i - 589824]);
  else if (i < 1769472)  out[i] = f2b(w3[i - 1179648]);
}

// ---------------- LayerNorm over D=384, one block per row (bf16 out) ----------------
__global__ __launch_bounds__(128)
void ln_kernel(const float* __restrict__ in, const float* __restrict__ gg, const float* __restrict__ bb,
               unsigned short* __restrict__ outb){
  int row = blockIdx.x, t = threadIdx.x;
  const float* r = in + (size_t)row*DD;
  float v0=r[t], v1=r[t+128], v2=r[t+256];
  float s=v0+v1+v2, q=v0*v0+v1*v1+v2*v2;
  #pragma unroll
  for (int o=32;o>0;o>>=1){ s+=__shfl_down(s,o); q+=__shfl_down(q,o); }
  __shared__ float ls[2], lq[2];
  if ((t&63)==0){ ls[t>>6]=s; lq[t>>6]=q; }
  __syncthreads();
  float S=ls[0]+ls[1], Q=lq[0]+lq[1];
  float mean=S*(1.0f/DD);
  float rstd=rsqrtf(Q*(1.0f/DD)-mean*mean+1e-5f);
  unsigned short* o=outb+(size_t)row*DD;
  o[t]    =f2b((v0-mean)*rstd*gg[t]+bb[t]);
  o[t+128]=f2b((v1-mean)*rstd*gg[t+128]+bb[t+128]);
  o[t+256]=f2b((v2-mean)*rstd*gg[t+256]+bb[t+256]);
}

// ---------------- depthwise conv1d (K=7, same) + bias + LayerNorm, bf16 in/out ----------------
__global__ __launch_bounds__(128)
void conv_ln_kernel(const unsigned short* __restrict__ h2, const float* __restrict__ dww, const float* __restrict__ dwb,
                    const float* __restrict__ gg, const float* __restrict__ bb, unsigned short* __restrict__ out){
  int row=blockIdx.x, t=threadIdx.x;
  int bi=row>>10, n=row&1023;
  const unsigned short* base = h2 + (size_t)(bi<<10)*DD;
  float a[3];
  #pragma unroll
  for (int j=0;j<3;j++){
    int d=t+j*128;
    float acc=dwb[d];
    #pragma unroll
    for (int k=0;k<7;k++){
      int nn=n+k-3;
      if (nn>=0 && nn<NN) acc += dww[d*7+k]*b2f(base[(size_t)nn*DD + d]);
    }
    a[j]=acc;
  }
  float s=a[0]+a[1]+a[2], q=a[0]*a[0]+a[1]*a[1]+a[2]*a[2];
  #pragma unroll
  for (int o=32;o>0;o>>=1){ s+=__shfl_down(s,o); q+=__shfl_down(q,o); }
  __shared__ float ls[2], lq[2];
  if ((t&63)==0){ ls[t>>6]=s; lq[t>>6]=q; }
  __syncthreads();
  float S=ls[0]+ls[1], Q=lq[0]+lq[1];
  float mean=S*(1.0f/DD);
  float rstd=rsqrtf(Q*(1.0f/DD)-mean*mean+1e-5f);
  unsigned short* o = out + (size_t)row*DD;
  #pragma unroll
  for (int j=0;j<3;j++){
    int d=t+j*128;
    o[d]=f2b((a[j]-mean)*rstd*gg[d]+bb[d]);
  }
}

// ================= LDS-staged bf16 MFMA GEMM, 128 x TN tile, BK=32, double-buffered =================
// MODE 0: qkv scatter: q,k -> fp8 planes in MFMA-FRAGMENT layout
//   qk8f[c][(bg)*64 + (n>>4)][lane=((d>>3)&3)*16 + (n&15)][byte=(d>>5)*8 + (d&7)]
//   v -> fp8 transposed V8[bg][d][m]
// MODE 1: out_f32 = resid + C   (proj / fc2)
// MODE 2: out_bf16 = gelu_exact(C)  (fc1)
template<int MODE, int TN>
__global__ __launch_bounds__(256)
void gemm_kernel(const unsigned short* __restrict__ A, const unsigned short* __restrict__ W,
                 const float* __restrict__ bias, const float* __restrict__ resid,
                 float* __restrict__ outf, unsigned short* __restrict__ outb,
                 unsigned char* __restrict__ qk8out, unsigned char* __restrict__ v8out,
                 int Kdim, int Ncols){
  constexpr int JF = TN/32;
  __shared__ __align__(16) unsigned short lds_a[2][128*32];
  __shared__ __align__(16) unsigned short lds_b[2][TN*32];
  int t=threadIdx.x, lane=t&63, w=t>>6;
  int bm = blockIdx.x*128;
  int bn = blockIdx.y*TN;
  int wr = w>>1, wc = w&1;
  int rm = lane&15, r16 = lane>>4;
  f32x4 acc[4][JF] = {};
  char* ldsa_c = (char*)lds_a;
  char* ldsb_c = (char*)lds_b;
  int abyte[4], bbyte[JF];
  #pragma unroll
  for (int i=0;i<4;i++){
    int ra = wr*64 + i*16 + rm;
    abyte[i] = ra*64 + ((r16 ^ ((ra>>1)&3))*16);
  }
  #pragma unroll
  for (int j=0;j<JF;j++){
    int rb = wc*(TN/2) + j*16 + rm;
    bbyte[j] = rb*64 + ((r16 ^ ((rb>>1)&3))*16);
  }
  auto stage = [&](int buf, int k0){
    #pragma unroll
    for (int c=0;c<2;c++){
      int u = t + c*256;
      int row = u>>2, sl = (u&3) ^ ((row>>1)&3);
      gload16(A + (size_t)(bm+row)*Kdim + k0 + sl*8, ldsa_c + buf*8192 + u*16);
    }
    #pragma unroll
    for (int c=0;c<TN/64;c++){
      int u = t + c*256;
      int row = u>>2, sl = (u&3) ^ ((row>>1)&3);
      gload16(W + (size_t)(bn+row)*Kdim + k0 + sl*8, ldsb_c + buf*(TN*64) + u*16);
    }
  };
  int niter = Kdim>>5;
  stage(0, 0);
  __syncthreads();
  for (int it=0; it<niter; ++it){
    if (it+1<niter) stage((it+1)&1, (it+1)<<5);
    int ab = (it&1)*8192, bb2 = (it&1)*(TN*64);
    short8 af[4], bf[JF];
    #pragma unroll
    for (int i=0;i<4;i++) af[i]=*reinterpret_cast<const short8*>(ldsa_c + ab + abyte[i]);
    #pragma unroll
    for (int j=0;j<JF;j++) bf[j]=*reinterpret_cast<const short8*>(ldsb_c + bb2 + bbyte[j]);
    #pragma unroll
    for (int i=0;i<4;i++)
      #pragma unroll
      for (int j=0;j<JF;j++)
        acc[i][j]=__builtin_amdgcn_mfma_f32_16x16x32_bf16(af[i],bf[j],acc[i][j],0,0,0);
    __syncthreads();
  }
  #pragma unroll
  for (int i=0;i<4;i++){
    #pragma unroll
    for (int j=0;j<JF;j++){
      #pragma unroll
      for (int r=0;r<4;r++){
        int row = bm + wr*64 + i*16 + r16*4 + r;
        int col = bn + wc*(TN/2) + j*16 + rm;
        float v = acc[i][j][r] + bias[col];
        if (MODE==0){
          int c = col/384; int rem = col - c*384; int hh = rem>>6, d = rem&63;
          int bi = row>>10, nn = row&1023;
          unsigned char pk = (unsigned char)(__builtin_amdgcn_cvt_pk_fp8_f32(v, v, 0, false) & 0xff);
          if (c==2){
            v8out[(((size_t)(bi*6+hh))<<16) + ((size_t)d<<10) + nn] = pk;
          } else {
            // fragment-order scatter: lane=((d>>3)&3)*16+(nn&15), byte=(d>>5)*8+(d&7)
            size_t fa = ((size_t)c*SEC)
                      + ((((size_t)(bi*6+hh))<<6) + (nn>>4))*1024
                      + ((((d>>3)&3)*16 + (nn&15))<<4) + ((d>>5)*8) + (d&7);
            qk8out[fa] = pk;
          }
        } else if (MODE==1){
          size_t idx = (size_t)row*Ncols + col;
          outf[idx] = resid[idx] + v;
        } else {
          float ge = 0.5f*v*(1.0f+erff(v*0.70710678118654752f));
          outb[(size_t)row*Ncols + col] = f2b(ge);
        }
      }
    }
  }
}

// ================= smx: E(fp8) = exp2(premix(Q8K8^T)·log2e·0.125), lpart[mh][bg][n] = partial rowsum =================
// NO LDS staging, NO main-loop barriers, NO atomics. block = (b, 16-row n-tile, m-half): 1024 blocks, 4 waves.
// ILP-2: each iteration loads TWO independent m-tiles (A at m0, B at m0+64) back-to-back, then
// MFMA-A -> VALU-A (kfa dies) -> MFMA-B -> VALU-B; B's load latency hides under A's compute.
// tbm kept raw (uniform -> SGPR); 0.125*log2(e) applied inside the exp2 argument.
// Partial l written with PLAIN STORES to disjoint [mh] slots (pure overwrite each call).
__global__ __launch_bounds__(256, 4)
void smx_kernel(const unsigned char* __restrict__ qk8, const float* __restrict__ tbm,
                unsigned char* __restrict__ E, float* __restrict__ lpart){
  __shared__ float lred[4][6][16];
  int t=threadIdx.x, lane=t&63, w=t>>6;
  int blk=blockIdx.x;
  int b = blk&7, nt = (blk>>3)&63, mh = blk>>9;
  int n0 = nt*16, mbase = mh*512;
  int c16=lane&15, r16=lane>>4;
  const unsigned char* q8f = qk8;
  const unsigned char* k8f = qk8 + SEC;
  // Q fragments: one 16B per lane per head (constant over m)
  v2i64 qf[6];
  #pragma unroll
  for (int h=0;h<6;h++)
    qf[h] = *(const v2i64*)(q8f + (((((size_t)(b*6+h))<<6) + (n0>>4))<<10) + lane*16);
  float tbr[36];
  #pragma unroll
  for (int i=0;i<36;i++) tbr[i] = tbm[i];   // uniform; scale folded into exp2 arg
  const float SC = 0.125f*1.44269504088896f;
  float lsum[6]={0.f,0.f,0.f,0.f,0.f,0.f};
  #pragma unroll
  for (int mt=0; mt<4; ++mt){
    int m0a = mbase + mt*128 + w*16;
    int m0b = m0a + 64;
    v2i64 kfa[6], kfb[6];
    #pragma unroll
    for (int h=0;h<6;h++)
      kfa[h] = *(const v2i64*)(k8f + (((((size_t)(b*6+h))<<6) + (m0a>>4))<<10) + lane*16);
    #pragma unroll
    for (int h=0;h<6;h++)
      kfb[h] = *(const v2i64*)(k8f + (((((size_t)(b*6+h))<<6) + (m0b>>4))<<10) + lane*16);
    // ---- tile A ----
    {
      f32x4 aq[6] = {};
      #pragma unroll
      for (int h=0;h<6;h++){
        aq[h] = __builtin_amdgcn_mfma_f32_16x16x32_fp8_fp8(kfa[h][0], qf[h][0], aq[h], 0,0,0);
        aq[h] = __builtin_amdgcn_mfma_f32_16x16x32_fp8_fp8(kfa[h][1], qf[h][1], aq[h], 0,0,0);
      }
      #pragma unroll
      for (int g=0;g<6;g++){
        float e0,e1,e2,e3;
        {
          float sm;
          sm = tbr[g*6]*aq[0][0]+tbr[g*6+1]*aq[1][0]+tbr[g*6+2]*aq[2][0]
             + tbr[g*6+3]*aq[3][0]+tbr[g*6+4]*aq[4][0]+tbr[g*6+5]*aq[5][0];
          e0 = __builtin_amdgcn_exp2f(sm*SC);
          sm = tbr[g*6]*aq[0][1]+tbr[g*6+1]*aq[1][1]+tbr[g*6+2]*aq[2][1]
             + tbr[g*6+3]*aq[3][1]+tbr[g*6+4]*aq[4][1]+tbr[g*6+5]*aq[5][1];
          e1 = __builtin_amdgcn_exp2f(sm*SC);
          sm = tbr[g*6]*aq[0][2]+tbr[g*6+1]*aq[1][2]+tbr[g*6+2]*aq[2][2]
             + tbr[g*6+3]*aq[3][2]+tbr[g*6+4]*aq[4][2]+tbr[g*6+5]*aq[5][2];
          e2 = __builtin_amdgcn_exp2f(sm*SC);
          sm = tbr[g*6]*aq[0][3]+tbr[g*6+1]*aq[1][3]+tbr[g*6+2]*aq[2][3]
             + tbr[g*6+3]*aq[3][3]+tbr[g*6+4]*aq[4][3]+tbr[g*6+5]*aq[5][3];
          e3 = __builtin_amdgcn_exp2f(sm*SC);
        }
        lsum[g] += (e0+e1)+(e2+e3);
        int pkv = __builtin_amdgcn_cvt_pk_fp8_f32(e0, e1, 0, false);
        pkv = __builtin_amdgcn_cvt_pk_fp8_f32(e2, e3, pkv, true);
        *(unsigned int*)(E + (((size_t)(b*6+g))<<20) + ((size_t)(n0+c16)<<10) + m0a + r16*4)
          = (unsigned int)pkv;
      }
    }
    // ---- tile B ----
    {
      f32x4 aq[6] = {};
      #pragma unroll
      for (int h=0;h<6;h++){
        aq[h] = __builtin_amdgcn_mfma_f32_16x16x32_fp8_fp8(kfb[h][0], qf[h][0], aq[h], 0,0,0);
        aq[h] = __builtin_amdgcn_mfma_f32_16x16x32_fp8_fp8(kfb[h][1], qf[h][1], aq[h], 0,0,0);
      }
      #pragma unroll
      for (int g=0;g<6;g++){
        float e0,e1,e2,e3;
        {
          float sm;
          sm = tbr[g*6]*aq[0][0]+tbr[g*6+1]*aq[1][0]+tbr[g*6+2]*aq[2][0]
             + tbr[g*6+3]*aq[3][0]+tbr[g*6+4]*aq[4][0]+tbr[g*6+5]*aq[5][0];
          e0 = __builtin_amdgcn_exp2f(sm*SC);
          sm = tbr[g*6]*aq[0][1]+tbr[g*6+1]*aq[1][1]+tbr[g*6+2]*aq[2][1]
             + tbr[g*6+3]*aq[3][1]+tbr[g*6+4]*aq[4][1]+tbr[g*6+5]*aq[5][1];
          e1 = __builtin_amdgcn_exp2f(sm*SC);
          sm = tbr[g*6]*aq[0][2]+tbr[g*6+1]*aq[1][2]+tbr[g*6+2]*aq[2][2]
             + tbr[g*6+3]*aq[3][2]+tbr[g*6+4]*aq[4][2]+tbr[g*6+5]*aq[5][2];
          e2 = __builtin_amdgcn_exp2f(sm*SC);
          sm = tbr[g*6]*aq[0][3]+tbr[g*6+1]*aq[1][3]+tbr[g*6+2]*aq[2][3]
             + tbr[g*6+3]*aq[3][3]+tbr[g*6+4]*aq[4][3]+tbr[g*6+5]*aq[5][3];
          e3 = __builtin_amdgcn_exp2f(sm*SC);
        }
        lsum[g] += (e0+e1)+(e2+e3);
        int pkv = __builtin_amdgcn_cvt_pk_fp8_f32(e0, e1, 0, false);
        pkv = __builtin_amdgcn_cvt_pk_fp8_f32(e2, e3, pkv, true);
        *(unsigned int*)(E + (((size_t)(b*6+g))<<20) + ((size_t)(n0+c16)<<10) + m0b + r16*4)
          = (unsigned int)pkv;
      }
    }
  }
  // l reduction: in-wave over r16, cross-wave via LDS, one plain store per (mh,g,n)
  #pragma unroll
  for (int g=0;g<6;g++){
    lsum[g] += __shfl_xor(lsum[g],16);
    lsum[g] += __shfl_xor(lsum[g],32);
  }
  if (r16==0){
    #pragma unroll
    for (int g=0;g<6;g++) lred[w][g][c16] = lsum[g];
  }
  __syncthreads();
  if (w==0 && r16==0){
    #pragma unroll
    for (int g=0;g<6;g++){
      float l = lred[0][g][c16]+lred[1][g][c16]+lred[2][g][c16]+lred[3][g][c16];
      lpart[(((size_t)(mh*48 + b*6+g))<<10) + n0 + c16] = l;
    }
  }
}

// ================= pvmix: out[n,g*64+d] = (1/256) sum_m (sum_h ta[g,h]*(256/l[h,n])*E[h,n,m]) * V8[g,d,m] =================
// block = (b, 16-row n-tile): 512 blocks, 4 waves (d-quarters), 2 blocks/CU. l = lpart[0]+lpart[1].
__global__ __launch_bounds__(256, 2)
void pvmix_kernel(const unsigned char* __restrict__ E, const unsigned char* __restrict__ V8,
                  const float* __restrict__ lpart, const float* __restrict__ tam,
                  unsigned short* __restrict__ outp){
  __shared__ __align__(16) unsigned char Es[6*16*64];    // 6 KB
  __shared__ __align__(16) unsigned char Vs[6*64*64];    // 24 KB
  __shared__ __align__(16) unsigned char pms[6*16*64];   // 6 KB
  int t=threadIdx.x, lane=t&63, w=t>>6;
  int b = blockIdx.x&7, nt = blockIdx.x>>3;
  int n0 = nt*16;
  int c16 = lane&15, r16 = lane>>4;
  int mn = t&15, mg = (t>>4)&7, gh = t>>7;
  float cf[3][6];
  #pragma unroll
  for (int g=0;g<6;g++){
    float l0 = lpart[(((size_t)(b*6+g))<<10) + n0 + mn];
    float l1 = lpart[(((size_t)(48 + b*6+g))<<10) + n0 + mn];
    float iv = 256.0f/(l0 + l1);
    #pragma unroll
    for (int j=0;j<3;j++) cf[j][g] = tam[(gh*3+j)*6 + g]*iv;
  }
  auto stageE = [&](int m0){
    #pragma unroll
    for (int i=0;i<2;i++){
      int u = t + i*256;
      if (u<384){
        int r = u>>2, s = (u&3) ^ (r&3);
        int g = r>>4, n = r&15;
        gload16(E + (((size_t)(b*6+g))<<20) + ((size_t)(n0+n)<<10) + m0 + s*16,
                (char*)Es + u*16);
      }
    }
  };
  auto stageV = [&](int m0){
    #pragma unroll
    for (int i=0;i<6;i++){
      int u = t + i*256;
      int r = u>>2, s = (u&3) ^ (r&3);
      int g = r>>6, d = r&63;
      gload16(V8 + (((size_t)(b*6+g))<<16) + ((size_t)d<<10) + m0 + s*16,
              (char*)Vs + u*16);
    }
  };
  stageE(0); stageV(0);
  __syncthreads();
  f32x4 acc[6] = {};
  for (int mt=0; mt<16; ++mt){
    // ---- MIX: Es -> pms ----
    float e[6][8];
    #pragma unroll
    for (int g=0;g<6;g++){
      int row = g*16 + mn;
      int byteo = row*64 + ((mg*8) ^ ((row&3)<<4));
      unsigned int lo = *(const unsigned int*)(Es + byteo);
      unsigned int hi = *(const unsigned int*)(Es + byteo + 4);
      f32x2 p0 = __builtin_amdgcn_cvt_pk_f32_fp8(lo, false);
      f32x2 p1 = __builtin_amdgcn_cvt_pk_f32_fp8(lo, true);
      f32x2 p2 = __builtin_amdgcn_cvt_pk_f32_fp8(hi, false);
      f32x2 p3 = __builtin_amdgcn_cvt_pk_f32_fp8(hi, true);
      e[g][0]=p0.x; e[g][1]=p0.y; e[g][2]=p1.x; e[g][3]=p1.y;
      e[g][4]=p2.x; e[g][5]=p2.y; e[g][6]=p3.x; e[g][7]=p3.y;
    }
    #pragma unroll
    for (int j=0;j<3;j++){
      float pm[8];
      #pragma unroll
      for (int m=0;m<8;m++)
        pm[m] = cf[j][0]*e[0][m]+cf[j][1]*e[1][m]+cf[j][2]*e[2][m]
              + cf[j][3]*e[3][m]+cf[j][4]*e[4][m]+cf[j][5]*e[5][m];
      int d0 = __builtin_amdgcn_cvt_pk_fp8_f32(pm[0], pm[1], 0, false);
      d0 = __builtin_amdgcn_cvt_pk_fp8_f32(pm[2], pm[3], d0, true);
      int d1 = __builtin_amdgcn_cvt_pk_fp8_f32(pm[4], pm[5], 0, false);
      d1 = __builtin_amdgcn_cvt_pk_fp8_f32(pm[6], pm[7], d1, true);
      int prow = (gh*3+j)*16 + mn;
      int pbyte = prow*64 + ((mg*8) ^ ((mn&7)<<3));
      *(unsigned int*)(pms + pbyte)     = (unsigned int)d0;
      *(unsigned int*)(pms + pbyte + 4) = (unsigned int)d1;
    }
    __syncthreads();                 // pms visible; Es reads done
    if (mt<15) stageE((mt+1)*64);
    // ---- MFMA: pm x V8 ----
    #pragma unroll
    for (int g=0;g<6;g++){
      int arow = g*16 + c16;
      int vrow = g*64 + w*16 + c16;
      #pragma unroll
      for (int kk=0;kk<2;kk++){
        long af = *(const long*)(pms + arow*64 + ((kk*32 + r16*8) ^ ((c16&7)<<3)));
        long bf = *(const long*)(Vs + vrow*64
                   + ((((kk*2 + (r16>>1)) ^ (vrow&3))<<4) + ((r16&1)<<3)));
        acc[g] = __builtin_amdgcn_mfma_f32_16x16x32_fp8_fp8(af, bf, acc[g], 0,0,0);
      }
    }
    __syncthreads();                 // pms/Vs reads done
    if (mt<15) stageV((mt+1)*64);
  }
  #pragma unroll
  for (int g=0;g<6;g++)
    #pragma unroll
    for (int r=0;r<4;r++){
      int n = n0 + r16*4 + r;
      int d = g*64 + w*16 + c16;
      outp[((size_t)(b*1024 + n))*DD + d] = f2b(acc[g][r] * 0.00390625f);
    }
}

extern "C" void kernel_launch(void* const* d_in, const int* in_sizes, int n_in,
                              void* d_out, int out_size, void* d_ws, size_t ws_size,
                              hipStream_t stream){
  const float* x      = (const float*)d_in[0];
  const float* qkv_w  = (const float*)d_in[1];
  const float* qkv_b  = (const float*)d_in[2];
  const float* proj_w = (const float*)d_in[3];
  const float* proj_b = (const float*)d_in[4];
  const float* t_before=(const float*)d_in[5];
  const float* t_after =(const float*)d_in[6];
  const float* dw_w   = (const float*)d_in[7];
  const float* dw_b   = (const float*)d_in[8];
  const float* mlp_g  = (const float*)d_in[9];
  const float* mlp_b  = (const float*)d_in[10];
  const float* n1_g   = (const float*)d_in[11];
  const float* n1_b   = (const float*)d_in[12];
  const float* n2_g   = (const float*)d_in[13];
  const float* n2_b   = (const float*)d_in[14];
  const float* fc1_w  = (const float*)d_in[15];
  const float* fc1_b  = (const float*)d_in[16];
  const float* fc2_w  = (const float*)d_in[17];
  const float* fc2_b  = (const float*)d_in[18];
  float* out = (float*)d_out;
  char* ws = (char*)d_ws;
  unsigned short* qkvwb = (unsigned short*)(ws + 0);          // 1152*384 bf16
  unsigned short* projwb= (unsigned short*)(ws + 884736);
  unsigned short* fc1wb = (unsigned short*)(ws + 1179648);
  unsigned short* fc2wb = (unsigned short*)(ws + 2359296);
  unsigned short* hb    = (unsigned short*)(ws + 3538944);    // 8192*384 bf16 (reuse: hcln)
  unsigned char*  qk8   = (unsigned char*) (ws + 9830400);    // q8f,k8f fp8 frag planes (reuse: h2 bf16)
  unsigned char*  V8    = (unsigned char*) (ws + 28704768);   // 48*64*1024 fp8
  float*          lpart = (float*)        (ws + 31850496);    // 2*48*1024 f32 partial l-sums
  unsigned char*  Ebuf  = (unsigned char*) (ws + 34996224);   // 48MB fp8 E (reuse: fc1o)
  unsigned short* attnb = (unsigned short*)(ws + 85327872);   // 8192*384 bf16
  float*          x2    = (float*)(ws + 91619328);            // 8192*384 f32
  unsigned short* h2 = (unsigned short*)qk8;
  unsigned short* hcln = hb;
  unsigned short* fc1o = (unsigned short*)Ebuf;

  cvt_kernel<<<6912,256,0,stream>>>(qkv_w, proj_w, fc1_w, fc2_w, qkvwb);

  ln_kernel<<<BN,128,0,stream>>>(x, n1_g, n1_b, hb);
  { dim3 g(BN/128, D3/128); gemm_kernel<0,128><<<g,256,0,stream>>>(hb, qkvwb, qkv_b, nullptr, nullptr, nullptr, qk8, V8, DD, D3); }
  smx_kernel<<<1024,256,0,stream>>>(qk8, t_before, Ebuf, lpart);
  pvmix_kernel<<<512,256,0,stream>>>(Ebuf, V8, lpart, t_after, attnb);
  { dim3 g(BN/128, DD/64); gemm_kernel<1,64><<<g,256,0,stream>>>(attnb, projwb, proj_b, x, x2, nullptr, nullptr, nullptr, DD, DD); }
  ln_kernel<<<BN,128,0,stream>>>(x2, n2_g, n2_b, h2);
  conv_ln_kernel<<<BN,128,0,stream>>>(h2, dw_w, dw_b, mlp_g, mlp_b, hcln);
  { dim3 g(BN/128, D4/128); gemm_kernel<2,128><<<g,256,0,stream>>>(hcln, fc1wb, fc1_b, nullptr, nullptr, fc1o, nullptr, nullptr, DD, D4); }
  { dim3 g(BN/128, DD/64); gemm_kernel<1,64><<<g,256,0,stream>>>(fc1o, fc2wb, fc2_b, x2, out, nullptr, nullptr, nullptr, D4, DD); }
}

// Round 19
// 187.675 us; speedup vs baseline: 1.2312x; 1.0279x over previous
//
#include <hip/hip_runtime.h>
#include <hip/hip_bf16.h>

#define BB 8
#define NN 1024
#define DD 384
#define HH 6
#define HD 64
#define BN 8192          // B*N rows
#define D3 1152          // 3*D
#define D4 1536          // 4*D
#define SEC 3145728      // B*H*N*HD elems per plane

typedef __attribute__((ext_vector_type(8))) short short8;
typedef __attribute__((ext_vector_type(4))) float f32x4;
typedef __attribute__((ext_vector_type(2))) float f32x2;
typedef long v2i64 __attribute__((ext_vector_type(2)));

typedef __attribute__((address_space(3))) unsigned char as3_byte;
typedef __attribute__((address_space(1))) const unsigned char as1_byte;

__device__ __forceinline__ void gload16(const void* g, void* l){
  __builtin_amdgcn_global_load_lds((as1_byte*)g, (as3_byte*)l, 16, 0, 0);
}

__device__ __forceinline__ float b2f(unsigned short u){
  union{unsigned int i; float f;} x; x.i=((unsigned int)u)<<16; return x.f;
}
__device__ __forceinline__ unsigned short f2b(float f){
  unsigned int u=__float_as_uint(f);
  return (unsigned short)((u + 0x7FFFu + ((u>>16)&1u))>>16);
}
__device__ __forceinline__ unsigned char f2f8(float f){
  return (unsigned char)(__builtin_amdgcn_cvt_pk_fp8_f32(f, f, 0, false) & 0xff);
}

// ---------------- weight convert: qkv/proj -> bf16; fc1/fc2 -> fp8 (x8), one launch ----------------
// bf16 region: qkvwb (442368) ++ projwb (147456) contiguous. fp8 region: fc1w8 (589824) ++ fc2w8 (589824).
__global__ void cvt_kernel(const float* __restrict__ w0, const float* __restrict__ w1,
                           const float* __restrict__ w2, const float* __restrict__ w3,
                           unsigned short* __restrict__ outb, unsigned char* __restrict__ out8){
  int i = blockIdx.x*256 + threadIdx.x;
  if (i < 442368)        outb[i] = f2b(w0[i]);
  else if (i < 589824)   outb[i] = f2b(w1[i - 442368]);
  else if (i < 1179648)  out8[i - 589824] = f2f8(w2[i - 589824]*8.0f);
  else if (i < 1769472)  out8[i - 589824] = f2f8(w3[i - 1179648]*8.0f);
}

// ---------------- LayerNorm over D=384, one block per row (bf16 out) ----------------
__global__ __launch_bounds__(128)
void ln_kernel(const float* __restrict__ in, const float* __restrict__ gg, const float* __restrict__ bb,
               unsigned short* __restrict__ outb){
  int row = blockIdx.x, t = threadIdx.x;
  const float* r = in + (size_t)row*DD;
  float v0=r[t], v1=r[t+128], v2=r[t+256];
  float s=v0+v1+v2, q=v0*v0+v1*v1+v2*v2;
  #pragma unroll
  for (int o=32;o>0;o>>=1){ s+=__shfl_down(s,o); q+=__shfl_down(q,o); }
  __shared__ float ls[2], lq[2];
  if ((t&63)==0){ ls[t>>6]=s; lq[t>>6]=q; }
  __syncthreads();
  float S=ls[0]+ls[1], Q=lq[0]+lq[1];
  float mean=S*(1.0f/DD);
  float rstd=rsqrtf(Q*(1.0f/DD)-mean*mean+1e-5f);
  unsigned short* o=outb+(size_t)row*DD;
  o[t]    =f2b((v0-mean)*rstd*gg[t]+bb[t]);
  o[t+128]=f2b((v1-mean)*rstd*gg[t+128]+bb[t+128]);
  o[t+256]=f2b((v2-mean)*rstd*gg[t+256]+bb[t+256]);
}

// ---------------- depthwise conv1d (K=7) + bias + LayerNorm; bf16 in, fp8(x4) out ----------------
__global__ __launch_bounds__(128)
void conv_ln_kernel(const unsigned short* __restrict__ h2, const float* __restrict__ dww, const float* __restrict__ dwb,
                    const float* __restrict__ gg, const float* __restrict__ bb, unsigned char* __restrict__ out8){
  int row=blockIdx.x, t=threadIdx.x;
  int bi=row>>10, n=row&1023;
  const unsigned short* base = h2 + (size_t)(bi<<10)*DD;
  float a[3];
  #pragma unroll
  for (int j=0;j<3;j++){
    int d=t+j*128;
    float acc=dwb[d];
    #pragma unroll
    for (int k=0;k<7;k++){
      int nn=n+k-3;
      if (nn>=0 && nn<NN) acc += dww[d*7+k]*b2f(base[(size_t)nn*DD + d]);
    }
    a[j]=acc;
  }
  float s=a[0]+a[1]+a[2], q=a[0]*a[0]+a[1]*a[1]+a[2]*a[2];
  #pragma unroll
  for (int o=32;o>0;o>>=1){ s+=__shfl_down(s,o); q+=__shfl_down(q,o); }
  __shared__ float ls[2], lq[2];
  if ((t&63)==0){ ls[t>>6]=s; lq[t>>6]=q; }
  __syncthreads();
  float S=ls[0]+ls[1], Q=lq[0]+lq[1];
  float mean=S*(1.0f/DD);
  float rstd=rsqrtf(Q*(1.0f/DD)-mean*mean+1e-5f);
  unsigned char* o = out8 + (size_t)row*DD;
  #pragma unroll
  for (int j=0;j<3;j++){
    int d=t+j*128;
    o[d]=f2f8(((a[j]-mean)*rstd*gg[d]+bb[d])*4.0f);
  }
}

// ================= LDS-staged bf16 MFMA GEMM, 128 x TN tile, BK=32, double-buffered =================
// MODE 0: qkv scatter: q,k -> fp8 planes in MFMA-FRAGMENT layout; v -> fp8 transposed V8[bg][d][m]
// MODE 1: out_f32 = resid + C   (proj)
template<int MODE, int TN>
__global__ __launch_bounds__(256)
void gemm_kernel(const unsigned short* __restrict__ A, const unsigned short* __restrict__ W,
                 const float* __restrict__ bias, const float* __restrict__ resid,
                 float* __restrict__ outf,
                 unsigned char* __restrict__ qk8out, unsigned char* __restrict__ v8out,
                 int Kdim, int Ncols){
  constexpr int JF = TN/32;
  __shared__ __align__(16) unsigned short lds_a[2][128*32];
  __shared__ __align__(16) unsigned short lds_b[2][TN*32];
  int t=threadIdx.x, lane=t&63, w=t>>6;
  int bm = blockIdx.x*128;
  int bn = blockIdx.y*TN;
  int wr = w>>1, wc = w&1;
  int rm = lane&15, r16 = lane>>4;
  f32x4 acc[4][JF] = {};
  char* ldsa_c = (char*)lds_a;
  char* ldsb_c = (char*)lds_b;
  int abyte[4], bbyte[JF];
  #pragma unroll
  for (int i=0;i<4;i++){
    int ra = wr*64 + i*16 + rm;
    abyte[i] = ra*64 + ((r16 ^ ((ra>>1)&3))*16);
  }
  #pragma unroll
  for (int j=0;j<JF;j++){
    int rb = wc*(TN/2) + j*16 + rm;
    bbyte[j] = rb*64 + ((r16 ^ ((rb>>1)&3))*16);
  }
  auto stage = [&](int buf, int k0){
    #pragma unroll
    for (int c=0;c<2;c++){
      int u = t + c*256;
      int row = u>>2, sl = (u&3) ^ ((row>>1)&3);
      gload16(A + (size_t)(bm+row)*Kdim + k0 + sl*8, ldsa_c + buf*8192 + u*16);
    }
    #pragma unroll
    for (int c=0;c<TN/64;c++){
      int u = t + c*256;
      int row = u>>2, sl = (u&3) ^ ((row>>1)&3);
      gload16(W + (size_t)(bn+row)*Kdim + k0 + sl*8, ldsb_c + buf*(TN*64) + u*16);
    }
  };
  int niter = Kdim>>5;
  stage(0, 0);
  __syncthreads();
  for (int it=0; it<niter; ++it){
    if (it+1<niter) stage((it+1)&1, (it+1)<<5);
    int ab = (it&1)*8192, bb2 = (it&1)*(TN*64);
    short8 af[4], bf[JF];
    #pragma unroll
    for (int i=0;i<4;i++) af[i]=*reinterpret_cast<const short8*>(ldsa_c + ab + abyte[i]);
    #pragma unroll
    for (int j=0;j<JF;j++) bf[j]=*reinterpret_cast<const short8*>(ldsb_c + bb2 + bbyte[j]);
    #pragma unroll
    for (int i=0;i<4;i++)
      #pragma unroll
      for (int j=0;j<JF;j++)
        acc[i][j]=__builtin_amdgcn_mfma_f32_16x16x32_bf16(af[i],bf[j],acc[i][j],0,0,0);
    __syncthreads();
  }
  #pragma unroll
  for (int i=0;i<4;i++){
    #pragma unroll
    for (int j=0;j<JF;j++){
      #pragma unroll
      for (int r=0;r<4;r++){
        int row = bm + wr*64 + i*16 + r16*4 + r;
        int col = bn + wc*(TN/2) + j*16 + rm;
        float v = acc[i][j][r] + bias[col];
        if (MODE==0){
          int c = col/384; int rem = col - c*384; int hh = rem>>6, d = rem&63;
          int bi = row>>10, nn = row&1023;
          unsigned char pk = f2f8(v);
          if (c==2){
            v8out[(((size_t)(bi*6+hh))<<16) + ((size_t)d<<10) + nn] = pk;
          } else {
            size_t fa = ((size_t)c*SEC)
                      + ((((size_t)(bi*6+hh))<<6) + (nn>>4))*1024
                      + ((((d>>3)&3)*16 + (nn&15))<<4) + ((d>>5)*8) + (d&7);
            qk8out[fa] = pk;
          }
        } else {
          size_t idx = (size_t)row*Ncols + col;
          outf[idx] = resid[idx] + v;
        }
      }
    }
  }
}

// ================= fp8 x fp8 GEMM (pv8 structure): C = (A8·W8^T)/32 + bias =================
// 64x64 tile, BK=64, double-buffered; 4 waves 2x2 (32x32 each).
// MODE 1: outf = resid + v  (fc2).  MODE 2: out8 = fp8(4*gelu(v))  (fc1).
template<int MODE>
__global__ __launch_bounds__(256)
void gemm8_kernel(const unsigned char* __restrict__ A8, const unsigned char* __restrict__ W8,
                  const float* __restrict__ bias, const float* __restrict__ resid,
                  float* __restrict__ outf, unsigned char* __restrict__ out8,
                  int Kdim, int Ncols){
  __shared__ __align__(16) unsigned char As[2][64*64];
  __shared__ __align__(16) unsigned char Bs[2][64*64];
  int t=threadIdx.x, lane=t&63, w=t>>6;
  int bm = blockIdx.x*64;
  int bn = blockIdx.y*64;
  int wr = w>>1, wc = w&1;
  int c16=lane&15, r16=lane>>4;
  f32x4 acc[2][2] = {};
  int arow = t>>2, aslot = (t&3) ^ (arow&3);
  auto stage = [&](int buf, int k0){
    gload16(A8 + (size_t)(bm+arow)*Kdim + k0 + aslot*16, (char*)As + buf*4096 + t*16);
    gload16(W8 + (size_t)(bn+arow)*Kdim + k0 + aslot*16, (char*)Bs + buf*4096 + t*16);
  };
  int niter = Kdim>>6;
  stage(0, 0);
  __syncthreads();
  for (int it=0; it<niter; ++it){
    if (it+1<niter) stage((it+1)&1, (it+1)<<6);
    int off = (it&1)*4096;
    #pragma unroll
    for (int kk=0;kk<2;kk++){
      long afr[2], bfr[2];
      #pragma unroll
      for (int i=0;i<2;i++){
        int ra = wr*32 + i*16 + c16;
        int sa = (kk*2 + (r16>>1)) ^ (ra&3);
        afr[i] = *(const long*)((char*)As + off + ra*64 + (sa<<4) + ((r16&1)<<3));
        int rb = wc*32 + i*16 + c16;
        int sb = (kk*2 + (r16>>1)) ^ (rb&3);
        bfr[i] = *(const long*)((char*)Bs + off + rb*64 + (sb<<4) + ((r16&1)<<3));
      }
      #pragma unroll
      for (int i=0;i<2;i++)
        #pragma unroll
        for (int j=0;j<2;j++)
          acc[i][j] = __builtin_amdgcn_mfma_f32_16x16x32_fp8_fp8(afr[i], bfr[j], acc[i][j], 0,0,0);
    }
    __syncthreads();
  }
  #pragma unroll
  for (int i=0;i<2;i++)
    #pragma unroll
    for (int j=0;j<2;j++)
      #pragma unroll
      for (int r=0;r<4;r++){
        int row = bm + wr*32 + i*16 + r16*4 + r;
        int col = bn + wc*32 + j*16 + c16;
        float v = acc[i][j][r]*0.03125f + bias[col];   // A8=4A, W8=8W -> /32
        if (MODE==1){
          size_t idx = (size_t)row*Ncols + col;
          outf[idx] = resid[idx] + v;
        } else {
          float ge = 0.5f*v*(1.0f+erff(v*0.70710678118654752f));
          out8[(size_t)row*Ncols + col] = f2f8(ge*4.0f);
        }
      }
}

// ================= smx: E(fp8) = exp2(premix(Q8K8^T)·log2e·0.125), lpart = partial rowsum =================
// (round-18 ILP-2 form, unchanged)
__global__ __launch_bounds__(256, 4)
void smx_kernel(const unsigned char* __restrict__ qk8, const float* __restrict__ tbm,
                unsigned char* __restrict__ E, float* __restrict__ lpart){
  __shared__ float lred[4][6][16];
  int t=threadIdx.x, lane=t&63, w=t>>6;
  int blk=blockIdx.x;
  int b = blk&7, nt = (blk>>3)&63, mh = blk>>9;
  int n0 = nt*16, mbase = mh*512;
  int c16=lane&15, r16=lane>>4;
  const unsigned char* q8f = qk8;
  const unsigned char* k8f = qk8 + SEC;
  v2i64 qf[6];
  #pragma unroll
  for (int h=0;h<6;h++)
    qf[h] = *(const v2i64*)(q8f + (((((size_t)(b*6+h))<<6) + (n0>>4))<<10) + lane*16);
  float tbr[36];
  #pragma unroll
  for (int i=0;i<36;i++) tbr[i] = tbm[i];
  const float SC = 0.125f*1.44269504088896f;
  float lsum[6]={0.f,0.f,0.f,0.f,0.f,0.f};
  #pragma unroll
  for (int mt=0; mt<4; ++mt){
    int m0a = mbase + mt*128 + w*16;
    int m0b = m0a + 64;
    v2i64 kfa[6], kfb[6];
    #pragma unroll
    for (int h=0;h<6;h++)
      kfa[h] = *(const v2i64*)(k8f + (((((size_t)(b*6+h))<<6) + (m0a>>4))<<10) + lane*16);
    #pragma unroll
    for (int h=0;h<6;h++)
      kfb[h] = *(const v2i64*)(k8f + (((((size_t)(b*6+h))<<6) + (m0b>>4))<<10) + lane*16);
    {
      f32x4 aq[6] = {};
      #pragma unroll
      for (int h=0;h<6;h++){
        aq[h] = __builtin_amdgcn_mfma_f32_16x16x32_fp8_fp8(kfa[h][0], qf[h][0], aq[h], 0,0,0);
        aq[h] = __builtin_amdgcn_mfma_f32_16x16x32_fp8_fp8(kfa[h][1], qf[h][1], aq[h], 0,0,0);
      }
      #pragma unroll
      for (int g=0;g<6;g++){
        float e0,e1,e2,e3;
        {
          float sm;
          sm = tbr[g*6]*aq[0][0]+tbr[g*6+1]*aq[1][0]+tbr[g*6+2]*aq[2][0]
             + tbr[g*6+3]*aq[3][0]+tbr[g*6+4]*aq[4][0]+tbr[g*6+5]*aq[5][0];
          e0 = __builtin_amdgcn_exp2f(sm*SC);
          sm = tbr[g*6]*aq[0][1]+tbr[g*6+1]*aq[1][1]+tbr[g*6+2]*aq[2][1]
             + tbr[g*6+3]*aq[3][1]+tbr[g*6+4]*aq[4][1]+tbr[g*6+5]*aq[5][1];
          e1 = __builtin_amdgcn_exp2f(sm*SC);
          sm = tbr[g*6]*aq[0][2]+tbr[g*6+1]*aq[1][2]+tbr[g*6+2]*aq[2][2]
             + tbr[g*6+3]*aq[3][2]+tbr[g*6+4]*aq[4][2]+tbr[g*6+5]*aq[5][2];
          e2 = __builtin_amdgcn_exp2f(sm*SC);
          sm = tbr[g*6]*aq[0][3]+tbr[g*6+1]*aq[1][3]+tbr[g*6+2]*aq[2][3]
             + tbr[g*6+3]*aq[3][3]+tbr[g*6+4]*aq[4][3]+tbr[g*6+5]*aq[5][3];
          e3 = __builtin_amdgcn_exp2f(sm*SC);
        }
        lsum[g] += (e0+e1)+(e2+e3);
        int pkv = __builtin_amdgcn_cvt_pk_fp8_f32(e0, e1, 0, false);
        pkv = __builtin_amdgcn_cvt_pk_fp8_f32(e2, e3, pkv, true);
        *(unsigned int*)(E + (((size_t)(b*6+g))<<20) + ((size_t)(n0+c16)<<10) + m0a + r16*4)
          = (unsigned int)pkv;
      }
    }
    {
      f32x4 aq[6] = {};
      #pragma unroll
      for (int h=0;h<6;h++){
        aq[h] = __builtin_amdgcn_mfma_f32_16x16x32_fp8_fp8(kfb[h][0], qf[h][0], aq[h], 0,0,0);
        aq[h] = __builtin_amdgcn_mfma_f32_16x16x32_fp8_fp8(kfb[h][1], qf[h][1], aq[h], 0,0,0);
      }
      #pragma unroll
      for (int g=0;g<6;g++){
        float e0,e1,e2,e3;
        {
          float sm;
          sm = tbr[g*6]*aq[0][0]+tbr[g*6+1]*aq[1][0]+tbr[g*6+2]*aq[2][0]
             + tbr[g*6+3]*aq[3][0]+tbr[g*6+4]*aq[4][0]+tbr[g*6+5]*aq[5][0];
          e0 = __builtin_amdgcn_exp2f(sm*SC);
          sm = tbr[g*6]*aq[0][1]+tbr[g*6+1]*aq[1][1]+tbr[g*6+2]*aq[2][1]
             + tbr[g*6+3]*aq[3][1]+tbr[g*6+4]*aq[4][1]+tbr[g*6+5]*aq[5][1];
          e1 = __builtin_amdgcn_exp2f(sm*SC);
          sm = tbr[g*6]*aq[0][2]+tbr[g*6+1]*aq[1][2]+tbr[g*6+2]*aq[2][2]
             + tbr[g*6+3]*aq[3][2]+tbr[g*6+4]*aq[4][2]+tbr[g*6+5]*aq[5][2];
          e2 = __builtin_amdgcn_exp2f(sm*SC);
          sm = tbr[g*6]*aq[0][3]+tbr[g*6+1]*aq[1][3]+tbr[g*6+2]*aq[2][3]
             + tbr[g*6+3]*aq[3][3]+tbr[g*6+4]*aq[4][3]+tbr[g*6+5]*aq[5][3];
          e3 = __builtin_amdgcn_exp2f(sm*SC);
        }
        lsum[g] += (e0+e1)+(e2+e3);
        int pkv = __builtin_amdgcn_cvt_pk_fp8_f32(e0, e1, 0, false);
        pkv = __builtin_amdgcn_cvt_pk_fp8_f32(e2, e3, pkv, true);
        *(unsigned int*)(E + (((size_t)(b*6+g))<<20) + ((size_t)(n0+c16)<<10) + m0b + r16*4)
          = (unsigned int)pkv;
      }
    }
  }
  #pragma unroll
  for (int g=0;g<6;g++){
    lsum[g] += __shfl_xor(lsum[g],16);
    lsum[g] += __shfl_xor(lsum[g],32);
  }
  if (r16==0){
    #pragma unroll
    for (int g=0;g<6;g++) lred[w][g][c16] = lsum[g];
  }
  __syncthreads();
  if (w==0 && r16==0){
    #pragma unroll
    for (int g=0;g<6;g++){
      float l = lred[0][g][c16]+lred[1][g][c16]+lred[2][g][c16]+lred[3][g][c16];
      lpart[(((size_t)(mh*48 + b*6+g))<<10) + n0 + c16] = l;
    }
  }
}

// ================= pvmix (round-18 form, unchanged) =================
__global__ __launch_bounds__(256, 2)
void pvmix_kernel(const unsigned char* __restrict__ E, const unsigned char* __restrict__ V8,
                  const float* __restrict__ lpart, const float* __restrict__ tam,
                  unsigned short* __restrict__ outp){
  __shared__ __align__(16) unsigned char Es[6*16*64];
  __shared__ __align__(16) unsigned char Vs[6*64*64];
  __shared__ __align__(16) unsigned char pms[6*16*64];
  int t=threadIdx.x, lane=t&63, w=t>>6;
  int b = blockIdx.x&7, nt = blockIdx.x>>3;
  int n0 = nt*16;
  int c16 = lane&15, r16 = lane>>4;
  int mn = t&15, mg = (t>>4)&7, gh = t>>7;
  float cf[3][6];
  #pragma unroll
  for (int g=0;g<6;g++){
    float l0 = lpart[(((size_t)(b*6+g))<<10) + n0 + mn];
    float l1 = lpart[(((size_t)(48 + b*6+g))<<10) + n0 + mn];
    float iv = 256.0f/(l0 + l1);
    #pragma unroll
    for (int j=0;j<3;j++) cf[j][g] = tam[(gh*3+j)*6 + g]*iv;
  }
  auto stageE = [&](int m0){
    #pragma unroll
    for (int i=0;i<2;i++){
      int u = t + i*256;
      if (u<384){
        int r = u>>2, s = (u&3) ^ (r&3);
        int g = r>>4, n = r&15;
        gload16(E + (((size_t)(b*6+g))<<20) + ((size_t)(n0+n)<<10) + m0 + s*16,
                (char*)Es + u*16);
      }
    }
  };
  auto stageV = [&](int m0){
    #pragma unroll
    for (int i=0;i<6;i++){
      int u = t + i*256;
      int r = u>>2, s = (u&3) ^ (r&3);
      int g = r>>6, d = r&63;
      gload16(V8 + (((size_t)(b*6+g))<<16) + ((size_t)d<<10) + m0 + s*16,
              (char*)Vs + u*16);
    }
  };
  stageE(0); stageV(0);
  __syncthreads();
  f32x4 acc[6] = {};
  for (int mt=0; mt<16; ++mt){
    float e[6][8];
    #pragma unroll
    for (int g=0;g<6;g++){
      int row = g*16 + mn;
      int byteo = row*64 + ((mg*8) ^ ((row&3)<<4));
      unsigned int lo = *(const unsigned int*)(Es + byteo);
      unsigned int hi = *(const unsigned int*)(Es + byteo + 4);
      f32x2 p0 = __builtin_amdgcn_cvt_pk_f32_fp8(lo, false);
      f32x2 p1 = __builtin_amdgcn_cvt_pk_f32_fp8(lo, true);
      f32x2 p2 = __builtin_amdgcn_cvt_pk_f32_fp8(hi, false);
      f32x2 p3 = __builtin_amdgcn_cvt_pk_f32_fp8(hi, true);
      e[g][0]=p0.x; e[g][1]=p0.y; e[g][2]=p1.x; e[g][3]=p1.y;
      e[g][4]=p2.x; e[g][5]=p2.y; e[g][6]=p3.x; e[g][7]=p3.y;
    }
    #pragma unroll
    for (int j=0;j<3;j++){
      float pm[8];
      #pragma unroll
      for (int m=0;m<8;m++)
        pm[m] = cf[j][0]*e[0][m]+cf[j][1]*e[1][m]+cf[j][2]*e[2][m]
              + cf[j][3]*e[3][m]+cf[j][4]*e[4][m]+cf[j][5]*e[5][m];
      int d0 = __builtin_amdgcn_cvt_pk_fp8_f32(pm[0], pm[1], 0, false);
      d0 = __builtin_amdgcn_cvt_pk_fp8_f32(pm[2], pm[3], d0, true);
      int d1 = __builtin_amdgcn_cvt_pk_fp8_f32(pm[4], pm[5], 0, false);
      d1 = __builtin_amdgcn_cvt_pk_fp8_f32(pm[6], pm[7], d1, true);
      int prow = (gh*3+j)*16 + mn;
      int pbyte = prow*64 + ((mg*8) ^ ((mn&7)<<3));
      *(unsigned int*)(pms + pbyte)     = (unsigned int)d0;
      *(unsigned int*)(pms + pbyte + 4) = (unsigned int)d1;
    }
    __syncthreads();
    if (mt<15) stageE((mt+1)*64);
    #pragma unroll
    for (int g=0;g<6;g++){
      int arow = g*16 + c16;
      int vrow = g*64 + w*16 + c16;
      #pragma unroll
      for (int kk=0;kk<2;kk++){
        long af = *(const long*)(pms + arow*64 + ((kk*32 + r16*8) ^ ((c16&7)<<3)));
        long bf = *(const long*)(Vs + vrow*64
                   + ((((kk*2 + (r16>>1)) ^ (vrow&3))<<4) + ((r16&1)<<3)));
        acc[g] = __builtin_amdgcn_mfma_f32_16x16x32_fp8_fp8(af, bf, acc[g], 0,0,0);
      }
    }
    __syncthreads();
    if (mt<15) stageV((mt+1)*64);
  }
  #pragma unroll
  for (int g=0;g<6;g++)
    #pragma unroll
    for (int r=0;r<4;r++){
      int n = n0 + r16*4 + r;
      int d = g*64 + w*16 + c16;
      outp[((size_t)(b*1024 + n))*DD + d] = f2b(acc[g][r] * 0.00390625f);
    }
}

extern "C" void kernel_launch(void* const* d_in, const int* in_sizes, int n_in,
                              void* d_out, int out_size, void* d_ws, size_t ws_size,
                              hipStream_t stream){
  const float* x      = (const float*)d_in[0];
  const float* qkv_w  = (const float*)d_in[1];
  const float* qkv_b  = (const float*)d_in[2];
  const float* proj_w = (const float*)d_in[3];
  const float* proj_b = (const float*)d_in[4];
  const float* t_before=(const float*)d_in[5];
  const float* t_after =(const float*)d_in[6];
  const float* dw_w   = (const float*)d_in[7];
  const float* dw_b   = (const float*)d_in[8];
  const float* mlp_g  = (const float*)d_in[9];
  const float* mlp_b  = (const float*)d_in[10];
  const float* n1_g   = (const float*)d_in[11];
  const float* n1_b   = (const float*)d_in[12];
  const float* n2_g   = (const float*)d_in[13];
  const float* n2_b   = (const float*)d_in[14];
  const float* fc1_w  = (const float*)d_in[15];
  const float* fc1_b  = (const float*)d_in[16];
  const float* fc2_w  = (const float*)d_in[17];
  const float* fc2_b  = (const float*)d_in[18];
  float* out = (float*)d_out;
  char* ws = (char*)d_ws;
  // layout (bytes):
  unsigned short* qkvwb = (unsigned short*)(ws + 0);          // 442368 bf16 (++ projwb contiguous)
  unsigned short* projwb= (unsigned short*)(ws + 884736);     // 147456 bf16
  unsigned char*  fc1w8 = (unsigned char*) (ws + 1179648);    // 589824 fp8 (++ fc2w8 contiguous)
  unsigned char*  fc2w8 = (unsigned char*) (ws + 1769472);    // 589824 fp8
  unsigned short* hb    = (unsigned short*)(ws + 2359296);    // 8192*384 bf16 (reuse: hcln8 fp8)
  unsigned char*  qk8   = (unsigned char*) (ws + 8650752);    // q8f,k8f fp8 frag planes (reuse: h2 bf16)
  unsigned char*  V8    = (unsigned char*) (ws + 27525120);   // 48*64*1024 fp8
  float*          lpart = (float*)        (ws + 30670848);    // 2*48*1024 f32 partial l-sums
  unsigned char*  Ebuf  = (unsigned char*) (ws + 31064064);   // 48MB fp8 E (reuse: fc1o8)
  unsigned short* attnb = (unsigned short*)(ws + 81395712);   // 8192*384 bf16
  float*          x2    = (float*)(ws + 87687168);            // 8192*384 f32
  unsigned short* h2 = (unsigned short*)qk8;
  unsigned char*  hcln8 = (unsigned char*)hb;
  unsigned char*  fc1o8 = Ebuf;

  cvt_kernel<<<6912,256,0,stream>>>(qkv_w, proj_w, fc1_w, fc2_w, qkvwb, fc1w8);

  ln_kernel<<<BN,128,0,stream>>>(x, n1_g, n1_b, hb);
  { dim3 g(BN/128, D3/128); gemm_kernel<0,128><<<g,256,0,stream>>>(hb, qkvwb, qkv_b, nullptr, nullptr, qk8, V8, DD, D3); }
  smx_kernel<<<1024,256,0,stream>>>(qk8, t_before, Ebuf, lpart);
  pvmix_kernel<<<512,256,0,stream>>>(Ebuf, V8, lpart, t_after, attnb);
  { dim3 g(BN/128, DD/64); gemm_kernel<1,64><<<g,256,0,stream>>>(attnb, projwb, proj_b, x, x2, nullptr, nullptr, DD, DD); }
  ln_kernel<<<BN,128,0,stream>>>(x2, n2_g, n2_b, h2);
  conv_ln_kernel<<<BN,128,0,stream>>>(h2, dw_w, dw_b, mlp_g, mlp_b, hcln8);
  { dim3 g(BN/64, D4/64); gemm8_kernel<2><<<g,256,0,stream>>>(hcln8, fc1w8, fc1_b, nullptr, nullptr, fc1o8, DD, D4); }
  { dim3 g(BN/64, DD/64); gemm8_kernel<1><<<g,256,0,stream>>>(fc1o8, fc2w8, fc2_b, x2, out, nullptr, D4, DD); }
}

// Round 20
// 186.533 us; speedup vs baseline: 1.2387x; 1.0061x over previous
//
#include <hip/hip_runtime.h>
#include <hip/hip_bf16.h>

#define BB 8
#define NN 1024
#define DD 384
#define HH 6
#define HD 64
#define BN 8192          // B*N rows
#define D3 1152          // 3*D
#define D4 1536          // 4*D
#define SEC 3145728      // B*H*N*HD elems per plane

typedef __attribute__((ext_vector_type(8))) short short8;
typedef __attribute__((ext_vector_type(4))) float f32x4;
typedef __attribute__((ext_vector_type(2))) float f32x2;
typedef long v2i64 __attribute__((ext_vector_type(2)));

typedef __attribute__((address_space(3))) unsigned char as3_byte;
typedef __attribute__((address_space(1))) const unsigned char as1_byte;

__device__ __forceinline__ void gload16(const void* g, void* l){
  __builtin_amdgcn_global_load_lds((as1_byte*)g, (as3_byte*)l, 16, 0, 0);
}

__device__ __forceinline__ float b2f(unsigned short u){
  union{unsigned int i; float f;} x; x.i=((unsigned int)u)<<16; return x.f;
}
__device__ __forceinline__ unsigned short f2b(float f){
  unsigned int u=__float_as_uint(f);
  return (unsigned short)((u + 0x7FFFu + ((u>>16)&1u))>>16);
}
__device__ __forceinline__ unsigned char f2f8(float f){
  return (unsigned char)(__builtin_amdgcn_cvt_pk_fp8_f32(f, f, 0, false) & 0xff);
}

// ---------------- weight convert: ALL weights -> fp8 (x8), one launch ----------------
// layout: qkvw8 (442368) ++ projw8 (147456) ++ fc1w8 (589824) ++ fc2w8 (589824)
__global__ void cvt_kernel(const float* __restrict__ w0, const float* __restrict__ w1,
                           const float* __restrict__ w2, const float* __restrict__ w3,
                           unsigned char* __restrict__ out8){
  int i = blockIdx.x*256 + threadIdx.x;
  if (i < 442368)        out8[i] = f2f8(w0[i]*8.0f);
  else if (i < 589824)   out8[i] = f2f8(w1[i - 442368]*8.0f);
  else if (i < 1179648)  out8[i] = f2f8(w2[i - 589824]*8.0f);
  else if (i < 1769472)  out8[i] = f2f8(w3[i - 1179648]*8.0f);
}

// ---------------- LayerNorm over D=384, one block per row; OUT8: fp8(x4) else bf16 ----------------
template<int OUT8>
__global__ __launch_bounds__(128)
void ln_kernel(const float* __restrict__ in, const float* __restrict__ gg, const float* __restrict__ bb,
               unsigned short* __restrict__ outb, unsigned char* __restrict__ out8){
  int row = blockIdx.x, t = threadIdx.x;
  const float* r = in + (size_t)row*DD;
  float v0=r[t], v1=r[t+128], v2=r[t+256];
  float s=v0+v1+v2, q=v0*v0+v1*v1+v2*v2;
  #pragma unroll
  for (int o=32;o>0;o>>=1){ s+=__shfl_down(s,o); q+=__shfl_down(q,o); }
  __shared__ float ls[2], lq[2];
  if ((t&63)==0){ ls[t>>6]=s; lq[t>>6]=q; }
  __syncthreads();
  float S=ls[0]+ls[1], Q=lq[0]+lq[1];
  float mean=S*(1.0f/DD);
  float rstd=rsqrtf(Q*(1.0f/DD)-mean*mean+1e-5f);
  float o0=(v0-mean)*rstd*gg[t]+bb[t];
  float o1=(v1-mean)*rstd*gg[t+128]+bb[t+128];
  float o2=(v2-mean)*rstd*gg[t+256]+bb[t+256];
  if (OUT8){
    unsigned char* o=out8+(size_t)row*DD;
    o[t]=f2f8(o0*4.0f); o[t+128]=f2f8(o1*4.0f); o[t+256]=f2f8(o2*4.0f);
  } else {
    unsigned short* o=outb+(size_t)row*DD;
    o[t]=f2b(o0); o[t+128]=f2b(o1); o[t+256]=f2b(o2);
  }
}

// ---------------- depthwise conv1d (K=7) + bias + LayerNorm; bf16 in, fp8(x4) out ----------------
__global__ __launch_bounds__(128)
void conv_ln_kernel(const unsigned short* __restrict__ h2, const float* __restrict__ dww, const float* __restrict__ dwb,
                    const float* __restrict__ gg, const float* __restrict__ bb, unsigned char* __restrict__ out8){
  int row=blockIdx.x, t=threadIdx.x;
  int bi=row>>10, n=row&1023;
  const unsigned short* base = h2 + (size_t)(bi<<10)*DD;
  float a[3];
  #pragma unroll
  for (int j=0;j<3;j++){
    int d=t+j*128;
    float acc=dwb[d];
    #pragma unroll
    for (int k=0;k<7;k++){
      int nn=n+k-3;
      if (nn>=0 && nn<NN) acc += dww[d*7+k]*b2f(base[(size_t)nn*DD + d]);
    }
    a[j]=acc;
  }
  float s=a[0]+a[1]+a[2], q=a[0]*a[0]+a[1]*a[1]+a[2]*a[2];
  #pragma unroll
  for (int o=32;o>0;o>>=1){ s+=__shfl_down(s,o); q+=__shfl_down(q,o); }
  __shared__ float ls[2], lq[2];
  if ((t&63)==0){ ls[t>>6]=s; lq[t>>6]=q; }
  __syncthreads();
  float S=ls[0]+ls[1], Q=lq[0]+lq[1];
  float mean=S*(1.0f/DD);
  float rstd=rsqrtf(Q*(1.0f/DD)-mean*mean+1e-5f);
  unsigned char* o = out8 + (size_t)row*DD;
  #pragma unroll
  for (int j=0;j<3;j++){
    int d=t+j*128;
    o[d]=f2f8(((a[j]-mean)*rstd*gg[d]+bb[d])*4.0f);
  }
}

// ================= fp8 x fp8 GEMM: C = (A8·W8^T)/32 + bias =================
// 64x64 tile, BK=64, double-buffered; 4 waves 2x2 (32x32 each). A8 = 4*act, W8 = 8*w.
// MODE 0: qkv scatter (q,k -> fp8 frag planes, v -> V8 transposed)
// MODE 1: outf = resid + v   (proj / fc2)
// MODE 2: out8 = fp8(4*gelu(v))   (fc1)
template<int MODE>
__global__ __launch_bounds__(256)
void gemm8_kernel(const unsigned char* __restrict__ A8, const unsigned char* __restrict__ W8,
                  const float* __restrict__ bias, const float* __restrict__ resid,
                  float* __restrict__ outf, unsigned char* __restrict__ out8,
                  unsigned char* __restrict__ qk8out, unsigned char* __restrict__ v8out,
                  int Kdim, int Ncols){
  __shared__ __align__(16) unsigned char As[2][64*64];
  __shared__ __align__(16) unsigned char Bs[2][64*64];
  int t=threadIdx.x, lane=t&63, w=t>>6;
  int bm = blockIdx.x*64;
  int bn = blockIdx.y*64;
  int wr = w>>1, wc = w&1;
  int c16=lane&15, r16=lane>>4;
  f32x4 acc[2][2] = {};
  int arow = t>>2, aslot = (t&3) ^ (arow&3);
  auto stage = [&](int buf, int k0){
    gload16(A8 + (size_t)(bm+arow)*Kdim + k0 + aslot*16, (char*)As + buf*4096 + t*16);
    gload16(W8 + (size_t)(bn+arow)*Kdim + k0 + aslot*16, (char*)Bs + buf*4096 + t*16);
  };
  int niter = Kdim>>6;
  stage(0, 0);
  __syncthreads();
  for (int it=0; it<niter; ++it){
    if (it+1<niter) stage((it+1)&1, (it+1)<<6);
    int off = (it&1)*4096;
    #pragma unroll
    for (int kk=0;kk<2;kk++){
      long afr[2], bfr[2];
      #pragma unroll
      for (int i=0;i<2;i++){
        int ra = wr*32 + i*16 + c16;
        int sa = (kk*2 + (r16>>1)) ^ (ra&3);
        afr[i] = *(const long*)((char*)As + off + ra*64 + (sa<<4) + ((r16&1)<<3));
        int rb = wc*32 + i*16 + c16;
        int sb = (kk*2 + (r16>>1)) ^ (rb&3);
        bfr[i] = *(const long*)((char*)Bs + off + rb*64 + (sb<<4) + ((r16&1)<<3));
      }
      #pragma unroll
      for (int i=0;i<2;i++)
        #pragma unroll
        for (int j=0;j<2;j++)
          acc[i][j] = __builtin_amdgcn_mfma_f32_16x16x32_fp8_fp8(afr[i], bfr[j], acc[i][j], 0,0,0);
    }
    __syncthreads();
  }
  #pragma unroll
  for (int i=0;i<2;i++)
    #pragma unroll
    for (int j=0;j<2;j++)
      #pragma unroll
      for (int r=0;r<4;r++){
        int row = bm + wr*32 + i*16 + r16*4 + r;
        int col = bn + wc*32 + j*16 + c16;
        float v = acc[i][j][r]*0.03125f + bias[col];   // A8=4A, W8=8W -> /32
        if (MODE==0){
          int c = col/384; int rem = col - c*384; int hh = rem>>6, d = rem&63;
          int bi = row>>10, nn = row&1023;
          unsigned char pk = f2f8(v);
          if (c==2){
            v8out[(((size_t)(bi*6+hh))<<16) + ((size_t)d<<10) + nn] = pk;
          } else {
            size_t fa = ((size_t)c*SEC)
                      + ((((size_t)(bi*6+hh))<<6) + (nn>>4))*1024
                      + ((((d>>3)&3)*16 + (nn&15))<<4) + ((d>>5)*8) + (d&7);
            qk8out[fa] = pk;
          }
        } else if (MODE==1){
          size_t idx = (size_t)row*Ncols + col;
          outf[idx] = resid[idx] + v;
        } else {
          float ge = 0.5f*v*(1.0f+erff(v*0.70710678118654752f));
          out8[(size_t)row*Ncols + col] = f2f8(ge*4.0f);
        }
      }
}

// ================= smx (round-18 ILP-2 form, unchanged) =================
__global__ __launch_bounds__(256, 4)
void smx_kernel(const unsigned char* __restrict__ qk8, const float* __restrict__ tbm,
                unsigned char* __restrict__ E, float* __restrict__ lpart){
  __shared__ float lred[4][6][16];
  int t=threadIdx.x, lane=t&63, w=t>>6;
  int blk=blockIdx.x;
  int b = blk&7, nt = (blk>>3)&63, mh = blk>>9;
  int n0 = nt*16, mbase = mh*512;
  int c16=lane&15, r16=lane>>4;
  const unsigned char* q8f = qk8;
  const unsigned char* k8f = qk8 + SEC;
  v2i64 qf[6];
  #pragma unroll
  for (int h=0;h<6;h++)
    qf[h] = *(const v2i64*)(q8f + (((((size_t)(b*6+h))<<6) + (n0>>4))<<10) + lane*16);
  float tbr[36];
  #pragma unroll
  for (int i=0;i<36;i++) tbr[i] = tbm[i];
  const float SC = 0.125f*1.44269504088896f;
  float lsum[6]={0.f,0.f,0.f,0.f,0.f,0.f};
  #pragma unroll
  for (int mt=0; mt<4; ++mt){
    int m0a = mbase + mt*128 + w*16;
    int m0b = m0a + 64;
    v2i64 kfa[6], kfb[6];
    #pragma unroll
    for (int h=0;h<6;h++)
      kfa[h] = *(const v2i64*)(k8f + (((((size_t)(b*6+h))<<6) + (m0a>>4))<<10) + lane*16);
    #pragma unroll
    for (int h=0;h<6;h++)
      kfb[h] = *(const v2i64*)(k8f + (((((size_t)(b*6+h))<<6) + (m0b>>4))<<10) + lane*16);
    {
      f32x4 aq[6] = {};
      #pragma unroll
      for (int h=0;h<6;h++){
        aq[h] = __builtin_amdgcn_mfma_f32_16x16x32_fp8_fp8(kfa[h][0], qf[h][0], aq[h], 0,0,0);
        aq[h] = __builtin_amdgcn_mfma_f32_16x16x32_fp8_fp8(kfa[h][1], qf[h][1], aq[h], 0,0,0);
      }
      #pragma unroll
      for (int g=0;g<6;g++){
        float e0,e1,e2,e3;
        {
          float sm;
          sm = tbr[g*6]*aq[0][0]+tbr[g*6+1]*aq[1][0]+tbr[g*6+2]*aq[2][0]
             + tbr[g*6+3]*aq[3][0]+tbr[g*6+4]*aq[4][0]+tbr[g*6+5]*aq[5][0];
          e0 = __builtin_amdgcn_exp2f(sm*SC);
          sm = tbr[g*6]*aq[0][1]+tbr[g*6+1]*aq[1][1]+tbr[g*6+2]*aq[2][1]
             + tbr[g*6+3]*aq[3][1]+tbr[g*6+4]*aq[4][1]+tbr[g*6+5]*aq[5][1];
          e1 = __builtin_amdgcn_exp2f(sm*SC);
          sm = tbr[g*6]*aq[0][2]+tbr[g*6+1]*aq[1][2]+tbr[g*6+2]*aq[2][2]
             + tbr[g*6+3]*aq[3][2]+tbr[g*6+4]*aq[4][2]+tbr[g*6+5]*aq[5][2];
          e2 = __builtin_amdgcn_exp2f(sm*SC);
          sm = tbr[g*6]*aq[0][3]+tbr[g*6+1]*aq[1][3]+tbr[g*6+2]*aq[2][3]
             + tbr[g*6+3]*aq[3][3]+tbr[g*6+4]*aq[4][3]+tbr[g*6+5]*aq[5][3];
          e3 = __builtin_amdgcn_exp2f(sm*SC);
        }
        lsum[g] += (e0+e1)+(e2+e3);
        int pkv = __builtin_amdgcn_cvt_pk_fp8_f32(e0, e1, 0, false);
        pkv = __builtin_amdgcn_cvt_pk_fp8_f32(e2, e3, pkv, true);
        *(unsigned int*)(E + (((size_t)(b*6+g))<<20) + ((size_t)(n0+c16)<<10) + m0a + r16*4)
          = (unsigned int)pkv;
      }
    }
    {
      f32x4 aq[6] = {};
      #pragma unroll
      for (int h=0;h<6;h++){
        aq[h] = __builtin_amdgcn_mfma_f32_16x16x32_fp8_fp8(kfb[h][0], qf[h][0], aq[h], 0,0,0);
        aq[h] = __builtin_amdgcn_mfma_f32_16x16x32_fp8_fp8(kfb[h][1], qf[h][1], aq[h], 0,0,0);
      }
      #pragma unroll
      for (int g=0;g<6;g++){
        float e0,e1,e2,e3;
        {
          float sm;
          sm = tbr[g*6]*aq[0][0]+tbr[g*6+1]*aq[1][0]+tbr[g*6+2]*aq[2][0]
             + tbr[g*6+3]*aq[3][0]+tbr[g*6+4]*aq[4][0]+tbr[g*6+5]*aq[5][0];
          e0 = __builtin_amdgcn_exp2f(sm*SC);
          sm = tbr[g*6]*aq[0][1]+tbr[g*6+1]*aq[1][1]+tbr[g*6+2]*aq[2][1]
             + tbr[g*6+3]*aq[3][1]+tbr[g*6+4]*aq[4][1]+tbr[g*6+5]*aq[5][1];
          e1 = __builtin_amdgcn_exp2f(sm*SC);
          sm = tbr[g*6]*aq[0][2]+tbr[g*6+1]*aq[1][2]+tbr[g*6+2]*aq[2][2]
             + tbr[g*6+3]*aq[3][2]+tbr[g*6+4]*aq[4][2]+tbr[g*6+5]*aq[5][2];
          e2 = __builtin_amdgcn_exp2f(sm*SC);
          sm = tbr[g*6]*aq[0][3]+tbr[g*6+1]*aq[1][3]+tbr[g*6+2]*aq[2][3]
             + tbr[g*6+3]*aq[3][3]+tbr[g*6+4]*aq[4][3]+tbr[g*6+5]*aq[5][3];
          e3 = __builtin_amdgcn_exp2f(sm*SC);
        }
        lsum[g] += (e0+e1)+(e2+e3);
        int pkv = __builtin_amdgcn_cvt_pk_fp8_f32(e0, e1, 0, false);
        pkv = __builtin_amdgcn_cvt_pk_fp8_f32(e2, e3, pkv, true);
        *(unsigned int*)(E + (((size_t)(b*6+g))<<20) + ((size_t)(n0+c16)<<10) + m0b + r16*4)
          = (unsigned int)pkv;
      }
    }
  }
  #pragma unroll
  for (int g=0;g<6;g++){
    lsum[g] += __shfl_xor(lsum[g],16);
    lsum[g] += __shfl_xor(lsum[g],32);
  }
  if (r16==0){
    #pragma unroll
    for (int g=0;g<6;g++) lred[w][g][c16] = lsum[g];
  }
  __syncthreads();
  if (w==0 && r16==0){
    #pragma unroll
    for (int g=0;g<6;g++){
      float l = lred[0][g][c16]+lred[1][g][c16]+lred[2][g][c16]+lred[3][g][c16];
      lpart[(((size_t)(mh*48 + b*6+g))<<10) + n0 + c16] = l;
    }
  }
}

// ================= pvmix (round-18 form; output now fp8 x4 attnb8) =================
__global__ __launch_bounds__(256, 2)
void pvmix_kernel(const unsigned char* __restrict__ E, const unsigned char* __restrict__ V8,
                  const float* __restrict__ lpart, const float* __restrict__ tam,
                  unsigned char* __restrict__ outp8){
  __shared__ __align__(16) unsigned char Es[6*16*64];
  __shared__ __align__(16) unsigned char Vs[6*64*64];
  __shared__ __align__(16) unsigned char pms[6*16*64];
  int t=threadIdx.x, lane=t&63, w=t>>6;
  int b = blockIdx.x&7, nt = blockIdx.x>>3;
  int n0 = nt*16;
  int c16 = lane&15, r16 = lane>>4;
  int mn = t&15, mg = (t>>4)&7, gh = t>>7;
  float cf[3][6];
  #pragma unroll
  for (int g=0;g<6;g++){
    float l0 = lpart[(((size_t)(b*6+g))<<10) + n0 + mn];
    float l1 = lpart[(((size_t)(48 + b*6+g))<<10) + n0 + mn];
    float iv = 256.0f/(l0 + l1);
    #pragma unroll
    for (int j=0;j<3;j++) cf[j][g] = tam[(gh*3+j)*6 + g]*iv;
  }
  auto stageE = [&](int m0){
    #pragma unroll
    for (int i=0;i<2;i++){
      int u = t + i*256;
      if (u<384){
        int r = u>>2, s = (u&3) ^ (r&3);
        int g = r>>4, n = r&15;
        gload16(E + (((size_t)(b*6+g))<<20) + ((size_t)(n0+n)<<10) + m0 + s*16,
                (char*)Es + u*16);
      }
    }
  };
  auto stageV = [&](int m0){
    #pragma unroll
    for (int i=0;i<6;i++){
      int u = t + i*256;
      int r = u>>2, s = (u&3) ^ (r&3);
      int g = r>>6, d = r&63;
      gload16(V8 + (((size_t)(b*6+g))<<16) + ((size_t)d<<10) + m0 + s*16,
              (char*)Vs + u*16);
    }
  };
  stageE(0); stageV(0);
  __syncthreads();
  f32x4 acc[6] = {};
  for (int mt=0; mt<16; ++mt){
    float e[6][8];
    #pragma unroll
    for (int g=0;g<6;g++){
      int row = g*16 + mn;
      int byteo = row*64 + ((mg*8) ^ ((row&3)<<4));
      unsigned int lo = *(const unsigned int*)(Es + byteo);
      unsigned int hi = *(const unsigned int*)(Es + byteo + 4);
      f32x2 p0 = __builtin_amdgcn_cvt_pk_f32_fp8(lo, false);
      f32x2 p1 = __builtin_amdgcn_cvt_pk_f32_fp8(lo, true);
      f32x2 p2 = __builtin_amdgcn_cvt_pk_f32_fp8(hi, false);
      f32x2 p3 = __builtin_amdgcn_cvt_pk_f32_fp8(hi, true);
      e[g][0]=p0.x; e[g][1]=p0.y; e[g][2]=p1.x; e[g][3]=p1.y;
      e[g][4]=p2.x; e[g][5]=p2.y; e[g][6]=p3.x; e[g][7]=p3.y;
    }
    #pragma unroll
    for (int j=0;j<3;j++){
      float pm[8];
      #pragma unroll
      for (int m=0;m<8;m++)
        pm[m] = cf[j][0]*e[0][m]+cf[j][1]*e[1][m]+cf[j][2]*e[2][m]
              + cf[j][3]*e[3][m]+cf[j][4]*e[4][m]+cf[j][5]*e[5][m];
      int d0 = __builtin_amdgcn_cvt_pk_fp8_f32(pm[0], pm[1], 0, false);
      d0 = __builtin_amdgcn_cvt_pk_fp8_f32(pm[2], pm[3], d0, true);
      int d1 = __builtin_amdgcn_cvt_pk_fp8_f32(pm[4], pm[5], 0, false);
      d1 = __builtin_amdgcn_cvt_pk_fp8_f32(pm[6], pm[7], d1, true);
      int prow = (gh*3+j)*16 + mn;
      int pbyte = prow*64 + ((mg*8) ^ ((mn&7)<<3));
      *(unsigned int*)(pms + pbyte)     = (unsigned int)d0;
      *(unsigned int*)(pms + pbyte + 4) = (unsigned int)d1;
    }
    __syncthreads();
    if (mt<15) stageE((mt+1)*64);
    #pragma unroll
    for (int g=0;g<6;g++){
      int arow = g*16 + c16;
      int vrow = g*64 + w*16 + c16;
      #pragma unroll
      for (int kk=0;kk<2;kk++){
        long af = *(const long*)(pms + arow*64 + ((kk*32 + r16*8) ^ ((c16&7)<<3)));
        long bf = *(const long*)(Vs + vrow*64
                   + ((((kk*2 + (r16>>1)) ^ (vrow&3))<<4) + ((r16&1)<<3)));
        acc[g] = __builtin_amdgcn_mfma_f32_16x16x32_fp8_fp8(af, bf, acc[g], 0,0,0);
      }
    }
    __syncthreads();
    if (mt<15) stageV((mt+1)*64);
  }
  #pragma unroll
  for (int g=0;g<6;g++)
    #pragma unroll
    for (int r=0;r<4;r++){
      int n = n0 + r16*4 + r;
      int d = g*64 + w*16 + c16;
      outp8[((size_t)(b*1024 + n))*DD + d] = f2f8(acc[g][r] * 0.015625f);  // /256 then x4
    }
}

extern "C" void kernel_launch(void* const* d_in, const int* in_sizes, int n_in,
                              void* d_out, int out_size, void* d_ws, size_t ws_size,
                              hipStream_t stream){
  const float* x      = (const float*)d_in[0];
  const float* qkv_w  = (const float*)d_in[1];
  const float* qkv_b  = (const float*)d_in[2];
  const float* proj_w = (const float*)d_in[3];
  const float* proj_b = (const float*)d_in[4];
  const float* t_before=(const float*)d_in[5];
  const float* t_after =(const float*)d_in[6];
  const float* dw_w   = (const float*)d_in[7];
  const float* dw_b   = (const float*)d_in[8];
  const float* mlp_g  = (const float*)d_in[9];
  const float* mlp_b  = (const float*)d_in[10];
  const float* n1_g   = (const float*)d_in[11];
  const float* n1_b   = (const float*)d_in[12];
  const float* n2_g   = (const float*)d_in[13];
  const float* n2_b   = (const float*)d_in[14];
  const float* fc1_w  = (const float*)d_in[15];
  const float* fc1_b  = (const float*)d_in[16];
  const float* fc2_w  = (const float*)d_in[17];
  const float* fc2_b  = (const float*)d_in[18];
  float* out = (float*)d_out;
  char* ws = (char*)d_ws;
  // layout (bytes), all 16-aligned:
  unsigned char*  qkvw8 = (unsigned char*)(ws + 0);           // 442368
  unsigned char*  projw8= (unsigned char*)(ws + 442368);      // 147456
  unsigned char*  fc1w8 = (unsigned char*)(ws + 589824);      // 589824
  unsigned char*  fc2w8 = (unsigned char*)(ws + 1179648);     // 589824
  unsigned char*  hb8   = (unsigned char*)(ws + 1769472);     // 8192*384 fp8 (reuse: hcln8)
  unsigned char*  qk8   = (unsigned char*)(ws + 4915200);     // 2*SEC fp8 frag planes (reuse: h2 bf16)
  unsigned char*  V8    = (unsigned char*)(ws + 11206656);    // 48*64*1024 fp8
  float*          lpart = (float*)        (ws + 14352384);    // 2*48*1024 f32
  unsigned char*  Ebuf  = (unsigned char*)(ws + 14745600);    // 48MB fp8 E (reuse: fc1o8)
  unsigned char*  attnb8= (unsigned char*)(ws + 65077248);    // 8192*384 fp8
  float*          x2    = (float*)        (ws + 68222976);    // 8192*384 f32
  unsigned short* h2 = (unsigned short*)qk8;
  unsigned char*  hcln8 = hb8;
  unsigned char*  fc1o8 = Ebuf;

  cvt_kernel<<<6912,256,0,stream>>>(qkv_w, proj_w, fc1_w, fc2_w, qkvw8);

  ln_kernel<1><<<BN,128,0,stream>>>(x, n1_g, n1_b, nullptr, hb8);
  { dim3 g(BN/64, D3/64); gemm8_kernel<0><<<g,256,0,stream>>>(hb8, qkvw8, qkv_b, nullptr, nullptr, nullptr, qk8, V8, DD, D3); }
  smx_kernel<<<1024,256,0,stream>>>(qk8, t_before, Ebuf, lpart);
  pvmix_kernel<<<512,256,0,stream>>>(Ebuf, V8, lpart, t_after, attnb8);
  { dim3 g(BN/64, DD/64); gemm8_kernel<1><<<g,256,0,stream>>>(attnb8, projw8, proj_b, x, x2, nullptr, nullptr, nullptr, DD, DD); }
  ln_kernel<0><<<BN,128,0,stream>>>(x2, n2_g, n2_b, h2, nullptr);
  conv_ln_kernel<<<BN,128,0,stream>>>(h2, dw_w, dw_b, mlp_g, mlp_b, hcln8);
  { dim3 g(BN/64, D4/64); gemm8_kernel<2><<<g,256,0,stream>>>(hcln8, fc1w8, fc1_b, nullptr, nullptr, fc1o8, nullptr, nullptr, DD, D4); }
  { dim3 g(BN/64, DD/64); gemm8_kernel<1><<<g,256,0,stream>>>(fc1o8, fc2w8, fc2_b, x2, out, nullptr, nullptr, nullptr, D4, DD); }
}

// Round 21
// 183.845 us; speedup vs baseline: 1.2569x; 1.0146x over previous
//
#include <hip/hip_runtime.h>
#include <hip/hip_bf16.h>

#define BB 8
#define NN 1024
#define DD 384
#define HH 6
#define HD 64
#define BN 8192          // B*N rows
#define D3 1152          // 3*D
#define D4 1536          // 4*D
#define SEC 3145728      // B*H*N*HD elems per plane

typedef __attribute__((ext_vector_type(8))) short short8;
typedef __attribute__((ext_vector_type(4))) float f32x4;
typedef __attribute__((ext_vector_type(2))) float f32x2;
typedef long v2i64 __attribute__((ext_vector_type(2)));

typedef __attribute__((address_space(3))) unsigned char as3_byte;
typedef __attribute__((address_space(1))) const unsigned char as1_byte;

__device__ __forceinline__ void gload16(const void* g, void* l){
  __builtin_amdgcn_global_load_lds((as1_byte*)g, (as3_byte*)l, 16, 0, 0);
}

__device__ __forceinline__ float b2f(unsigned short u){
  union{unsigned int i; float f;} x; x.i=((unsigned int)u)<<16; return x.f;
}
__device__ __forceinline__ unsigned short f2b(float f){
  unsigned int u=__float_as_uint(f);
  return (unsigned short)((u + 0x7FFFu + ((u>>16)&1u))>>16);
}
__device__ __forceinline__ unsigned char f2f8(float f){
  return (unsigned char)(__builtin_amdgcn_cvt_pk_fp8_f32(f, f, 0, false) & 0xff);
}

// ---------------- weight convert: ALL weights -> fp8 (x8), one launch ----------------
__global__ void cvt_kernel(const float* __restrict__ w0, const float* __restrict__ w1,
                           const float* __restrict__ w2, const float* __restrict__ w3,
                           unsigned char* __restrict__ out8){
  int i = blockIdx.x*256 + threadIdx.x;
  if (i < 442368)        out8[i] = f2f8(w0[i]*8.0f);
  else if (i < 589824)   out8[i] = f2f8(w1[i - 442368]*8.0f);
  else if (i < 1179648)  out8[i] = f2f8(w2[i - 589824]*8.0f);
  else if (i < 1769472)  out8[i] = f2f8(w3[i - 1179648]*8.0f);
}

// ---------------- LayerNorm over D=384, one block per row; OUT8: fp8(x4) else bf16 ----------------
template<int OUT8>
__global__ __launch_bounds__(128)
void ln_kernel(const float* __restrict__ in, const float* __restrict__ gg, const float* __restrict__ bb,
               unsigned short* __restrict__ outb, unsigned char* __restrict__ out8){
  int row = blockIdx.x, t = threadIdx.x;
  const float* r = in + (size_t)row*DD;
  float v0=r[t], v1=r[t+128], v2=r[t+256];
  float s=v0+v1+v2, q=v0*v0+v1*v1+v2*v2;
  #pragma unroll
  for (int o=32;o>0;o>>=1){ s+=__shfl_down(s,o); q+=__shfl_down(q,o); }
  __shared__ float ls[2], lq[2];
  if ((t&63)==0){ ls[t>>6]=s; lq[t>>6]=q; }
  __syncthreads();
  float S=ls[0]+ls[1], Q=lq[0]+lq[1];
  float mean=S*(1.0f/DD);
  float rstd=rsqrtf(Q*(1.0f/DD)-mean*mean+1e-5f);
  float o0=(v0-mean)*rstd*gg[t]+bb[t];
  float o1=(v1-mean)*rstd*gg[t+128]+bb[t+128];
  float o2=(v2-mean)*rstd*gg[t+256]+bb[t+256];
  if (OUT8){
    unsigned char* o=out8+(size_t)row*DD;
    o[t]=f2f8(o0*4.0f); o[t+128]=f2f8(o1*4.0f); o[t+256]=f2f8(o2*4.0f);
  } else {
    unsigned short* o=outb+(size_t)row*DD;
    o[t]=f2b(o0); o[t+128]=f2b(o1); o[t+256]=f2b(o2);
  }
}

// ---------------- depthwise conv1d (K=7) + bias + LayerNorm; bf16 in, fp8(x4) out ----------------
__global__ __launch_bounds__(128)
void conv_ln_kernel(const unsigned short* __restrict__ h2, const float* __restrict__ dww, const float* __restrict__ dwb,
                    const float* __restrict__ gg, const float* __restrict__ bb, unsigned char* __restrict__ out8){
  int row=blockIdx.x, t=threadIdx.x;
  int bi=row>>10, n=row&1023;
  const unsigned short* base = h2 + (size_t)(bi<<10)*DD;
  float a[3];
  #pragma unroll
  for (int j=0;j<3;j++){
    int d=t+j*128;
    float acc=dwb[d];
    #pragma unroll
    for (int k=0;k<7;k++){
      int nn=n+k-3;
      if (nn>=0 && nn<NN) acc += dww[d*7+k]*b2f(base[(size_t)nn*DD + d]);
    }
    a[j]=acc;
  }
  float s=a[0]+a[1]+a[2], q=a[0]*a[0]+a[1]*a[1]+a[2]*a[2];
  #pragma unroll
  for (int o=32;o>0;o>>=1){ s+=__shfl_down(s,o); q+=__shfl_down(q,o); }
  __shared__ float ls[2], lq[2];
  if ((t&63)==0){ ls[t>>6]=s; lq[t>>6]=q; }
  __syncthreads();
  float S=ls[0]+ls[1], Q=lq[0]+lq[1];
  float mean=S*(1.0f/DD);
  float rstd=rsqrtf(Q*(1.0f/DD)-mean*mean+1e-5f);
  unsigned char* o = out8 + (size_t)row*DD;
  #pragma unroll
  for (int j=0;j<3;j++){
    int d=t+j*128;
    o[d]=f2f8(((a[j]-mean)*rstd*gg[d]+bb[d])*4.0f);
  }
}

// ================= fp8 x fp8 GEMM: C = (A8·W8^T)/32 + bias =================
// MODE 0: qkv scatter (q,k -> fp8 frag planes, v -> V8 transposed)
// MODE 1: outf = resid + v   (proj / fc2)
// MODE 2: out8 = fp8(4*gelu(v))   (fc1)
template<int MODE>
__global__ __launch_bounds__(256)
void gemm8_kernel(const unsigned char* __restrict__ A8, const unsigned char* __restrict__ W8,
                  const float* __restrict__ bias, const float* __restrict__ resid,
                  float* __restrict__ outf, unsigned char* __restrict__ out8,
                  unsigned char* __restrict__ qk8out, unsigned char* __restrict__ v8out,
                  int Kdim, int Ncols){
  __shared__ __align__(16) unsigned char As[2][64*64];
  __shared__ __align__(16) unsigned char Bs[2][64*64];
  int t=threadIdx.x, lane=t&63, w=t>>6;
  int bm = blockIdx.x*64;
  int bn = blockIdx.y*64;
  int wr = w>>1, wc = w&1;
  int c16=lane&15, r16=lane>>4;
  f32x4 acc[2][2] = {};
  int arow = t>>2, aslot = (t&3) ^ (arow&3);
  auto stage = [&](int buf, int k0){
    gload16(A8 + (size_t)(bm+arow)*Kdim + k0 + aslot*16, (char*)As + buf*4096 + t*16);
    gload16(W8 + (size_t)(bn+arow)*Kdim + k0 + aslot*16, (char*)Bs + buf*4096 + t*16);
  };
  int niter = Kdim>>6;
  stage(0, 0);
  __syncthreads();
  for (int it=0; it<niter; ++it){
    if (it+1<niter) stage((it+1)&1, (it+1)<<6);
    int off = (it&1)*4096;
    #pragma unroll
    for (int kk=0;kk<2;kk++){
      long afr[2], bfr[2];
      #pragma unroll
      for (int i=0;i<2;i++){
        int ra = wr*32 + i*16 + c16;
        int sa = (kk*2 + (r16>>1)) ^ (ra&3);
        afr[i] = *(const long*)((char*)As + off + ra*64 + (sa<<4) + ((r16&1)<<3));
        int rb = wc*32 + i*16 + c16;
        int sb = (kk*2 + (r16>>1)) ^ (rb&3);
        bfr[i] = *(const long*)((char*)Bs + off + rb*64 + (sb<<4) + ((r16&1)<<3));
      }
      #pragma unroll
      for (int i=0;i<2;i++)
        #pragma unroll
        for (int j=0;j<2;j++)
          acc[i][j] = __builtin_amdgcn_mfma_f32_16x16x32_fp8_fp8(afr[i], bfr[j], acc[i][j], 0,0,0);
    }
    __syncthreads();
  }
  #pragma unroll
  for (int i=0;i<2;i++)
    #pragma unroll
    for (int j=0;j<2;j++)
      #pragma unroll
      for (int r=0;r<4;r++){
        int row = bm + wr*32 + i*16 + r16*4 + r;
        int col = bn + wc*32 + j*16 + c16;
        float v = acc[i][j][r]*0.03125f + bias[col];   // A8=4A, W8=8W -> /32
        if (MODE==0){
          int c = col/384; int rem = col - c*384; int hh = rem>>6, d = rem&63;
          int bi = row>>10, nn = row&1023;
          unsigned char pk = f2f8(v);
          if (c==2){
            v8out[(((size_t)(bi*6+hh))<<16) + ((size_t)d<<10) + nn] = pk;
          } else {
            size_t fa = ((size_t)c*SEC)
                      + ((((size_t)(bi*6+hh))<<6) + (nn>>4))*1024
                      + ((((d>>3)&3)*16 + (nn&15))<<4) + ((d>>5)*8) + (d&7);
            qk8out[fa] = pk;
          }
        } else if (MODE==1){
          size_t idx = (size_t)row*Ncols + col;
          outf[idx] = resid[idx] + v;
        } else {
          float ge = 0.5f*v*(1.0f+erff(v*0.70710678118654752f));
          out8[(size_t)row*Ncols + col] = f2f8(ge*4.0f);
        }
      }
}

// ================= fattn8: fused smx + pvmix. block = (b, 16-row n-tile), 512 blocks, 4 waves =================
// Pass 1 (no barriers): QK^T (fp8 frag planes) + premix + exp2 -> lsum in registers, all 1024 m (ILP-2).
// Reduce l in-block -> invl[g] (256/l) in registers.
// Pass 2 per 64-m tile: recompute QK^T for wave's m-slice, e*invl, postmix -> pms(fp8 LDS);
// bar; PV MFMA (pms x Vs, wave = d-quarter); bar; stageV(next). Output fp8(x4) attnb8.
__global__ __launch_bounds__(256, 2)
void fattn8_kernel(const unsigned char* __restrict__ qk8, const unsigned char* __restrict__ V8,
                   const float* __restrict__ tbm, const float* __restrict__ tam,
                   unsigned char* __restrict__ outp8){
  __shared__ __align__(16) unsigned char Vs[6*64*64];    // 24 KB
  __shared__ __align__(16) unsigned char pms[6*16*64];   // 6 KB
  __shared__ float lred[4][6][16];
  int t=threadIdx.x, lane=t&63, w=t>>6;
  int b = blockIdx.x&7, nt = blockIdx.x>>3;
  int n0 = nt*16;
  int c16=lane&15, r16=lane>>4;
  const unsigned char* q8f = qk8;
  const unsigned char* k8f = qk8 + SEC;
  v2i64 qf[6];
  #pragma unroll
  for (int h=0;h<6;h++)
    qf[h] = *(const v2i64*)(q8f + (((((size_t)(b*6+h))<<6) + (n0>>4))<<10) + lane*16);
  float tbr[36], tar[36];
  #pragma unroll
  for (int i=0;i<36;i++){ tbr[i]=tbm[i]; tar[i]=tam[i]; }
  const float SC = 0.125f*1.44269504088896f;
  // ---------------- PASS 1: l over all m (ILP-2, no stores, no barriers) ----------------
  float lsum[6]={0.f,0.f,0.f,0.f,0.f,0.f};
  #pragma unroll
  for (int mt=0; mt<8; ++mt){
    int m0a = mt*128 + w*16;
    int m0b = m0a + 64;
    v2i64 kfa[6], kfb[6];
    #pragma unroll
    for (int h=0;h<6;h++)
      kfa[h] = *(const v2i64*)(k8f + (((((size_t)(b*6+h))<<6) + (m0a>>4))<<10) + lane*16);
    #pragma unroll
    for (int h=0;h<6;h++)
      kfb[h] = *(const v2i64*)(k8f + (((((size_t)(b*6+h))<<6) + (m0b>>4))<<10) + lane*16);
    {
      f32x4 aq[6] = {};
      #pragma unroll
      for (int h=0;h<6;h++){
        aq[h] = __builtin_amdgcn_mfma_f32_16x16x32_fp8_fp8(kfa[h][0], qf[h][0], aq[h], 0,0,0);
        aq[h] = __builtin_amdgcn_mfma_f32_16x16x32_fp8_fp8(kfa[h][1], qf[h][1], aq[h], 0,0,0);
      }
      #pragma unroll
      for (int r=0;r<4;r++){
        float s0=aq[0][r], s1=aq[1][r], s2=aq[2][r],
              s3=aq[3][r], s4=aq[4][r], s5=aq[5][r];
        #pragma unroll
        for (int g=0;g<6;g++){
          float sm = tbr[g*6]*s0 + tbr[g*6+1]*s1 + tbr[g*6+2]*s2
                   + tbr[g*6+3]*s3 + tbr[g*6+4]*s4 + tbr[g*6+5]*s5;
          lsum[g] += __builtin_amdgcn_exp2f(sm*SC);
        }
      }
    }
    {
      f32x4 aq[6] = {};
      #pragma unroll
      for (int h=0;h<6;h++){
        aq[h] = __builtin_amdgcn_mfma_f32_16x16x32_fp8_fp8(kfb[h][0], qf[h][0], aq[h], 0,0,0);
        aq[h] = __builtin_amdgcn_mfma_f32_16x16x32_fp8_fp8(kfb[h][1], qf[h][1], aq[h], 0,0,0);
      }
      #pragma unroll
      for (int r=0;r<4;r++){
        float s0=aq[0][r], s1=aq[1][r], s2=aq[2][r],
              s3=aq[3][r], s4=aq[4][r], s5=aq[5][r];
        #pragma unroll
        for (int g=0;g<6;g++){
          float sm = tbr[g*6]*s0 + tbr[g*6+1]*s1 + tbr[g*6+2]*s2
                   + tbr[g*6+3]*s3 + tbr[g*6+4]*s4 + tbr[g*6+5]*s5;
          lsum[g] += __builtin_amdgcn_exp2f(sm*SC);
        }
      }
    }
  }
  #pragma unroll
  for (int g=0;g<6;g++){
    lsum[g] += __shfl_xor(lsum[g],16);
    lsum[g] += __shfl_xor(lsum[g],32);
  }
  if (r16==0){
    #pragma unroll
    for (int g=0;g<6;g++) lred[w][g][c16] = lsum[g];
  }
  __syncthreads();
  float invl[6];
  #pragma unroll
  for (int g=0;g<6;g++)
    invl[g] = 256.0f/(lred[0][g][c16]+lred[1][g][c16]+lred[2][g][c16]+lred[3][g][c16]);
  // ---------------- PASS 2: recompute + mix + PV ----------------
  auto stageV = [&](int m0){
    #pragma unroll
    for (int i=0;i<6;i++){
      int u = t + i*256;
      int r = u>>2, s = (u&3) ^ (r&3);
      int g = r>>6, d = r&63;
      gload16(V8 + (((size_t)(b*6+g))<<16) + ((size_t)d<<10) + m0 + s*16,
              (char*)Vs + u*16);
    }
  };
  stageV(0);
  __syncthreads();
  f32x4 acc[6] = {};
  int pmoff = (((w*2+(r16>>1))<<3) ^ ((c16&7)<<3)) + ((r16&1)<<2);
  for (int mt=0; mt<16; ++mt){
    int m0 = mt*64 + w*16;
    v2i64 kf[6];
    #pragma unroll
    for (int h=0;h<6;h++)
      kf[h] = *(const v2i64*)(k8f + (((((size_t)(b*6+h))<<6) + (m0>>4))<<10) + lane*16);
    f32x4 aq[6] = {};
    #pragma unroll
    for (int h=0;h<6;h++){
      aq[h] = __builtin_amdgcn_mfma_f32_16x16x32_fp8_fp8(kf[h][0], qf[h][0], aq[h], 0,0,0);
      aq[h] = __builtin_amdgcn_mfma_f32_16x16x32_fp8_fp8(kf[h][1], qf[h][1], aq[h], 0,0,0);
    }
    float pm[6][4];
    #pragma unroll
    for (int r=0;r<4;r++){
      float s0=aq[0][r], s1=aq[1][r], s2=aq[2][r],
            s3=aq[3][r], s4=aq[4][r], s5=aq[5][r];
      float eg[6];
      #pragma unroll
      for (int g=0;g<6;g++){
        float sm = tbr[g*6]*s0 + tbr[g*6+1]*s1 + tbr[g*6+2]*s2
                 + tbr[g*6+3]*s3 + tbr[g*6+4]*s4 + tbr[g*6+5]*s5;
        eg[g] = __builtin_amdgcn_exp2f(sm*SC) * invl[g];   // 256*P
      }
      #pragma unroll
      for (int g2=0;g2<6;g2++)
        pm[g2][r] = tar[g2*6]*eg[0] + tar[g2*6+1]*eg[1] + tar[g2*6+2]*eg[2]
                  + tar[g2*6+3]*eg[3] + tar[g2*6+4]*eg[4] + tar[g2*6+5]*eg[5];
    }
    #pragma unroll
    for (int g2=0;g2<6;g2++){
      int d0 = __builtin_amdgcn_cvt_pk_fp8_f32(pm[g2][0], pm[g2][1], 0, false);
      d0 = __builtin_amdgcn_cvt_pk_fp8_f32(pm[g2][2], pm[g2][3], d0, true);
      *(unsigned int*)(pms + (g2*16 + c16)*64 + pmoff) = (unsigned int)d0;
    }
    __syncthreads();                 // pms complete; prior stageV drained
    #pragma unroll
    for (int g=0;g<6;g++){
      int arow = g*16 + c16;
      int vrow = g*64 + w*16 + c16;
      #pragma unroll
      for (int kk=0;kk<2;kk++){
        long af = *(const long*)(pms + arow*64 + ((kk*32 + r16*8) ^ ((c16&7)<<3)));
        long bf = *(const long*)(Vs + vrow*64
                   + ((((kk*2 + (r16>>1)) ^ (vrow&3))<<4) + ((r16&1)<<3)));
        acc[g] = __builtin_amdgcn_mfma_f32_16x16x32_fp8_fp8(af, bf, acc[g], 0,0,0);
      }
    }
    __syncthreads();                 // pms/Vs reads done
    if (mt<15) stageV((mt+1)*64);
  }
  #pragma unroll
  for (int g=0;g<6;g++)
    #pragma unroll
    for (int r=0;r<4;r++){
      int n = n0 + r16*4 + r;
      int d = g*64 + w*16 + c16;
      outp8[((size_t)(b*1024 + n))*DD + d] = f2f8(acc[g][r] * 0.015625f);  // /256 then x4
    }
}

extern "C" void kernel_launch(void* const* d_in, const int* in_sizes, int n_in,
                              void* d_out, int out_size, void* d_ws, size_t ws_size,
                              hipStream_t stream){
  const float* x      = (const float*)d_in[0];
  const float* qkv_w  = (const float*)d_in[1];
  const float* qkv_b  = (const float*)d_in[2];
  const float* proj_w = (const float*)d_in[3];
  const float* proj_b = (const float*)d_in[4];
  const float* t_before=(const float*)d_in[5];
  const float* t_after =(const float*)d_in[6];
  const float* dw_w   = (const float*)d_in[7];
  const float* dw_b   = (const float*)d_in[8];
  const float* mlp_g  = (const float*)d_in[9];
  const float* mlp_b  = (const float*)d_in[10];
  const float* n1_g   = (const float*)d_in[11];
  const float* n1_b   = (const float*)d_in[12];
  const float* n2_g   = (const float*)d_in[13];
  const float* n2_b   = (const float*)d_in[14];
  const float* fc1_w  = (const float*)d_in[15];
  const float* fc1_b  = (const float*)d_in[16];
  const float* fc2_w  = (const float*)d_in[17];
  const float* fc2_b  = (const float*)d_in[18];
  float* out = (float*)d_out;
  char* ws = (char*)d_ws;
  unsigned char*  qkvw8 = (unsigned char*)(ws + 0);           // 442368
  unsigned char*  projw8= (unsigned char*)(ws + 442368);      // 147456
  unsigned char*  fc1w8 = (unsigned char*)(ws + 589824);      // 589824
  unsigned char*  fc2w8 = (unsigned char*)(ws + 1179648);     // 589824
  unsigned char*  hb8   = (unsigned char*)(ws + 1769472);     // 8192*384 fp8 (reuse: hcln8)
  unsigned char*  qk8   = (unsigned char*)(ws + 4915200);     // 2*SEC fp8 frag planes (reuse: h2 bf16)
  unsigned char*  V8    = (unsigned char*)(ws + 11206656);    // 48*64*1024 fp8
  unsigned char*  fc1o8 = (unsigned char*)(ws + 14745600);    // 8192*1536 fp8
  unsigned char*  attnb8= (unsigned char*)(ws + 65077248);    // 8192*384 fp8
  float*          x2    = (float*)        (ws + 68222976);    // 8192*384 f32
  unsigned short* h2 = (unsigned short*)qk8;
  unsigned char*  hcln8 = hb8;

  cvt_kernel<<<6912,256,0,stream>>>(qkv_w, proj_w, fc1_w, fc2_w, qkvw8);

  ln_kernel<1><<<BN,128,0,stream>>>(x, n1_g, n1_b, nullptr, hb8);
  { dim3 g(BN/64, D3/64); gemm8_kernel<0><<<g,256,0,stream>>>(hb8, qkvw8, qkv_b, nullptr, nullptr, nullptr, qk8, V8, DD, D3); }
  fattn8_kernel<<<512,256,0,stream>>>(qk8, V8, t_before, t_after, attnb8);
  { dim3 g(BN/64, DD/64); gemm8_kernel<1><<<g,256,0,stream>>>(attnb8, projw8, proj_b, x, x2, nullptr, nullptr, nullptr, DD, DD); }
  ln_kernel<0><<<BN,128,0,stream>>>(x2, n2_g, n2_b, h2, nullptr);
  conv_ln_kernel<<<BN,128,0,stream>>>(h2, dw_w, dw_b, mlp_g, mlp_b, hcln8);
  { dim3 g(BN/64, D4/64); gemm8_kernel<2><<<g,256,0,stream>>>(hcln8, fc1w8, fc1_b, nullptr, nullptr, fc1o8, nullptr, nullptr, DD, D4); }
  { dim3 g(BN/64, DD/64); gemm8_kernel<1><<<g,256,0,stream>>>(fc1o8, fc2w8, fc2_b, x2, out, nullptr, nullptr, nullptr, D4, DD); }
}

// Round 22
// 181.553 us; speedup vs baseline: 1.2727x; 1.0126x over previous
//
#include <hip/hip_runtime.h>
#include <hip/hip_bf16.h>

#define BB 8
#define NN 1024
#define DD 384
#define HH 6
#define HD 64
#define BN 8192          // B*N rows
#define D3 1152          // 3*D
#define D4 1536          // 4*D
#define SEC 3145728      // B*H*N*HD elems per plane

typedef __attribute__((ext_vector_type(8))) short short8;
typedef __attribute__((ext_vector_type(4))) float f32x4;
typedef __attribute__((ext_vector_type(2))) float f32x2;
typedef long v2i64 __attribute__((ext_vector_type(2)));

typedef __attribute__((address_space(3))) unsigned char as3_byte;
typedef __attribute__((address_space(1))) const unsigned char as1_byte;

__device__ __forceinline__ void gload16(const void* g, void* l){
  __builtin_amdgcn_global_load_lds((as1_byte*)g, (as3_byte*)l, 16, 0, 0);
}

__device__ __forceinline__ float b2f(unsigned short u){
  union{unsigned int i; float f;} x; x.i=((unsigned int)u)<<16; return x.f;
}
__device__ __forceinline__ unsigned short f2b(float f){
  unsigned int u=__float_as_uint(f);
  return (unsigned short)((u + 0x7FFFu + ((u>>16)&1u))>>16);
}
__device__ __forceinline__ unsigned char f2f8(float f){
  return (unsigned char)(__builtin_amdgcn_cvt_pk_fp8_f32(f, f, 0, false) & 0xff);
}

// ---------------- weight convert: ALL weights -> fp8 (x8), one launch ----------------
__global__ void cvt_kernel(const float* __restrict__ w0, const float* __restrict__ w1,
                           const float* __restrict__ w2, const float* __restrict__ w3,
                           unsigned char* __restrict__ out8){
  int i = blockIdx.x*256 + threadIdx.x;
  if (i < 442368)        out8[i] = f2f8(w0[i]*8.0f);
  else if (i < 589824)   out8[i] = f2f8(w1[i - 442368]*8.0f);
  else if (i < 1179648)  out8[i] = f2f8(w2[i - 589824]*8.0f);
  else if (i < 1769472)  out8[i] = f2f8(w3[i - 1179648]*8.0f);
}

// ---------------- LayerNorm over D=384, one block per row; OUT8: fp8(x4) else bf16 ----------------
template<int OUT8>
__global__ __launch_bounds__(128)
void ln_kernel(const float* __restrict__ in, const float* __restrict__ gg, const float* __restrict__ bb,
               unsigned short* __restrict__ outb, unsigned char* __restrict__ out8){
  int row = blockIdx.x, t = threadIdx.x;
  const float* r = in + (size_t)row*DD;
  float v0=r[t], v1=r[t+128], v2=r[t+256];
  float s=v0+v1+v2, q=v0*v0+v1*v1+v2*v2;
  #pragma unroll
  for (int o=32;o>0;o>>=1){ s+=__shfl_down(s,o); q+=__shfl_down(q,o); }
  __shared__ float ls[2], lq[2];
  if ((t&63)==0){ ls[t>>6]=s; lq[t>>6]=q; }
  __syncthreads();
  float S=ls[0]+ls[1], Q=lq[0]+lq[1];
  float mean=S*(1.0f/DD);
  float rstd=rsqrtf(Q*(1.0f/DD)-mean*mean+1e-5f);
  float o0=(v0-mean)*rstd*gg[t]+bb[t];
  float o1=(v1-mean)*rstd*gg[t+128]+bb[t+128];
  float o2=(v2-mean)*rstd*gg[t+256]+bb[t+256];
  if (OUT8){
    unsigned char* o=out8+(size_t)row*DD;
    o[t]=f2f8(o0*4.0f); o[t+128]=f2f8(o1*4.0f); o[t+256]=f2f8(o2*4.0f);
  } else {
    unsigned short* o=outb+(size_t)row*DD;
    o[t]=f2b(o0); o[t+128]=f2b(o1); o[t+256]=f2b(o2);
  }
}

// ---------------- depthwise conv1d (K=7) + bias + LayerNorm; bf16 in, fp8(x4) out ----------------
__global__ __launch_bounds__(128)
void conv_ln_kernel(const unsigned short* __restrict__ h2, const float* __restrict__ dww, const float* __restrict__ dwb,
                    const float* __restrict__ gg, const float* __restrict__ bb, unsigned char* __restrict__ out8){
  int row=blockIdx.x, t=threadIdx.x;
  int bi=row>>10, n=row&1023;
  const unsigned short* base = h2 + (size_t)(bi<<10)*DD;
  float a[3];
  #pragma unroll
  for (int j=0;j<3;j++){
    int d=t+j*128;
    float acc=dwb[d];
    #pragma unroll
    for (int k=0;k<7;k++){
      int nn=n+k-3;
      if (nn>=0 && nn<NN) acc += dww[d*7+k]*b2f(base[(size_t)nn*DD + d]);
    }
    a[j]=acc;
  }
  float s=a[0]+a[1]+a[2], q=a[0]*a[0]+a[1]*a[1]+a[2]*a[2];
  #pragma unroll
  for (int o=32;o>0;o>>=1){ s+=__shfl_down(s,o); q+=__shfl_down(q,o); }
  __shared__ float ls[2], lq[2];
  if ((t&63)==0){ ls[t>>6]=s; lq[t>>6]=q; }
  __syncthreads();
  float S=ls[0]+ls[1], Q=lq[0]+lq[1];
  float mean=S*(1.0f/DD);
  float rstd=rsqrtf(Q*(1.0f/DD)-mean*mean+1e-5f);
  unsigned char* o = out8 + (size_t)row*DD;
  #pragma unroll
  for (int j=0;j<3;j++){
    int d=t+j*128;
    o[d]=f2f8(((a[j]-mean)*rstd*gg[d]+bb[d])*4.0f);
  }
}

// ================= fp8 x fp8 GEMM: C = (A8·W8^T)/32 + bias =================
// MODE 0: qkv scatter (q,k -> fp8 frag planes, v -> V8 transposed)
// MODE 1: outf = resid + v   (proj / fc2)
// MODE 2: out8 = fp8(4*gelu(v))   (fc1)
template<int MODE>
__global__ __launch_bounds__(256)
void gemm8_kernel(const unsigned char* __restrict__ A8, const unsigned char* __restrict__ W8,
                  const float* __restrict__ bias, const float* __restrict__ resid,
                  float* __restrict__ outf, unsigned char* __restrict__ out8,
                  unsigned char* __restrict__ qk8out, unsigned char* __restrict__ v8out,
                  int Kdim, int Ncols){
  __shared__ __align__(16) unsigned char As[2][64*64];
  __shared__ __align__(16) unsigned char Bs[2][64*64];
  int t=threadIdx.x, lane=t&63, w=t>>6;
  int bm = blockIdx.x*64;
  int bn = blockIdx.y*64;
  int wr = w>>1, wc = w&1;
  int c16=lane&15, r16=lane>>4;
  f32x4 acc[2][2] = {};
  int arow = t>>2, aslot = (t&3) ^ (arow&3);
  auto stage = [&](int buf, int k0){
    gload16(A8 + (size_t)(bm+arow)*Kdim + k0 + aslot*16, (char*)As + buf*4096 + t*16);
    gload16(W8 + (size_t)(bn+arow)*Kdim + k0 + aslot*16, (char*)Bs + buf*4096 + t*16);
  };
  int niter = Kdim>>6;
  stage(0, 0);
  __syncthreads();
  for (int it=0; it<niter; ++it){
    if (it+1<niter) stage((it+1)&1, (it+1)<<6);
    int off = (it&1)*4096;
    #pragma unroll
    for (int kk=0;kk<2;kk++){
      long afr[2], bfr[2];
      #pragma unroll
      for (int i=0;i<2;i++){
        int ra = wr*32 + i*16 + c16;
        int sa = (kk*2 + (r16>>1)) ^ (ra&3);
        afr[i] = *(const long*)((char*)As + off + ra*64 + (sa<<4) + ((r16&1)<<3));
        int rb = wc*32 + i*16 + c16;
        int sb = (kk*2 + (r16>>1)) ^ (rb&3);
        bfr[i] = *(const long*)((char*)Bs + off + rb*64 + (sb<<4) + ((r16&1)<<3));
      }
      #pragma unroll
      for (int i=0;i<2;i++)
        #pragma unroll
        for (int j=0;j<2;j++)
          acc[i][j] = __builtin_amdgcn_mfma_f32_16x16x32_fp8_fp8(afr[i], bfr[j], acc[i][j], 0,0,0);
    }
    __syncthreads();
  }
  #pragma unroll
  for (int i=0;i<2;i++)
    #pragma unroll
    for (int j=0;j<2;j++)
      #pragma unroll
      for (int r=0;r<4;r++){
        int row = bm + wr*32 + i*16 + r16*4 + r;
        int col = bn + wc*32 + j*16 + c16;
        float v = acc[i][j][r]*0.03125f + bias[col];   // A8=4A, W8=8W -> /32
        if (MODE==0){
          int c = col/384; int rem = col - c*384; int hh = rem>>6, d = rem&63;
          int bi = row>>10, nn = row&1023;
          unsigned char pk = f2f8(v);
          if (c==2){
            v8out[(((size_t)(bi*6+hh))<<16) + ((size_t)d<<10) + nn] = pk;
          } else {
            size_t fa = ((size_t)c*SEC)
                      + ((((size_t)(bi*6+hh))<<6) + (nn>>4))*1024
                      + ((((d>>3)&3)*16 + (nn&15))<<4) + ((d>>5)*8) + (d&7);
            qk8out[fa] = pk;
          }
        } else if (MODE==1){
          size_t idx = (size_t)row*Ncols + col;
          outf[idx] = resid[idx] + v;
        } else {
          float ge = 0.5f*v*(1.0f+erff(v*0.70710678118654752f));
          out8[(size_t)row*Ncols + col] = f2f8(ge*4.0f);
        }
      }
}

// ================= fattn8: fused smx + pvmix. block = (b, 16-row n-tile), 512 blocks, 4 waves =================
// pms row stride padded 64 -> 72 bytes: A-frag reads spread over all 16 even banks (was 16-bank 8-way).
// stageV(0) issued before pass 1; the lred barrier drains it.
__global__ __launch_bounds__(256, 2)
void fattn8_kernel(const unsigned char* __restrict__ qk8, const unsigned char* __restrict__ V8,
                   const float* __restrict__ tbm, const float* __restrict__ tam,
                   unsigned char* __restrict__ outp8){
  __shared__ __align__(16) unsigned char Vs[6*64*64];    // 24 KB
  __shared__ __align__(16) unsigned char pms[6*16*72];   // 6.75 KB, 72B row stride
  __shared__ float lred[4][6][16];
  int t=threadIdx.x, lane=t&63, w=t>>6;
  int b = blockIdx.x&7, nt = blockIdx.x>>3;
  int n0 = nt*16;
  int c16=lane&15, r16=lane>>4;
  const unsigned char* q8f = qk8;
  const unsigned char* k8f = qk8 + SEC;
  v2i64 qf[6];
  #pragma unroll
  for (int h=0;h<6;h++)
    qf[h] = *(const v2i64*)(q8f + (((((size_t)(b*6+h))<<6) + (n0>>4))<<10) + lane*16);
  float tbr[36], tar[36];
  #pragma unroll
  for (int i=0;i<36;i++){ tbr[i]=tbm[i]; tar[i]=tam[i]; }
  const float SC = 0.125f*1.44269504088896f;
  auto stageV = [&](int m0){
    #pragma unroll
    for (int i=0;i<6;i++){
      int u = t + i*256;
      int r = u>>2, s = (u&3) ^ (r&3);
      int g = r>>6, d = r&63;
      gload16(V8 + (((size_t)(b*6+g))<<16) + ((size_t)d<<10) + m0 + s*16,
              (char*)Vs + u*16);
    }
  };
  stageV(0);   // independent of pass 1; drained by the lred barrier
  // ---------------- PASS 1: l over all m (ILP-2, no stores, no barriers) ----------------
  float lsum[6]={0.f,0.f,0.f,0.f,0.f,0.f};
  #pragma unroll
  for (int mt=0; mt<8; ++mt){
    int m0a = mt*128 + w*16;
    int m0b = m0a + 64;
    v2i64 kfa[6], kfb[6];
    #pragma unroll
    for (int h=0;h<6;h++)
      kfa[h] = *(const v2i64*)(k8f + (((((size_t)(b*6+h))<<6) + (m0a>>4))<<10) + lane*16);
    #pragma unroll
    for (int h=0;h<6;h++)
      kfb[h] = *(const v2i64*)(k8f + (((((size_t)(b*6+h))<<6) + (m0b>>4))<<10) + lane*16);
    {
      f32x4 aq[6] = {};
      #pragma unroll
      for (int h=0;h<6;h++){
        aq[h] = __builtin_amdgcn_mfma_f32_16x16x32_fp8_fp8(kfa[h][0], qf[h][0], aq[h], 0,0,0);
        aq[h] = __builtin_amdgcn_mfma_f32_16x16x32_fp8_fp8(kfa[h][1], qf[h][1], aq[h], 0,0,0);
      }
      #pragma unroll
      for (int r=0;r<4;r++){
        float s0=aq[0][r], s1=aq[1][r], s2=aq[2][r],
              s3=aq[3][r], s4=aq[4][r], s5=aq[5][r];
        #pragma unroll
        for (int g=0;g<6;g++){
          float sm = tbr[g*6]*s0 + tbr[g*6+1]*s1 + tbr[g*6+2]*s2
                   + tbr[g*6+3]*s3 + tbr[g*6+4]*s4 + tbr[g*6+5]*s5;
          lsum[g] += __builtin_amdgcn_exp2f(sm*SC);
        }
      }
    }
    {
      f32x4 aq[6] = {};
      #pragma unroll
      for (int h=0;h<6;h++){
        aq[h] = __builtin_amdgcn_mfma_f32_16x16x32_fp8_fp8(kfb[h][0], qf[h][0], aq[h], 0,0,0);
        aq[h] = __builtin_amdgcn_mfma_f32_16x16x32_fp8_fp8(kfb[h][1], qf[h][1], aq[h], 0,0,0);
      }
      #pragma unroll
      for (int r=0;r<4;r++){
        float s0=aq[0][r], s1=aq[1][r], s2=aq[2][r],
              s3=aq[3][r], s4=aq[4][r], s5=aq[5][r];
        #pragma unroll
        for (int g=0;g<6;g++){
          float sm = tbr[g*6]*s0 + tbr[g*6+1]*s1 + tbr[g*6+2]*s2
                   + tbr[g*6+3]*s3 + tbr[g*6+4]*s4 + tbr[g*6+5]*s5;
          lsum[g] += __builtin_amdgcn_exp2f(sm*SC);
        }
      }
    }
  }
  #pragma unroll
  for (int g=0;g<6;g++){
    lsum[g] += __shfl_xor(lsum[g],16);
    lsum[g] += __shfl_xor(lsum[g],32);
  }
  if (r16==0){
    #pragma unroll
    for (int g=0;g<6;g++) lred[w][g][c16] = lsum[g];
  }
  __syncthreads();      // lred visible; stageV(0) drained
  float invl[6];
  #pragma unroll
  for (int g=0;g<6;g++)
    invl[g] = 256.0f/(lred[0][g][c16]+lred[1][g][c16]+lred[2][g][c16]+lred[3][g][c16]);
  // ---------------- PASS 2: recompute + mix + PV ----------------
  f32x4 acc[6] = {};
  int pmoff = (((w*2+(r16>>1))<<3) ^ ((c16&7)<<3)) + ((r16&1)<<2);
  for (int mt=0; mt<16; ++mt){
    int m0 = mt*64 + w*16;
    v2i64 kf[6];
    #pragma unroll
    for (int h=0;h<6;h++)
      kf[h] = *(const v2i64*)(k8f + (((((size_t)(b*6+h))<<6) + (m0>>4))<<10) + lane*16);
    f32x4 aq[6] = {};
    #pragma unroll
    for (int h=0;h<6;h++){
      aq[h] = __builtin_amdgcn_mfma_f32_16x16x32_fp8_fp8(kf[h][0], qf[h][0], aq[h], 0,0,0);
      aq[h] = __builtin_amdgcn_mfma_f32_16x16x32_fp8_fp8(kf[h][1], qf[h][1], aq[h], 0,0,0);
    }
    float pm[6][4];
    #pragma unroll
    for (int r=0;r<4;r++){
      float s0=aq[0][r], s1=aq[1][r], s2=aq[2][r],
            s3=aq[3][r], s4=aq[4][r], s5=aq[5][r];
      float eg[6];
      #pragma unroll
      for (int g=0;g<6;g++){
        float sm = tbr[g*6]*s0 + tbr[g*6+1]*s1 + tbr[g*6+2]*s2
                 + tbr[g*6+3]*s3 + tbr[g*6+4]*s4 + tbr[g*6+5]*s5;
        eg[g] = __builtin_amdgcn_exp2f(sm*SC) * invl[g];   // 256*P
      }
      #pragma unroll
      for (int g2=0;g2<6;g2++)
        pm[g2][r] = tar[g2*6]*eg[0] + tar[g2*6+1]*eg[1] + tar[g2*6+2]*eg[2]
                  + tar[g2*6+3]*eg[3] + tar[g2*6+4]*eg[4] + tar[g2*6+5]*eg[5];
    }
    #pragma unroll
    for (int g2=0;g2<6;g2++){
      int d0 = __builtin_amdgcn_cvt_pk_fp8_f32(pm[g2][0], pm[g2][1], 0, false);
      d0 = __builtin_amdgcn_cvt_pk_fp8_f32(pm[g2][2], pm[g2][3], d0, true);
      *(unsigned int*)(pms + (g2*16 + c16)*72 + pmoff) = (unsigned int)d0;
    }
    __syncthreads();                 // pms complete; prior stageV drained
    #pragma unroll
    for (int g=0;g<6;g++){
      int arow = g*16 + c16;
      int vrow = g*64 + w*16 + c16;
      #pragma unroll
      for (int kk=0;kk<2;kk++){
        long af = *(const long*)(pms + arow*72 + ((kk*32 + r16*8) ^ ((c16&7)<<3)));
        long bf = *(const long*)(Vs + vrow*64
                   + ((((kk*2 + (r16>>1)) ^ (vrow&3))<<4) + ((r16&1)<<3)));
        acc[g] = __builtin_amdgcn_mfma_f32_16x16x32_fp8_fp8(af, bf, acc[g], 0,0,0);
      }
    }
    __syncthreads();                 // pms/Vs reads done
    if (mt<15) stageV((mt+1)*64);
  }
  #pragma unroll
  for (int g=0;g<6;g++)
    #pragma unroll
    for (int r=0;r<4;r++){
      int n = n0 + r16*4 + r;
      int d = g*64 + w*16 + c16;
      outp8[((size_t)(b*1024 + n))*DD + d] = f2f8(acc[g][r] * 0.015625f);  // /256 then x4
    }
}

extern "C" void kernel_launch(void* const* d_in, const int* in_sizes, int n_in,
                              void* d_out, int out_size, void* d_ws, size_t ws_size,
                              hipStream_t stream){
  const float* x      = (const float*)d_in[0];
  const float* qkv_w  = (const float*)d_in[1];
  const float* qkv_b  = (const float*)d_in[2];
  const float* proj_w = (const float*)d_in[3];
  const float* proj_b = (const float*)d_in[4];
  const float* t_before=(const float*)d_in[5];
  const float* t_after =(const float*)d_in[6];
  const float* dw_w   = (const float*)d_in[7];
  const float* dw_b   = (const float*)d_in[8];
  const float* mlp_g  = (const float*)d_in[9];
  const float* mlp_b  = (const float*)d_in[10];
  const float* n1_g   = (const float*)d_in[11];
  const float* n1_b   = (const float*)d_in[12];
  const float* n2_g   = (const float*)d_in[13];
  const float* n2_b   = (const float*)d_in[14];
  const float* fc1_w  = (const float*)d_in[15];
  const float* fc1_b  = (const float*)d_in[16];
  const float* fc2_w  = (const float*)d_in[17];
  const float* fc2_b  = (const float*)d_in[18];
  float* out = (float*)d_out;
  char* ws = (char*)d_ws;
  unsigned char*  qkvw8 = (unsigned char*)(ws + 0);           // 442368
  unsigned char*  projw8= (unsigned char*)(ws + 442368);      // 147456
  unsigned char*  fc1w8 = (unsigned char*)(ws + 589824);      // 589824
  unsigned char*  fc2w8 = (unsigned char*)(ws + 1179648);     // 589824
  unsigned char*  hb8   = (unsigned char*)(ws + 1769472);     // 8192*384 fp8 (reuse: hcln8)
  unsigned char*  qk8   = (unsigned char*)(ws + 4915200);     // 2*SEC fp8 frag planes (reuse: h2 bf16)
  unsigned char*  V8    = (unsigned char*)(ws + 11206656);    // 48*64*1024 fp8
  unsigned char*  fc1o8 = (unsigned char*)(ws + 14745600);    // 8192*1536 fp8
  unsigned char*  attnb8= (unsigned char*)(ws + 65077248);    // 8192*384 fp8
  float*          x2    = (float*)        (ws + 68222976);    // 8192*384 f32
  unsigned short* h2 = (unsigned short*)qk8;
  unsigned char*  hcln8 = hb8;

  cvt_kernel<<<6912,256,0,stream>>>(qkv_w, proj_w, fc1_w, fc2_w, qkvw8);

  ln_kernel<1><<<BN,128,0,stream>>>(x, n1_g, n1_b, nullptr, hb8);
  { dim3 g(BN/64, D3/64); gemm8_kernel<0><<<g,256,0,stream>>>(hb8, qkvw8, qkv_b, nullptr, nullptr, nullptr, qk8, V8, DD, D3); }
  fattn8_kernel<<<512,256,0,stream>>>(qk8, V8, t_before, t_after, attnb8);
  { dim3 g(BN/64, DD/64); gemm8_kernel<1><<<g,256,0,stream>>>(attnb8, projw8, proj_b, x, x2, nullptr, nullptr, nullptr, DD, DD); }
  ln_kernel<0><<<BN,128,0,stream>>>(x2, n2_g, n2_b, h2, nullptr);
  conv_ln_kernel<<<BN,128,0,stream>>>(h2, dw_w, dw_b, mlp_g, mlp_b, hcln8);
  { dim3 g(BN/64, D4/64); gemm8_kernel<2><<<g,256,0,stream>>>(hcln8, fc1w8, fc1_b, nullptr, nullptr, fc1o8, nullptr, nullptr, DD, D4); }
  { dim3 g(BN/64, DD/64); gemm8_kernel<1><<<g,256,0,stream>>>(fc1o8, fc2w8, fc2_b, x2, out, nullptr, nullptr, nullptr, D4, DD); }
}

// Round 23
// 180.582 us; speedup vs baseline: 1.2796x; 1.0054x over previous
//
#include <hip/hip_runtime.h>
#include <hip/hip_bf16.h>

#define BB 8
#define NN 1024
#define DD 384
#define HH 6
#define HD 64
#define BN 8192          // B*N rows
#define D3 1152          // 3*D
#define D4 1536          // 4*D
#define SEC 3145728      // B*H*N*HD elems per plane

typedef __attribute__((ext_vector_type(8))) short short8;
typedef __attribute__((ext_vector_type(4))) float f32x4;
typedef __attribute__((ext_vector_type(2))) float f32x2;
typedef long v2i64 __attribute__((ext_vector_type(2)));

typedef __attribute__((address_space(3))) unsigned char as3_byte;
typedef __attribute__((address_space(1))) const unsigned char as1_byte;

__device__ __forceinline__ void gload16(const void* g, void* l){
  __builtin_amdgcn_global_load_lds((as1_byte*)g, (as3_byte*)l, 16, 0, 0);
}

__device__ __forceinline__ float b2f(unsigned short u){
  union{unsigned int i; float f;} x; x.i=((unsigned int)u)<<16; return x.f;
}
__device__ __forceinline__ unsigned short f2b(float f){
  unsigned int u=__float_as_uint(f);
  return (unsigned short)((u + 0x7FFFu + ((u>>16)&1u))>>16);
}
__device__ __forceinline__ unsigned char f2f8(float f){
  return (unsigned char)(__builtin_amdgcn_cvt_pk_fp8_f32(f, f, 0, false) & 0xff);
}

// ---------------- weight convert: ALL weights -> fp8 (x8), one launch ----------------
__global__ void cvt_kernel(const float* __restrict__ w0, const float* __restrict__ w1,
                           const float* __restrict__ w2, const float* __restrict__ w3,
                           unsigned char* __restrict__ out8){
  int i = blockIdx.x*256 + threadIdx.x;
  if (i < 442368)        out8[i] = f2f8(w0[i]*8.0f);
  else if (i < 589824)   out8[i] = f2f8(w1[i - 442368]*8.0f);
  else if (i < 1179648)  out8[i] = f2f8(w2[i - 589824]*8.0f);
  else if (i < 1769472)  out8[i] = f2f8(w3[i - 1179648]*8.0f);
}

// ---------------- LayerNorm over D=384, one block per row; OUT8: fp8(x4) else bf16 ----------------
template<int OUT8>
__global__ __launch_bounds__(128)
void ln_kernel(const float* __restrict__ in, const float* __restrict__ gg, const float* __restrict__ bb,
               unsigned short* __restrict__ outb, unsigned char* __restrict__ out8){
  int row = blockIdx.x, t = threadIdx.x;
  const float* r = in + (size_t)row*DD;
  float v0=r[t], v1=r[t+128], v2=r[t+256];
  float s=v0+v1+v2, q=v0*v0+v1*v1+v2*v2;
  #pragma unroll
  for (int o=32;o>0;o>>=1){ s+=__shfl_down(s,o); q+=__shfl_down(q,o); }
  __shared__ float ls[2], lq[2];
  if ((t&63)==0){ ls[t>>6]=s; lq[t>>6]=q; }
  __syncthreads();
  float S=ls[0]+ls[1], Q=lq[0]+lq[1];
  float mean=S*(1.0f/DD);
  float rstd=rsqrtf(Q*(1.0f/DD)-mean*mean+1e-5f);
  float o0=(v0-mean)*rstd*gg[t]+bb[t];
  float o1=(v1-mean)*rstd*gg[t+128]+bb[t+128];
  float o2=(v2-mean)*rstd*gg[t+256]+bb[t+256];
  if (OUT8){
    unsigned char* o=out8+(size_t)row*DD;
    o[t]=f2f8(o0*4.0f); o[t+128]=f2f8(o1*4.0f); o[t+256]=f2f8(o2*4.0f);
  } else {
    unsigned short* o=outb+(size_t)row*DD;
    o[t]=f2b(o0); o[t+128]=f2b(o1); o[t+256]=f2b(o2);
  }
}

// ---------------- depthwise conv1d (K=7) + bias + LayerNorm; bf16 in, fp8(x4) out ----------------
__global__ __launch_bounds__(128)
void conv_ln_kernel(const unsigned short* __restrict__ h2, const float* __restrict__ dww, const float* __restrict__ dwb,
                    const float* __restrict__ gg, const float* __restrict__ bb, unsigned char* __restrict__ out8){
  int row=blockIdx.x, t=threadIdx.x;
  int bi=row>>10, n=row&1023;
  const unsigned short* base = h2 + (size_t)(bi<<10)*DD;
  float a[3];
  #pragma unroll
  for (int j=0;j<3;j++){
    int d=t+j*128;
    float acc=dwb[d];
    #pragma unroll
    for (int k=0;k<7;k++){
      int nn=n+k-3;
      if (nn>=0 && nn<NN) acc += dww[d*7+k]*b2f(base[(size_t)nn*DD + d]);
    }
    a[j]=acc;
  }
  float s=a[0]+a[1]+a[2], q=a[0]*a[0]+a[1]*a[1]+a[2]*a[2];
  #pragma unroll
  for (int o=32;o>0;o>>=1){ s+=__shfl_down(s,o); q+=__shfl_down(q,o); }
  __shared__ float ls[2], lq[2];
  if ((t&63)==0){ ls[t>>6]=s; lq[t>>6]=q; }
  __syncthreads();
  float S=ls[0]+ls[1], Q=lq[0]+lq[1];
  float mean=S*(1.0f/DD);
  float rstd=rsqrtf(Q*(1.0f/DD)-mean*mean+1e-5f);
  unsigned char* o = out8 + (size_t)row*DD;
  #pragma unroll
  for (int j=0;j<3;j++){
    int d=t+j*128;
    o[d]=f2f8(((a[j]-mean)*rstd*gg[d]+bb[d])*4.0f);
  }
}

// ================= fp8 x fp8 GEMM: C = (A8·W8^T)/32 + bias =================
// MODE 0: qkv scatter (q,k -> fp8 frag planes, v -> V8 transposed)
// MODE 1: outf = resid + v   (proj / fc2)
// MODE 2: out8 = fp8(4*gelu(v))   (fc1)
template<int MODE>
__global__ __launch_bounds__(256)
void gemm8_kernel(const unsigned char* __restrict__ A8, const unsigned char* __restrict__ W8,
                  const float* __restrict__ bias, const float* __restrict__ resid,
                  float* __restrict__ outf, unsigned char* __restrict__ out8,
                  unsigned char* __restrict__ qk8out, unsigned char* __restrict__ v8out,
                  int Kdim, int Ncols){
  __shared__ __align__(16) unsigned char As[2][64*64];
  __shared__ __align__(16) unsigned char Bs[2][64*64];
  int t=threadIdx.x, lane=t&63, w=t>>6;
  int bm = blockIdx.x*64;
  int bn = blockIdx.y*64;
  int wr = w>>1, wc = w&1;
  int c16=lane&15, r16=lane>>4;
  f32x4 acc[2][2] = {};
  int arow = t>>2, aslot = (t&3) ^ (arow&3);
  auto stage = [&](int buf, int k0){
    gload16(A8 + (size_t)(bm+arow)*Kdim + k0 + aslot*16, (char*)As + buf*4096 + t*16);
    gload16(W8 + (size_t)(bn+arow)*Kdim + k0 + aslot*16, (char*)Bs + buf*4096 + t*16);
  };
  int niter = Kdim>>6;
  stage(0, 0);
  __syncthreads();
  for (int it=0; it<niter; ++it){
    if (it+1<niter) stage((it+1)&1, (it+1)<<6);
    int off = (it&1)*4096;
    #pragma unroll
    for (int kk=0;kk<2;kk++){
      long afr[2], bfr[2];
      #pragma unroll
      for (int i=0;i<2;i++){
        int ra = wr*32 + i*16 + c16;
        int sa = (kk*2 + (r16>>1)) ^ (ra&3);
        afr[i] = *(const long*)((char*)As + off + ra*64 + (sa<<4) + ((r16&1)<<3));
        int rb = wc*32 + i*16 + c16;
        int sb = (kk*2 + (r16>>1)) ^ (rb&3);
        bfr[i] = *(const long*)((char*)Bs + off + rb*64 + (sb<<4) + ((r16&1)<<3));
      }
      #pragma unroll
      for (int i=0;i<2;i++)
        #pragma unroll
        for (int j=0;j<2;j++)
          acc[i][j] = __builtin_amdgcn_mfma_f32_16x16x32_fp8_fp8(afr[i], bfr[j], acc[i][j], 0,0,0);
    }
    __syncthreads();
  }
  #pragma unroll
  for (int i=0;i<2;i++)
    #pragma unroll
    for (int j=0;j<2;j++)
      #pragma unroll
      for (int r=0;r<4;r++){
        int row = bm + wr*32 + i*16 + r16*4 + r;
        int col = bn + wc*32 + j*16 + c16;
        float v = acc[i][j][r]*0.03125f + bias[col];   // A8=4A, W8=8W -> /32
        if (MODE==0){
          int c = col/384; int rem = col - c*384; int hh = rem>>6, d = rem&63;
          int bi = row>>10, nn = row&1023;
          unsigned char pk = f2f8(v);
          if (c==2){
            v8out[(((size_t)(bi*6+hh))<<16) + ((size_t)d<<10) + nn] = pk;
          } else {
            size_t fa = ((size_t)c*SEC)
                      + ((((size_t)(bi*6+hh))<<6) + (nn>>4))*1024
                      + ((((d>>3)&3)*16 + (nn&15))<<4) + ((d>>5)*8) + (d&7);
            qk8out[fa] = pk;
          }
        } else if (MODE==1){
          size_t idx = (size_t)row*Ncols + col;
          outf[idx] = resid[idx] + v;
        } else {
          float ge = 0.5f*v*(1.0f+erff(v*0.70710678118654752f));
          out8[(size_t)row*Ncols + col] = f2f8(ge*4.0f);
        }
      }
}

// ================= fattn8: fused smx + pvmix. block = (b, 16-row n-tile), 512 blocks, 4 waves =================
// Pass 1: ILP-2 QK^T+premix+exp -> lsum, no barriers. Pass 2: per 64-m tile recompute + mix -> pms,
// PV MFMA; kf loads for tile mt+1 PREFETCHED before tile mt's VALU/PV phase (reg-pipelined, named
// arrays, statically indexed; launch_bounds(256,2) caps VGPR at 256 -> no spill).
__global__ __launch_bounds__(256, 2)
void fattn8_kernel(const unsigned char* __restrict__ qk8, const unsigned char* __restrict__ V8,
                   const float* __restrict__ tbm, const float* __restrict__ tam,
                   unsigned char* __restrict__ outp8){
  __shared__ __align__(16) unsigned char Vs[6*64*64];    // 24 KB
  __shared__ __align__(16) unsigned char pms[6*16*72];   // 6.75 KB, 72B row stride
  __shared__ float lred[4][6][16];
  int t=threadIdx.x, lane=t&63, w=t>>6;
  int b = blockIdx.x&7, nt = blockIdx.x>>3;
  int n0 = nt*16;
  int c16=lane&15, r16=lane>>4;
  const unsigned char* q8f = qk8;
  const unsigned char* k8f = qk8 + SEC;
  v2i64 qf[6];
  #pragma unroll
  for (int h=0;h<6;h++)
    qf[h] = *(const v2i64*)(q8f + (((((size_t)(b*6+h))<<6) + (n0>>4))<<10) + lane*16);
  float tbr[36], tar[36];
  #pragma unroll
  for (int i=0;i<36;i++){ tbr[i]=tbm[i]; tar[i]=tam[i]; }
  const float SC = 0.125f*1.44269504088896f;
  auto stageV = [&](int m0){
    #pragma unroll
    for (int i=0;i<6;i++){
      int u = t + i*256;
      int r = u>>2, s = (u&3) ^ (r&3);
      int g = r>>6, d = r&63;
      gload16(V8 + (((size_t)(b*6+g))<<16) + ((size_t)d<<10) + m0 + s*16,
              (char*)Vs + u*16);
    }
  };
  stageV(0);   // independent of pass 1; drained by the lred barrier
  // ---------------- PASS 1: l over all m (ILP-2, no stores, no barriers) ----------------
  float lsum[6]={0.f,0.f,0.f,0.f,0.f,0.f};
  #pragma unroll
  for (int mt=0; mt<8; ++mt){
    int m0a = mt*128 + w*16;
    int m0b = m0a + 64;
    v2i64 kfa[6], kfb[6];
    #pragma unroll
    for (int h=0;h<6;h++)
      kfa[h] = *(const v2i64*)(k8f + (((((size_t)(b*6+h))<<6) + (m0a>>4))<<10) + lane*16);
    #pragma unroll
    for (int h=0;h<6;h++)
      kfb[h] = *(const v2i64*)(k8f + (((((size_t)(b*6+h))<<6) + (m0b>>4))<<10) + lane*16);
    {
      f32x4 aq[6] = {};
      #pragma unroll
      for (int h=0;h<6;h++){
        aq[h] = __builtin_amdgcn_mfma_f32_16x16x32_fp8_fp8(kfa[h][0], qf[h][0], aq[h], 0,0,0);
        aq[h] = __builtin_amdgcn_mfma_f32_16x16x32_fp8_fp8(kfa[h][1], qf[h][1], aq[h], 0,0,0);
      }
      #pragma unroll
      for (int r=0;r<4;r++){
        float s0=aq[0][r], s1=aq[1][r], s2=aq[2][r],
              s3=aq[3][r], s4=aq[4][r], s5=aq[5][r];
        #pragma unroll
        for (int g=0;g<6;g++){
          float sm = tbr[g*6]*s0 + tbr[g*6+1]*s1 + tbr[g*6+2]*s2
                   + tbr[g*6+3]*s3 + tbr[g*6+4]*s4 + tbr[g*6+5]*s5;
          lsum[g] += __builtin_amdgcn_exp2f(sm*SC);
        }
      }
    }
    {
      f32x4 aq[6] = {};
      #pragma unroll
      for (int h=0;h<6;h++){
        aq[h] = __builtin_amdgcn_mfma_f32_16x16x32_fp8_fp8(kfb[h][0], qf[h][0], aq[h], 0,0,0);
        aq[h] = __builtin_amdgcn_mfma_f32_16x16x32_fp8_fp8(kfb[h][1], qf[h][1], aq[h], 0,0,0);
      }
      #pragma unroll
      for (int r=0;r<4;r++){
        float s0=aq[0][r], s1=aq[1][r], s2=aq[2][r],
              s3=aq[3][r], s4=aq[4][r], s5=aq[5][r];
        #pragma unroll
        for (int g=0;g<6;g++){
          float sm = tbr[g*6]*s0 + tbr[g*6+1]*s1 + tbr[g*6+2]*s2
                   + tbr[g*6+3]*s3 + tbr[g*6+4]*s4 + tbr[g*6+5]*s5;
          lsum[g] += __builtin_amdgcn_exp2f(sm*SC);
        }
      }
    }
  }
  #pragma unroll
  for (int g=0;g<6;g++){
    lsum[g] += __shfl_xor(lsum[g],16);
    lsum[g] += __shfl_xor(lsum[g],32);
  }
  if (r16==0){
    #pragma unroll
    for (int g=0;g<6;g++) lred[w][g][c16] = lsum[g];
  }
  __syncthreads();      // lred visible; stageV(0) drained
  float invl[6];
  #pragma unroll
  for (int g=0;g<6;g++)
    invl[g] = 256.0f/(lred[0][g][c16]+lred[1][g][c16]+lred[2][g][c16]+lred[3][g][c16]);
  // ---------------- PASS 2: recompute + mix + PV, kf register-pipelined ----------------
  f32x4 acc[6] = {};
  int pmoff = (((w*2+(r16>>1))<<3) ^ ((c16&7)<<3)) + ((r16&1)<<2);
  v2i64 kfc[6], kfn[6];
  #pragma unroll
  for (int h=0;h<6;h++)
    kfc[h] = *(const v2i64*)(k8f + (((((size_t)(b*6+h))<<6) + ((w*16)>>4))<<10) + lane*16);
  for (int mt=0; mt<16; ++mt){
    // prefetch next tile's fragments: latency hides under this tile's VALU + PV
    if (mt<15){
      int m1 = (mt+1)*64 + w*16;
      #pragma unroll
      for (int h=0;h<6;h++)
        kfn[h] = *(const v2i64*)(k8f + (((((size_t)(b*6+h))<<6) + (m1>>4))<<10) + lane*16);
    }
    f32x4 aq[6] = {};
    #pragma unroll
    for (int h=0;h<6;h++){
      aq[h] = __builtin_amdgcn_mfma_f32_16x16x32_fp8_fp8(kfc[h][0], qf[h][0], aq[h], 0,0,0);
      aq[h] = __builtin_amdgcn_mfma_f32_16x16x32_fp8_fp8(kfc[h][1], qf[h][1], aq[h], 0,0,0);
    }
    float pm[6][4];
    #pragma unroll
    for (int r=0;r<4;r++){
      float s0=aq[0][r], s1=aq[1][r], s2=aq[2][r],
            s3=aq[3][r], s4=aq[4][r], s5=aq[5][r];
      float eg[6];
      #pragma unroll
      for (int g=0;g<6;g++){
        float sm = tbr[g*6]*s0 + tbr[g*6+1]*s1 + tbr[g*6+2]*s2
                 + tbr[g*6+3]*s3 + tbr[g*6+4]*s4 + tbr[g*6+5]*s5;
        eg[g] = __builtin_amdgcn_exp2f(sm*SC) * invl[g];   // 256*P
      }
      #pragma unroll
      for (int g2=0;g2<6;g2++)
        pm[g2][r] = tar[g2*6]*eg[0] + tar[g2*6+1]*eg[1] + tar[g2*6+2]*eg[2]
                  + tar[g2*6+3]*eg[3] + tar[g2*6+4]*eg[4] + tar[g2*6+5]*eg[5];
    }
    #pragma unroll
    for (int g2=0;g2<6;g2++){
      int d0 = __builtin_amdgcn_cvt_pk_fp8_f32(pm[g2][0], pm[g2][1], 0, false);
      d0 = __builtin_amdgcn_cvt_pk_fp8_f32(pm[g2][2], pm[g2][3], d0, true);
      *(unsigned int*)(pms + (g2*16 + c16)*72 + pmoff) = (unsigned int)d0;
    }
    __syncthreads();                 // pms complete; prior stageV drained
    #pragma unroll
    for (int g=0;g<6;g++){
      int arow = g*16 + c16;
      int vrow = g*64 + w*16 + c16;
      #pragma unroll
      for (int kk=0;kk<2;kk++){
        long af = *(const long*)(pms + arow*72 + ((kk*32 + r16*8) ^ ((c16&7)<<3)));
        long bf = *(const long*)(Vs + vrow*64
                   + ((((kk*2 + (r16>>1)) ^ (vrow&3))<<4) + ((r16&1)<<3)));
        acc[g] = __builtin_amdgcn_mfma_f32_16x16x32_fp8_fp8(af, bf, acc[g], 0,0,0);
      }
    }
    __syncthreads();                 // pms/Vs reads done
    if (mt<15) stageV((mt+1)*64);
    #pragma unroll
    for (int h=0;h<6;h++) kfc[h] = kfn[h];
  }
  #pragma unroll
  for (int g=0;g<6;g++)
    #pragma unroll
    for (int r=0;r<4;r++){
      int n = n0 + r16*4 + r;
      int d = g*64 + w*16 + c16;
      outp8[((size_t)(b*1024 + n))*DD + d] = f2f8(acc[g][r] * 0.015625f);  // /256 then x4
    }
}

extern "C" void kernel_launch(void* const* d_in, const int* in_sizes, int n_in,
                              void* d_out, int out_size, void* d_ws, size_t ws_size,
                              hipStream_t stream){
  const float* x      = (const float*)d_in[0];
  const float* qkv_w  = (const float*)d_in[1];
  const float* qkv_b  = (const float*)d_in[2];
  const float* proj_w = (const float*)d_in[3];
  const float* proj_b = (const float*)d_in[4];
  const float* t_before=(const float*)d_in[5];
  const float* t_after =(const float*)d_in[6];
  const float* dw_w   = (const float*)d_in[7];
  const float* dw_b   = (const float*)d_in[8];
  const float* mlp_g  = (const float*)d_in[9];
  const float* mlp_b  = (const float*)d_in[10];
  const float* n1_g   = (const float*)d_in[11];
  const float* n1_b   = (const float*)d_in[12];
  const float* n2_g   = (const float*)d_in[13];
  const float* n2_b   = (const float*)d_in[14];
  const float* fc1_w  = (const float*)d_in[15];
  const float* fc1_b  = (const float*)d_in[16];
  const float* fc2_w  = (const float*)d_in[17];
  const float* fc2_b  = (const float*)d_in[18];
  float* out = (float*)d_out;
  char* ws = (char*)d_ws;
  unsigned char*  qkvw8 = (unsigned char*)(ws + 0);           // 442368
  unsigned char*  projw8= (unsigned char*)(ws + 442368);      // 147456
  unsigned char*  fc1w8 = (unsigned char*)(ws + 589824);      // 589824
  unsigned char*  fc2w8 = (unsigned char*)(ws + 1179648);     // 589824
  unsigned char*  hb8   = (unsigned char*)(ws + 1769472);     // 8192*384 fp8 (reuse: hcln8)
  unsigned char*  qk8   = (unsigned char*)(ws + 4915200);     // 2*SEC fp8 frag planes (reuse: h2 bf16)
  unsigned char*  V8    = (unsigned char*)(ws + 11206656);    // 48*64*1024 fp8
  unsigned char*  fc1o8 = (unsigned char*)(ws + 14745600);    // 8192*1536 fp8
  unsigned char*  attnb8= (unsigned char*)(ws + 65077248);    // 8192*384 fp8
  float*          x2    = (float*)        (ws + 68222976);    // 8192*384 f32
  unsigned short* h2 = (unsigned short*)qk8;
  unsigned char*  hcln8 = hb8;

  cvt_kernel<<<6912,256,0,stream>>>(qkv_w, proj_w, fc1_w, fc2_w, qkvw8);

  ln_kernel<1><<<BN,128,0,stream>>>(x, n1_g, n1_b, nullptr, hb8);
  { dim3 g(BN/64, D3/64); gemm8_kernel<0><<<g,256,0,stream>>>(hb8, qkvw8, qkv_b, nullptr, nullptr, nullptr, qk8, V8, DD, D3); }
  fattn8_kernel<<<512,256,0,stream>>>(qk8, V8, t_before, t_after, attnb8);
  { dim3 g(BN/64, DD/64); gemm8_kernel<1><<<g,256,0,stream>>>(attnb8, projw8, proj_b, x, x2, nullptr, nullptr, nullptr, DD, DD); }
  ln_kernel<0><<<BN,128,0,stream>>>(x2, n2_g, n2_b, h2, nullptr);
  conv_ln_kernel<<<BN,128,0,stream>>>(h2, dw_w, dw_b, mlp_g, mlp_b, hcln8);
  { dim3 g(BN/64, D4/64); gemm8_kernel<2><<<g,256,0,stream>>>(hcln8, fc1w8, fc1_b, nullptr, nullptr, fc1o8, nullptr, nullptr, DD, D4); }
  { dim3 g(BN/64, DD/64); gemm8_kernel<1><<<g,256,0,stream>>>(fc1o8, fc2w8, fc2_b, x2, out, nullptr, nullptr, nullptr, D4, DD); }
}